// Round 1
// baseline (6223.838 us; speedup 1.0000x reference)
//
#include <hip/hip_runtime.h>
#include <hip/hip_bf16.h>
#include <math.h>

// Problem constants
#define BB 2
#define SS 2048
#define DD 1024
#define HH 16
#define DH 64
#define NROW (BB*SS)          // 4096
#define FFN (4*DD)            // 4096

// ---------------- LayerNorm (torch semantics: ddof=1, eps on std) -------------
__global__ __launch_bounds__(256)
void ln_kernel(const float* __restrict__ x, const float* __restrict__ scale,
               const float* __restrict__ shift, float* __restrict__ y) {
    int row = blockIdx.x;
    const float* xr = x + (size_t)row * DD;
    float* yr = y + (size_t)row * DD;
    int t = threadIdx.x;
    float v[4];
    float s = 0.f, ss = 0.f;
#pragma unroll
    for (int i = 0; i < 4; ++i) {
        v[i] = xr[t + 256 * i];
        s += v[i];
        ss += v[i] * v[i];
    }
#pragma unroll
    for (int off = 32; off; off >>= 1) {
        s  += __shfl_xor(s, off);
        ss += __shfl_xor(ss, off);
    }
    __shared__ float red[8];
    int w = t >> 6;
    if ((t & 63) == 0) { red[w] = s; red[w + 4] = ss; }
    __syncthreads();
    float st  = red[0] + red[1] + red[2] + red[3];
    float sst = red[4] + red[5] + red[6] + red[7];
    float mu = st * (1.f / DD);
    float var = (sst - DD * mu * mu) * (1.f / (DD - 1));
    var = fmaxf(var, 0.f);
    float inv = 1.f / (sqrtf(var) + 1e-9f);
#pragma unroll
    for (int i = 0; i < 4; ++i) {
        int c = t + 256 * i;
        yr[c] = scale[c] * (v[i] - mu) * inv + shift[c];
    }
}

// LN over (a + b) (residual then LN2)
__global__ __launch_bounds__(256)
void ln_res_kernel(const float* __restrict__ xa, const float* __restrict__ xb,
                   const float* __restrict__ scale, const float* __restrict__ shift,
                   float* __restrict__ y) {
    int row = blockIdx.x;
    const float* ar = xa + (size_t)row * DD;
    const float* br = xb + (size_t)row * DD;
    float* yr = y + (size_t)row * DD;
    int t = threadIdx.x;
    float v[4];
    float s = 0.f, ss = 0.f;
#pragma unroll
    for (int i = 0; i < 4; ++i) {
        int c = t + 256 * i;
        v[i] = ar[c] + br[c];
        s += v[i];
        ss += v[i] * v[i];
    }
#pragma unroll
    for (int off = 32; off; off >>= 1) {
        s  += __shfl_xor(s, off);
        ss += __shfl_xor(ss, off);
    }
    __shared__ float red[8];
    int w = t >> 6;
    if ((t & 63) == 0) { red[w] = s; red[w + 4] = ss; }
    __syncthreads();
    float st  = red[0] + red[1] + red[2] + red[3];
    float sst = red[4] + red[5] + red[6] + red[7];
    float mu = st * (1.f / DD);
    float var = (sst - DD * mu * mu) * (1.f / (DD - 1));
    var = fmaxf(var, 0.f);
    float inv = 1.f / (sqrtf(var) + 1e-9f);
#pragma unroll
    for (int i = 0; i < 4; ++i) {
        int c = t + 256 * i;
        yr[c] = scale[c] * (v[i] - mu) * inv + shift[c];
    }
}

// ---------------- Tiled fp32 GEMM: C = A(MxK) @ W(KxN) + bias [+relu | +add] --
// MODE 0: +bias; 1: +bias,relu; 2: +bias,+addsrc
#define BM 64
#define BN 64
#define BKT 16

template <int MODE>
__global__ __launch_bounds__(256)
void gemm_kernel(const float* __restrict__ A, const float* __restrict__ W,
                 const float* __restrict__ bias, const float* __restrict__ addsrc,
                 float* __restrict__ C, int M, int N, int K) {
    __shared__ float As[BKT][BM];   // transposed A tile
    __shared__ float Bs[BKT][BN];
    int tid = threadIdx.x;
    int tx = tid & 15;          // 0..15  (cols)
    int ty = tid >> 4;          // 0..15  (rows)
    int block_row = blockIdx.y * BM;
    int block_col = blockIdx.x * BN;

    float acc[4][4] = {};

    int a_m = tid >> 2;            // 0..63
    int a_k = (tid & 3) * 4;       // 0,4,8,12
    int b_k = tid >> 4;            // 0..15
    int b_n = (tid & 15) * 4;      // 0..60

    for (int k0 = 0; k0 < K; k0 += BKT) {
        float4 av = *reinterpret_cast<const float4*>(&A[(size_t)(block_row + a_m) * K + k0 + a_k]);
        float4 bv = *reinterpret_cast<const float4*>(&W[(size_t)(k0 + b_k) * N + block_col + b_n]);
        As[a_k + 0][a_m] = av.x;
        As[a_k + 1][a_m] = av.y;
        As[a_k + 2][a_m] = av.z;
        As[a_k + 3][a_m] = av.w;
        *reinterpret_cast<float4*>(&Bs[b_k][b_n]) = bv;
        __syncthreads();
#pragma unroll
        for (int kk = 0; kk < BKT; ++kk) {
            float4 a4 = *reinterpret_cast<const float4*>(&As[kk][ty * 4]);
            float4 b4 = *reinterpret_cast<const float4*>(&Bs[kk][tx * 4]);
            float a[4] = {a4.x, a4.y, a4.z, a4.w};
            float b[4] = {b4.x, b4.y, b4.z, b4.w};
#pragma unroll
            for (int i = 0; i < 4; ++i)
#pragma unroll
                for (int j = 0; j < 4; ++j)
                    acc[i][j] = fmaf(a[i], b[j], acc[i][j]);
        }
        __syncthreads();
    }

#pragma unroll
    for (int i = 0; i < 4; ++i) {
        int r = block_row + ty * 4 + i;
#pragma unroll
        for (int j = 0; j < 4; ++j) {
            int c = block_col + tx * 4 + j;
            float val = acc[i][j] + bias[c];
            if (MODE == 1) val = fmaxf(val, 0.f);
            if (MODE == 2) val += addsrc[(size_t)r * N + c];
            C[(size_t)r * N + c] = val;
        }
    }
}

// ---------------- Causal attention: one wave per query row -------------------
__global__ __launch_bounds__(256)
void attn_kernel(const float* __restrict__ Q, const float* __restrict__ K,
                 const float* __restrict__ V, float* __restrict__ O) {
    int wid = (blockIdx.x * blockDim.x + threadIdx.x) >> 6;
    int lane = threadIdx.x & 63;
    int q = wid % SS;
    int bh = wid / SS;          // b*HH + h
    int h = bh % HH;
    int b = bh / HH;

    const float* qptr = Q + (size_t)(b * SS + q) * DD + h * DH;
    float qv = qptr[lane] * 0.125f;   // 1/sqrt(64)
    const float* kbase = K + (size_t)(b * SS) * DD + h * DH;
    const float* vbase = V + (size_t)(b * SS) * DD + h * DH;

    float m = -INFINITY, l = 0.f, acc = 0.f;
    for (int k = 0; k <= q; ++k) {
        float s = qv * kbase[(size_t)k * DD + lane];
#pragma unroll
        for (int off = 32; off; off >>= 1) s += __shfl_xor(s, off);
        float m_new = fmaxf(m, s);
        float p = __expf(s - m_new);
        float corr = __expf(m - m_new);
        l = l * corr + p;
        acc = fmaf(p, vbase[(size_t)k * DD + lane], acc * corr);
        m = m_new;
    }
    O[(size_t)(b * SS + q) * DD + h * DH + lane] = acc / l;
}

// ---------------- Launch ------------------------------------------------------
extern "C" void kernel_launch(void* const* d_in, const int* in_sizes, int n_in,
                              void* d_out, int out_size, void* d_ws, size_t ws_size,
                              hipStream_t stream) {
    const float* inputs    = (const float*)d_in[0];
    const float* ln1_scale = (const float*)d_in[1];
    const float* ln1_shift = (const float*)d_in[2];
    const float* Wq = (const float*)d_in[3];
    const float* bq = (const float*)d_in[4];
    const float* Wk = (const float*)d_in[5];
    const float* bk = (const float*)d_in[6];
    const float* Wv = (const float*)d_in[7];
    const float* bv = (const float*)d_in[8];
    const float* Wo = (const float*)d_in[9];
    const float* bo = (const float*)d_in[10];
    const float* W1 = (const float*)d_in[11];
    const float* b1 = (const float*)d_in[12];
    const float* W2 = (const float*)d_in[13];
    const float* b2 = (const float*)d_in[14];
    const float* ln2_scale = (const float*)d_in[15];
    const float* ln2_shift = (const float*)d_in[16];
    float* out = (float*)d_out;

    const size_t SZ = (size_t)NROW * DD;   // 4M floats
    float* f0 = (float*)d_ws;              // xn, later attn_out
    float* f1 = f0 + SZ;                   // q, later proj
    float* f2 = f1 + SZ;                   // k, later o2
    float* f3 = f2 + SZ;                   // v
    float* f4 = f3 + SZ;                   // h1 (4096x4096)

    // 1. LN1
    ln_kernel<<<NROW, 256, 0, stream>>>(inputs, ln1_scale, ln1_shift, f0);

    // 2. QKV projections
    dim3 g1(DD / BN, NROW / BM);
    gemm_kernel<0><<<g1, 256, 0, stream>>>(f0, Wq, bq, nullptr, f1, NROW, DD, DD);
    gemm_kernel<0><<<g1, 256, 0, stream>>>(f0, Wk, bk, nullptr, f2, NROW, DD, DD);
    gemm_kernel<0><<<g1, 256, 0, stream>>>(f0, Wv, bv, nullptr, f3, NROW, DD, DD);

    // 3. Attention (writes f0; xn is dead)
    attn_kernel<<<(BB * HH * SS) / 4, 256, 0, stream>>>(f1, f2, f3, f0);

    // 4. Output projection (writes f1; q dead)
    gemm_kernel<0><<<g1, 256, 0, stream>>>(f0, Wo, bo, nullptr, f1, NROW, DD, DD);

    // 5. residual + LN2 -> o2 (f2; k dead)
    ln_res_kernel<<<NROW, 256, 0, stream>>>(f1, inputs, ln2_scale, ln2_shift, f2);

    // 6. FFN up + relu -> h1 (f4)
    dim3 g2(FFN / BN, NROW / BM);
    gemm_kernel<1><<<g2, 256, 0, stream>>>(f2, W1, b1, nullptr, f4, NROW, FFN, DD);

    // 7. FFN down + bias + o2 -> out
    gemm_kernel<2><<<g1, 256, 0, stream>>>(f4, W2, b2, f2, out, NROW, DD, FFN);
}

// Round 2
// 2032.157 us; speedup vs baseline: 3.0627x; 3.0627x over previous
//
#include <hip/hip_runtime.h>
#include <hip/hip_bf16.h>
#include <math.h>

// Problem constants
#define BB 2
#define SS 2048
#define DD 1024
#define HH 16
#define DH 64
#define NROW (BB*SS)          // 4096
#define FFN (4*DD)            // 4096

// ---------------- LayerNorm (torch semantics: ddof=1, eps on std) -------------
__global__ __launch_bounds__(256)
void ln_kernel(const float* __restrict__ x, const float* __restrict__ scale,
               const float* __restrict__ shift, float* __restrict__ y) {
    int row = blockIdx.x;
    const float* xr = x + (size_t)row * DD;
    float* yr = y + (size_t)row * DD;
    int t = threadIdx.x;
    float v[4];
    float s = 0.f, ss = 0.f;
#pragma unroll
    for (int i = 0; i < 4; ++i) {
        v[i] = xr[t + 256 * i];
        s += v[i];
        ss += v[i] * v[i];
    }
#pragma unroll
    for (int off = 32; off; off >>= 1) {
        s  += __shfl_xor(s, off);
        ss += __shfl_xor(ss, off);
    }
    __shared__ float red[8];
    int w = t >> 6;
    if ((t & 63) == 0) { red[w] = s; red[w + 4] = ss; }
    __syncthreads();
    float st  = red[0] + red[1] + red[2] + red[3];
    float sst = red[4] + red[5] + red[6] + red[7];
    float mu = st * (1.f / DD);
    float var = (sst - DD * mu * mu) * (1.f / (DD - 1));
    var = fmaxf(var, 0.f);
    float inv = 1.f / (sqrtf(var) + 1e-9f);
#pragma unroll
    for (int i = 0; i < 4; ++i) {
        int c = t + 256 * i;
        yr[c] = scale[c] * (v[i] - mu) * inv + shift[c];
    }
}

// LN over (a + b) (residual then LN2)
__global__ __launch_bounds__(256)
void ln_res_kernel(const float* __restrict__ xa, const float* __restrict__ xb,
                   const float* __restrict__ scale, const float* __restrict__ shift,
                   float* __restrict__ y) {
    int row = blockIdx.x;
    const float* ar = xa + (size_t)row * DD;
    const float* br = xb + (size_t)row * DD;
    float* yr = y + (size_t)row * DD;
    int t = threadIdx.x;
    float v[4];
    float s = 0.f, ss = 0.f;
#pragma unroll
    for (int i = 0; i < 4; ++i) {
        int c = t + 256 * i;
        v[i] = ar[c] + br[c];
        s += v[i];
        ss += v[i] * v[i];
    }
#pragma unroll
    for (int off = 32; off; off >>= 1) {
        s  += __shfl_xor(s, off);
        ss += __shfl_xor(ss, off);
    }
    __shared__ float red[8];
    int w = t >> 6;
    if ((t & 63) == 0) { red[w] = s; red[w + 4] = ss; }
    __syncthreads();
    float st  = red[0] + red[1] + red[2] + red[3];
    float sst = red[4] + red[5] + red[6] + red[7];
    float mu = st * (1.f / DD);
    float var = (sst - DD * mu * mu) * (1.f / (DD - 1));
    var = fmaxf(var, 0.f);
    float inv = 1.f / (sqrtf(var) + 1e-9f);
#pragma unroll
    for (int i = 0; i < 4; ++i) {
        int c = t + 256 * i;
        yr[c] = scale[c] * (v[i] - mu) * inv + shift[c];
    }
}

// ---------------- Tiled fp32 GEMM: C = A(MxK) @ W(KxN) + bias [+relu | +add] --
// MODE 0: +bias; 1: +bias,relu; 2: +bias,+addsrc
#define BM 64
#define BN 64
#define BKT 16

template <int MODE>
__global__ __launch_bounds__(256)
void gemm_kernel(const float* __restrict__ A, const float* __restrict__ W,
                 const float* __restrict__ bias, const float* __restrict__ addsrc,
                 float* __restrict__ C, int M, int N, int K) {
    __shared__ float As[BKT][BM];   // transposed A tile
    __shared__ float Bs[BKT][BN];
    int tid = threadIdx.x;
    int tx = tid & 15;          // 0..15  (cols)
    int ty = tid >> 4;          // 0..15  (rows)
    int block_row = blockIdx.y * BM;
    int block_col = blockIdx.x * BN;

    float acc[4][4] = {};

    int a_m = tid >> 2;            // 0..63
    int a_k = (tid & 3) * 4;       // 0,4,8,12
    int b_k = tid >> 4;            // 0..15
    int b_n = (tid & 15) * 4;      // 0..60

    for (int k0 = 0; k0 < K; k0 += BKT) {
        float4 av = *reinterpret_cast<const float4*>(&A[(size_t)(block_row + a_m) * K + k0 + a_k]);
        float4 bv = *reinterpret_cast<const float4*>(&W[(size_t)(k0 + b_k) * N + block_col + b_n]);
        As[a_k + 0][a_m] = av.x;
        As[a_k + 1][a_m] = av.y;
        As[a_k + 2][a_m] = av.z;
        As[a_k + 3][a_m] = av.w;
        *reinterpret_cast<float4*>(&Bs[b_k][b_n]) = bv;
        __syncthreads();
#pragma unroll
        for (int kk = 0; kk < BKT; ++kk) {
            float4 a4 = *reinterpret_cast<const float4*>(&As[kk][ty * 4]);
            float4 b4 = *reinterpret_cast<const float4*>(&Bs[kk][tx * 4]);
            float a[4] = {a4.x, a4.y, a4.z, a4.w};
            float b[4] = {b4.x, b4.y, b4.z, b4.w};
#pragma unroll
            for (int i = 0; i < 4; ++i)
#pragma unroll
                for (int j = 0; j < 4; ++j)
                    acc[i][j] = fmaf(a[i], b[j], acc[i][j]);
        }
        __syncthreads();
    }

#pragma unroll
    for (int i = 0; i < 4; ++i) {
        int r = block_row + ty * 4 + i;
#pragma unroll
        for (int j = 0; j < 4; ++j) {
            int c = block_col + tx * 4 + j;
            float val = acc[i][j] + bias[c];
            if (MODE == 1) val = fmaxf(val, 0.f);
            if (MODE == 2) val += addsrc[(size_t)r * N + c];
            C[(size_t)r * N + c] = val;
        }
    }
}

// ---------------- Tiled causal flash attention ------------------------------
// One block per (b, h, 64-query tile). 256 threads = 16x16 thread grid.
// Thread (ty,tx) owns S/P rows ty*4..+3 x cols tx*4..+3 and O rows ty*4..+3
// x dims tx*4..+3. K staged transposed; P reuses K's LDS.
#define QT 64
#define KT 64
#define LDT 68   // padded leading dim for transposed tiles (16B-aligned rows)

__global__ __launch_bounds__(256)
void attn_tile_kernel(const float* __restrict__ Q, const float* __restrict__ K,
                      const float* __restrict__ V, float* __restrict__ O) {
    __shared__ float Qs[DH][LDT];   // [d][qrow], pre-scaled by 1/8
    __shared__ float Ks[DH][LDT];   // [d][krow]; later reused as Ps[qrow][LDT]
    __shared__ float Vs[KT][DH];    // [krow][d]

    int tid = threadIdx.x;
    int bh = blockIdx.y;
    int b = bh >> 4, h = bh & 15;
    int q0 = blockIdx.x * QT;

    const float* Qbase = Q + ((size_t)(b * SS + q0)) * DD + h * DH;
    const float* Kbase = K + ((size_t)(b * SS)) * DD + h * DH;
    const float* Vbase = V + ((size_t)(b * SS)) * DD + h * DH;

    // stage Q transposed + scaled (once)
    {
        int r = tid >> 4;             // 0..15
        int d0 = (tid & 15) * 4;
#pragma unroll
        for (int p = 0; p < 4; ++p) {
            int rr = r + 16 * p;
            float4 v4 = *reinterpret_cast<const float4*>(&Qbase[(size_t)rr * DD + d0]);
            Qs[d0 + 0][rr] = v4.x * 0.125f;
            Qs[d0 + 1][rr] = v4.y * 0.125f;
            Qs[d0 + 2][rr] = v4.z * 0.125f;
            Qs[d0 + 3][rr] = v4.w * 0.125f;
        }
    }

    int tx = tid & 15, ty = tid >> 4;
    float acc[4][4] = {};
    float m[4] = {-INFINITY, -INFINITY, -INFINITY, -INFINITY};
    float l[4] = {0.f, 0.f, 0.f, 0.f};

    int nt = q0 / KT + 1;
    for (int t = 0; t < nt; ++t) {
        int k0 = t * KT;
        __syncthreads();   // prev PV done with Ks(=Ps)/Vs; Q staged (t=0)
        // stage K transposed + V natural
        {
            int r = tid >> 4;
            int d0 = (tid & 15) * 4;
#pragma unroll
            for (int p = 0; p < 4; ++p) {
                int rr = r + 16 * p;
                float4 kv = *reinterpret_cast<const float4*>(&Kbase[(size_t)(k0 + rr) * DD + d0]);
                Ks[d0 + 0][rr] = kv.x;
                Ks[d0 + 1][rr] = kv.y;
                Ks[d0 + 2][rr] = kv.z;
                Ks[d0 + 3][rr] = kv.w;
                float4 vv = *reinterpret_cast<const float4*>(&Vbase[(size_t)(k0 + rr) * DD + d0]);
                *reinterpret_cast<float4*>(&Vs[rr][d0]) = vv;
            }
        }
        __syncthreads();

        // S tile: s[i][j] = sum_d Qs[d][ty*4+i] * Ks[d][tx*4+j]
        float s[4][4] = {};
#pragma unroll 8
        for (int kk = 0; kk < DH; ++kk) {
            float4 a4 = *reinterpret_cast<const float4*>(&Qs[kk][ty * 4]);
            float4 b4 = *reinterpret_cast<const float4*>(&Ks[kk][tx * 4]);
            float a[4] = {a4.x, a4.y, a4.z, a4.w};
            float b[4] = {b4.x, b4.y, b4.z, b4.w};
#pragma unroll
            for (int i = 0; i < 4; ++i)
#pragma unroll
                for (int j = 0; j < 4; ++j)
                    s[i][j] = fmaf(a[i], b[j], s[i][j]);
        }

        // causal mask on the diagonal tile (k0 == q0 by construction)
        if (k0 == q0) {
#pragma unroll
            for (int i = 0; i < 4; ++i)
#pragma unroll
                for (int j = 0; j < 4; ++j)
                    if (tx * 4 + j > ty * 4 + i) s[i][j] = -INFINITY;
        }

        // online softmax (row stats across the 16 lanes sharing ty)
        float p[4][4];
#pragma unroll
        for (int i = 0; i < 4; ++i) {
            float mx = fmaxf(fmaxf(s[i][0], s[i][1]), fmaxf(s[i][2], s[i][3]));
#pragma unroll
            for (int off = 1; off < 16; off <<= 1) mx = fmaxf(mx, __shfl_xor(mx, off));
            float mn = fmaxf(m[i], mx);
            float corr = __expf(m[i] - mn);
            m[i] = mn;
            float rs = 0.f;
#pragma unroll
            for (int j = 0; j < 4; ++j) { p[i][j] = __expf(s[i][j] - mn); rs += p[i][j]; }
#pragma unroll
            for (int off = 1; off < 16; off <<= 1) rs += __shfl_xor(rs, off);
            l[i] = l[i] * corr + rs;
#pragma unroll
            for (int j = 0; j < 4; ++j) acc[i][j] *= corr;
        }

        __syncthreads();   // all waves done reading Ks before P overwrites it
        float* Ps = &Ks[0][0];
#pragma unroll
        for (int i = 0; i < 4; ++i)
            *reinterpret_cast<float4*>(&Ps[(size_t)(ty * 4 + i) * LDT + tx * 4]) =
                make_float4(p[i][0], p[i][1], p[i][2], p[i][3]);
        __syncthreads();   // P visible

        // PV: acc[i][j] += sum_k P[ty*4+i][k] * V[k][tx*4+j]
#pragma unroll
        for (int kk = 0; kk < KT; kk += 4) {
            float pr[4][4];
#pragma unroll
            for (int i = 0; i < 4; ++i) {
                float4 p4 = *reinterpret_cast<const float4*>(&Ps[(size_t)(ty * 4 + i) * LDT + kk]);
                pr[i][0] = p4.x; pr[i][1] = p4.y; pr[i][2] = p4.z; pr[i][3] = p4.w;
            }
#pragma unroll
            for (int jj = 0; jj < 4; ++jj) {
                float4 v4 = *reinterpret_cast<const float4*>(&Vs[kk + jj][tx * 4]);
                float vv[4] = {v4.x, v4.y, v4.z, v4.w};
#pragma unroll
                for (int i = 0; i < 4; ++i)
#pragma unroll
                    for (int j = 0; j < 4; ++j)
                        acc[i][j] = fmaf(pr[i][jj], vv[j], acc[i][j]);
            }
        }
    }

    // epilogue
    float* Op = O + ((size_t)(b * SS + q0)) * DD + h * DH;
#pragma unroll
    for (int i = 0; i < 4; ++i) {
        float inv = 1.f / l[i];
        int row = ty * 4 + i;
        float4 o4 = make_float4(acc[i][0] * inv, acc[i][1] * inv,
                                acc[i][2] * inv, acc[i][3] * inv);
        *reinterpret_cast<float4*>(&Op[(size_t)row * DD + tx * 4]) = o4;
    }
}

// ---------------- Launch ------------------------------------------------------
extern "C" void kernel_launch(void* const* d_in, const int* in_sizes, int n_in,
                              void* d_out, int out_size, void* d_ws, size_t ws_size,
                              hipStream_t stream) {
    const float* inputs    = (const float*)d_in[0];
    const float* ln1_scale = (const float*)d_in[1];
    const float* ln1_shift = (const float*)d_in[2];
    const float* Wq = (const float*)d_in[3];
    const float* bq = (const float*)d_in[4];
    const float* Wk = (const float*)d_in[5];
    const float* bk = (const float*)d_in[6];
    const float* Wv = (const float*)d_in[7];
    const float* bv = (const float*)d_in[8];
    const float* Wo = (const float*)d_in[9];
    const float* bo = (const float*)d_in[10];
    const float* W1 = (const float*)d_in[11];
    const float* b1 = (const float*)d_in[12];
    const float* W2 = (const float*)d_in[13];
    const float* b2 = (const float*)d_in[14];
    const float* ln2_scale = (const float*)d_in[15];
    const float* ln2_shift = (const float*)d_in[16];
    float* out = (float*)d_out;

    const size_t SZ = (size_t)NROW * DD;   // 4M floats
    float* f0 = (float*)d_ws;              // xn, later attn_out
    float* f1 = f0 + SZ;                   // q, later proj
    float* f2 = f1 + SZ;                   // k, later o2
    float* f3 = f2 + SZ;                   // v
    float* f4 = f3 + SZ;                   // h1 (4096x4096)

    // 1. LN1
    ln_kernel<<<NROW, 256, 0, stream>>>(inputs, ln1_scale, ln1_shift, f0);

    // 2. QKV projections
    dim3 g1(DD / BN, NROW / BM);
    gemm_kernel<0><<<g1, 256, 0, stream>>>(f0, Wq, bq, nullptr, f1, NROW, DD, DD);
    gemm_kernel<0><<<g1, 256, 0, stream>>>(f0, Wk, bk, nullptr, f2, NROW, DD, DD);
    gemm_kernel<0><<<g1, 256, 0, stream>>>(f0, Wv, bv, nullptr, f3, NROW, DD, DD);

    // 3. Attention (writes f0; xn is dead)
    dim3 ga(SS / QT, BB * HH);
    attn_tile_kernel<<<ga, 256, 0, stream>>>(f1, f2, f3, f0);

    // 4. Output projection (writes f1; q dead)
    gemm_kernel<0><<<g1, 256, 0, stream>>>(f0, Wo, bo, nullptr, f1, NROW, DD, DD);

    // 5. residual + LN2 -> o2 (f2; k dead)
    ln_res_kernel<<<NROW, 256, 0, stream>>>(f1, inputs, ln2_scale, ln2_shift, f2);

    // 6. FFN up + relu -> h1 (f4)
    dim3 g2(FFN / BN, NROW / BM);
    gemm_kernel<1><<<g2, 256, 0, stream>>>(f2, W1, b1, nullptr, f4, NROW, FFN, DD);

    // 7. FFN down + bias + o2 -> out
    gemm_kernel<2><<<g1, 256, 0, stream>>>(f4, W2, b2, f2, out, NROW, DD, FFN);
}

// Round 3
// 917.334 us; speedup vs baseline: 6.7847x; 2.2153x over previous
//
#include <hip/hip_runtime.h>
#include <hip/hip_bf16.h>
#include <math.h>

// Problem constants
#define BB 2
#define SS 2048
#define DD 1024
#define HH 16
#define DH 64
#define NROW (BB*SS)          // 4096
#define FFN (4*DD)            // 4096

typedef __attribute__((ext_vector_type(8))) __bf16 bf16x8;
typedef __attribute__((ext_vector_type(4))) float f32x4;

__device__ __forceinline__ ushort f2b(float f) {
    union { float f; uint32_t u; } x; x.f = f;
    uint32_t r = x.u + 0x7FFF + ((x.u >> 16) & 1);
    return (ushort)(r >> 16);
}

// ---------------- LayerNorm (torch semantics: ddof=1, eps on std) -> bf16 ----
__global__ __launch_bounds__(256)
void ln_kernel(const float* __restrict__ x, const float* __restrict__ scale,
               const float* __restrict__ shift, ushort* __restrict__ y) {
    int row = blockIdx.x;
    const float* xr = x + (size_t)row * DD;
    ushort* yr = y + (size_t)row * DD;
    int t = threadIdx.x;
    float v[4];
    float s = 0.f, ss = 0.f;
#pragma unroll
    for (int i = 0; i < 4; ++i) {
        v[i] = xr[t + 256 * i];
        s += v[i];
        ss += v[i] * v[i];
    }
#pragma unroll
    for (int off = 32; off; off >>= 1) {
        s  += __shfl_xor(s, off);
        ss += __shfl_xor(ss, off);
    }
    __shared__ float red[8];
    int w = t >> 6;
    if ((t & 63) == 0) { red[w] = s; red[w + 4] = ss; }
    __syncthreads();
    float st  = red[0] + red[1] + red[2] + red[3];
    float sst = red[4] + red[5] + red[6] + red[7];
    float mu = st * (1.f / DD);
    float var = (sst - DD * mu * mu) * (1.f / (DD - 1));
    var = fmaxf(var, 0.f);
    float inv = 1.f / (sqrtf(var) + 1e-9f);
#pragma unroll
    for (int i = 0; i < 4; ++i) {
        int c = t + 256 * i;
        yr[c] = f2b(scale[c] * (v[i] - mu) * inv + shift[c]);
    }
}

// LN over (a + b): writes bf16 (for FFN GEMM) and fp32 (for final residual)
__global__ __launch_bounds__(256)
void ln_res_kernel(const float* __restrict__ xa, const float* __restrict__ xb,
                   const float* __restrict__ scale, const float* __restrict__ shift,
                   ushort* __restrict__ yb, float* __restrict__ yf) {
    int row = blockIdx.x;
    const float* ar = xa + (size_t)row * DD;
    const float* br = xb + (size_t)row * DD;
    ushort* ybr = yb + (size_t)row * DD;
    float* yfr = yf + (size_t)row * DD;
    int t = threadIdx.x;
    float v[4];
    float s = 0.f, ss = 0.f;
#pragma unroll
    for (int i = 0; i < 4; ++i) {
        int c = t + 256 * i;
        v[i] = ar[c] + br[c];
        s += v[i];
        ss += v[i] * v[i];
    }
#pragma unroll
    for (int off = 32; off; off >>= 1) {
        s  += __shfl_xor(s, off);
        ss += __shfl_xor(ss, off);
    }
    __shared__ float red[8];
    int w = t >> 6;
    if ((t & 63) == 0) { red[w] = s; red[w + 4] = ss; }
    __syncthreads();
    float st  = red[0] + red[1] + red[2] + red[3];
    float sst = red[4] + red[5] + red[6] + red[7];
    float mu = st * (1.f / DD);
    float var = (sst - DD * mu * mu) * (1.f / (DD - 1));
    var = fmaxf(var, 0.f);
    float inv = 1.f / (sqrtf(var) + 1e-9f);
#pragma unroll
    for (int i = 0; i < 4; ++i) {
        int c = t + 256 * i;
        float o = scale[c] * (v[i] - mu) * inv + shift[c];
        ybr[c] = f2b(o);
        yfr[c] = o;
    }
}

// ---------------- fp32 -> bf16 transpose-convert for weights -----------------
// W: K x N (fp32, row-major) -> Wt: N x K (bf16, row-major)
__global__ __launch_bounds__(256)
void transpose_bf16_kernel(const float* __restrict__ W, ushort* __restrict__ Wt,
                           int K, int N) {
    __shared__ ushort tile[32][33];
    int tx = threadIdx.x & 31;
    int ty = threadIdx.x >> 5;      // 0..7
    int n0 = blockIdx.x * 32;
    int k0 = blockIdx.y * 32;
#pragma unroll
    for (int i = 0; i < 32; i += 8)
        tile[ty + i][tx] = f2b(W[(size_t)(k0 + ty + i) * N + n0 + tx]);
    __syncthreads();
#pragma unroll
    for (int i = 0; i < 32; i += 8)
        Wt[(size_t)(n0 + ty + i) * K + k0 + tx] = tile[tx][ty + i];
}

// elementwise fp32 -> bf16
__global__ __launch_bounds__(256)
void cvt_bf16_kernel(const float* __restrict__ in, ushort* __restrict__ out) {
    int i = blockIdx.x * 256 + threadIdx.x;
    float4 v = reinterpret_cast<const float4*>(in)[i];
    ushort4 o;
    o.x = f2b(v.x); o.y = f2b(v.y); o.z = f2b(v.z); o.w = f2b(v.w);
    reinterpret_cast<ushort4*>(out)[i] = o;
}

// ---------------- bf16 MFMA GEMM: C = A(MxK) @ Wt(NxK)^T + bias --------------
// 128x128 tile, BK=32, 4 waves in 2x2, each wave 64x64 = 4x4 mfma 16x16x32.
// MODE 0: +bias; 1: +bias,relu; 2: +bias,+addsrc(fp32)
// BF16_OUT: write bf16 (ushort) else fp32.
#define GBM 128
#define GBN 128
#define GBK 32

template <int MODE, bool BF16_OUT>
__global__ __launch_bounds__(256)
void gemm_bf16_kernel(const ushort* __restrict__ A, const ushort* __restrict__ Wt,
                      const float* __restrict__ bias, const float* __restrict__ addsrc,
                      void* __restrict__ Cout, int M, int N, int K) {
    __shared__ ushort As[GBM * GBK];   // [row][k] 64B rows, XOR-swizzled granules
    __shared__ ushort Bs[GBN * GBK];

    int tid = threadIdx.x;
    int lane = tid & 63;
    int wid = tid >> 6;          // 0..3
    int wr = wid >> 1, wc = wid & 1;
    int brow = blockIdx.y * GBM;
    int bcol = blockIdx.x * GBN;

    int lrow = lane & 15;        // fragment row/col
    int kgrp = lane >> 4;        // 0..3 (16B granule in K)

    f32x4 acc[4][4] = {};

    // staging address precompute: wave w loads rows [w*32, w*32+32) of each tile
    int srow_base = wid * 32;               // + i*16 + lane/4
    int sgran = lane & 3;

    for (int k0 = 0; k0 < K; k0 += GBK) {
#pragma unroll
        for (int i = 0; i < 2; ++i) {
            int row = srow_base + i * 16 + (lane >> 2);
            int gran = sgran ^ ((row >> 1) & 3);
            const char* ga = (const char*)A +
                ((size_t)(brow + row) * K + k0) * 2 + gran * 16;
            __builtin_amdgcn_global_load_lds(
                (const __attribute__((address_space(1))) uint32_t*)ga,
                (__attribute__((address_space(3))) uint32_t*)(As + (srow_base + i * 16) * GBK),
                16, 0, 0);
            const char* gb = (const char*)Wt +
                ((size_t)(bcol + row) * K + k0) * 2 + gran * 16;
            __builtin_amdgcn_global_load_lds(
                (const __attribute__((address_space(1))) uint32_t*)gb,
                (__attribute__((address_space(3))) uint32_t*)(Bs + (srow_base + i * 16) * GBK),
                16, 0, 0);
        }
        __syncthreads();   // drain vmcnt + make tile visible

        bf16x8 afrag[4], bfrag[4];
#pragma unroll
        for (int mi = 0; mi < 4; ++mi) {
            int row = wr * 64 + mi * 16 + lrow;
            int gran = kgrp ^ ((row >> 1) & 3);
            afrag[mi] = *(const bf16x8*)((const char*)As + row * 64 + gran * 16);
        }
#pragma unroll
        for (int ni = 0; ni < 4; ++ni) {
            int row = wc * 64 + ni * 16 + lrow;
            int gran = kgrp ^ ((row >> 1) & 3);
            bfrag[ni] = *(const bf16x8*)((const char*)Bs + row * 64 + gran * 16);
        }
#pragma unroll
        for (int mi = 0; mi < 4; ++mi)
#pragma unroll
            for (int ni = 0; ni < 4; ++ni)
                acc[mi][ni] = __builtin_amdgcn_mfma_f32_16x16x32_bf16(
                    afrag[mi], bfrag[ni], acc[mi][ni], 0, 0, 0);
        __syncthreads();   // all reads done before next stage
    }

    // epilogue: C/D layout col=lane&15, row=(lane>>4)*4+j
#pragma unroll
    for (int ni = 0; ni < 4; ++ni) {
        int col = bcol + wc * 64 + ni * 16 + lrow;
        float bsv = bias[col];
#pragma unroll
        for (int mi = 0; mi < 4; ++mi) {
            f32x4 a = acc[mi][ni];
#pragma unroll
            for (int j = 0; j < 4; ++j) {
                int row = brow + wr * 64 + mi * 16 + kgrp * 4 + j;
                float val = a[j] + bsv;
                if (MODE == 1) val = fmaxf(val, 0.f);
                if (MODE == 2) val += addsrc[(size_t)row * N + col];
                if (BF16_OUT)
                    ((ushort*)Cout)[(size_t)row * N + col] = f2b(val);
                else
                    ((float*)Cout)[(size_t)row * N + col] = val;
            }
        }
    }
}

// ---------------- Tiled causal flash attention (fp32, unchanged) -------------
#define QT 64
#define KT 64
#define LDT 68

__global__ __launch_bounds__(256)
void attn_tile_kernel(const float* __restrict__ Q, const float* __restrict__ K,
                      const float* __restrict__ V, float* __restrict__ O) {
    __shared__ float Qs[DH][LDT];
    __shared__ float Ks[DH][LDT];
    __shared__ float Vs[KT][DH];

    int tid = threadIdx.x;
    int bh = blockIdx.y;
    int b = bh >> 4, h = bh & 15;
    int q0 = blockIdx.x * QT;

    const float* Qbase = Q + ((size_t)(b * SS + q0)) * DD + h * DH;
    const float* Kbase = K + ((size_t)(b * SS)) * DD + h * DH;
    const float* Vbase = V + ((size_t)(b * SS)) * DD + h * DH;

    {
        int r = tid >> 4;
        int d0 = (tid & 15) * 4;
#pragma unroll
        for (int p = 0; p < 4; ++p) {
            int rr = r + 16 * p;
            float4 v4 = *reinterpret_cast<const float4*>(&Qbase[(size_t)rr * DD + d0]);
            Qs[d0 + 0][rr] = v4.x * 0.125f;
            Qs[d0 + 1][rr] = v4.y * 0.125f;
            Qs[d0 + 2][rr] = v4.z * 0.125f;
            Qs[d0 + 3][rr] = v4.w * 0.125f;
        }
    }

    int tx = tid & 15, ty = tid >> 4;
    float acc[4][4] = {};
    float m[4] = {-INFINITY, -INFINITY, -INFINITY, -INFINITY};
    float l[4] = {0.f, 0.f, 0.f, 0.f};

    int nt = q0 / KT + 1;
    for (int t = 0; t < nt; ++t) {
        int k0 = t * KT;
        __syncthreads();
        {
            int r = tid >> 4;
            int d0 = (tid & 15) * 4;
#pragma unroll
            for (int p = 0; p < 4; ++p) {
                int rr = r + 16 * p;
                float4 kv = *reinterpret_cast<const float4*>(&Kbase[(size_t)(k0 + rr) * DD + d0]);
                Ks[d0 + 0][rr] = kv.x;
                Ks[d0 + 1][rr] = kv.y;
                Ks[d0 + 2][rr] = kv.z;
                Ks[d0 + 3][rr] = kv.w;
                float4 vv = *reinterpret_cast<const float4*>(&Vbase[(size_t)(k0 + rr) * DD + d0]);
                *reinterpret_cast<float4*>(&Vs[rr][d0]) = vv;
            }
        }
        __syncthreads();

        float s[4][4] = {};
#pragma unroll 8
        for (int kk = 0; kk < DH; ++kk) {
            float4 a4 = *reinterpret_cast<const float4*>(&Qs[kk][ty * 4]);
            float4 b4 = *reinterpret_cast<const float4*>(&Ks[kk][tx * 4]);
            float a[4] = {a4.x, a4.y, a4.z, a4.w};
            float b[4] = {b4.x, b4.y, b4.z, b4.w};
#pragma unroll
            for (int i = 0; i < 4; ++i)
#pragma unroll
                for (int j = 0; j < 4; ++j)
                    s[i][j] = fmaf(a[i], b[j], s[i][j]);
        }

        if (k0 == q0) {
#pragma unroll
            for (int i = 0; i < 4; ++i)
#pragma unroll
                for (int j = 0; j < 4; ++j)
                    if (tx * 4 + j > ty * 4 + i) s[i][j] = -INFINITY;
        }

        float p[4][4];
#pragma unroll
        for (int i = 0; i < 4; ++i) {
            float mx = fmaxf(fmaxf(s[i][0], s[i][1]), fmaxf(s[i][2], s[i][3]));
#pragma unroll
            for (int off = 1; off < 16; off <<= 1) mx = fmaxf(mx, __shfl_xor(mx, off));
            float mn = fmaxf(m[i], mx);
            float corr = __expf(m[i] - mn);
            m[i] = mn;
            float rs = 0.f;
#pragma unroll
            for (int j = 0; j < 4; ++j) { p[i][j] = __expf(s[i][j] - mn); rs += p[i][j]; }
#pragma unroll
            for (int off = 1; off < 16; off <<= 1) rs += __shfl_xor(rs, off);
            l[i] = l[i] * corr + rs;
#pragma unroll
            for (int j = 0; j < 4; ++j) acc[i][j] *= corr;
        }

        __syncthreads();
        float* Ps = &Ks[0][0];
#pragma unroll
        for (int i = 0; i < 4; ++i)
            *reinterpret_cast<float4*>(&Ps[(size_t)(ty * 4 + i) * LDT + tx * 4]) =
                make_float4(p[i][0], p[i][1], p[i][2], p[i][3]);
        __syncthreads();

#pragma unroll
        for (int kk = 0; kk < KT; kk += 4) {
            float pr[4][4];
#pragma unroll
            for (int i = 0; i < 4; ++i) {
                float4 p4 = *reinterpret_cast<const float4*>(&Ps[(size_t)(ty * 4 + i) * LDT + kk]);
                pr[i][0] = p4.x; pr[i][1] = p4.y; pr[i][2] = p4.z; pr[i][3] = p4.w;
            }
#pragma unroll
            for (int jj = 0; jj < 4; ++jj) {
                float4 v4 = *reinterpret_cast<const float4*>(&Vs[kk + jj][tx * 4]);
                float vv[4] = {v4.x, v4.y, v4.z, v4.w};
#pragma unroll
                for (int i = 0; i < 4; ++i)
#pragma unroll
                    for (int j = 0; j < 4; ++j)
                        acc[i][j] = fmaf(pr[i][jj], vv[j], acc[i][j]);
            }
        }
    }

    float* Op = O + ((size_t)(b * SS + q0)) * DD + h * DH;
#pragma unroll
    for (int i = 0; i < 4; ++i) {
        float inv = 1.f / l[i];
        int row = ty * 4 + i;
        float4 o4 = make_float4(acc[i][0] * inv, acc[i][1] * inv,
                                acc[i][2] * inv, acc[i][3] * inv);
        *reinterpret_cast<float4*>(&Op[(size_t)row * DD + tx * 4]) = o4;
    }
}

// ---------------- Launch ------------------------------------------------------
extern "C" void kernel_launch(void* const* d_in, const int* in_sizes, int n_in,
                              void* d_out, int out_size, void* d_ws, size_t ws_size,
                              hipStream_t stream) {
    const float* inputs    = (const float*)d_in[0];
    const float* ln1_scale = (const float*)d_in[1];
    const float* ln1_shift = (const float*)d_in[2];
    const float* Wq = (const float*)d_in[3];
    const float* bq = (const float*)d_in[4];
    const float* Wk = (const float*)d_in[5];
    const float* bk = (const float*)d_in[6];
    const float* Wv = (const float*)d_in[7];
    const float* bv = (const float*)d_in[8];
    const float* Wo = (const float*)d_in[9];
    const float* bo = (const float*)d_in[10];
    const float* W1 = (const float*)d_in[11];
    const float* b1 = (const float*)d_in[12];
    const float* W2 = (const float*)d_in[13];
    const float* b2 = (const float*)d_in[14];
    const float* ln2_scale = (const float*)d_in[15];
    const float* ln2_shift = (const float*)d_in[16];
    float* out = (float*)d_out;

    const size_t MB = 1024 * 1024;
    char* w = (char*)d_ws;
    float*  q_f   = (float*)(w + 0 * MB);      // R0 16MB
    float*  k_f   = (float*)(w + 16 * MB);     // R1 16MB
    float*  v_f   = (float*)(w + 32 * MB);     // R2 16MB
    float*  att_f = (float*)(w + 48 * MB);     // R3 16MB
    ushort* h1_b  = (ushort*)(w + 64 * MB);    // R4 32MB
    ushort* wq_t  = (ushort*)(w + 96 * MB);    // 2MB
    ushort* wk_t  = (ushort*)(w + 98 * MB);
    ushort* wv_t  = (ushort*)(w + 100 * MB);
    ushort* wo_t  = (ushort*)(w + 102 * MB);
    ushort* w1_t  = (ushort*)(w + 104 * MB);   // 8MB
    ushort* w2_t  = (ushort*)(w + 112 * MB);   // 8MB
    ushort* xn_b  = (ushort*)(w + 120 * MB);   // 8MB
    // reuse after attention:
    ushort* att_b = (ushort*)(w + 0 * MB);     // R0 (q dead)
    float*  proj  = (float*)(w + 32 * MB);     // R2 (v dead)
    ushort* o2_b  = (ushort*)(w + 16 * MB);    // R1 (k dead)
    float*  o2_f  = (float*)(w + 48 * MB);     // R3 (att_f dead)

    // 0. weight convert+transpose (K x N fp32 -> N x K bf16)
    transpose_bf16_kernel<<<dim3(DD / 32, DD / 32), 256, 0, stream>>>(Wq, wq_t, DD, DD);
    transpose_bf16_kernel<<<dim3(DD / 32, DD / 32), 256, 0, stream>>>(Wk, wk_t, DD, DD);
    transpose_bf16_kernel<<<dim3(DD / 32, DD / 32), 256, 0, stream>>>(Wv, wv_t, DD, DD);
    transpose_bf16_kernel<<<dim3(DD / 32, DD / 32), 256, 0, stream>>>(Wo, wo_t, DD, DD);
    transpose_bf16_kernel<<<dim3(FFN / 32, DD / 32), 256, 0, stream>>>(W1, w1_t, DD, FFN);
    transpose_bf16_kernel<<<dim3(DD / 32, FFN / 32), 256, 0, stream>>>(W2, w2_t, FFN, DD);

    // 1. LN1 -> bf16
    ln_kernel<<<NROW, 256, 0, stream>>>(inputs, ln1_scale, ln1_shift, xn_b);

    // 2. QKV projections (bf16 MFMA, fp32 out for fp32 attention)
    dim3 g1(DD / GBN, NROW / GBM);    // 8 x 32
    gemm_bf16_kernel<0, false><<<g1, 256, 0, stream>>>(xn_b, wq_t, bq, nullptr, q_f, NROW, DD, DD);
    gemm_bf16_kernel<0, false><<<g1, 256, 0, stream>>>(xn_b, wk_t, bk, nullptr, k_f, NROW, DD, DD);
    gemm_bf16_kernel<0, false><<<g1, 256, 0, stream>>>(xn_b, wv_t, bv, nullptr, v_f, NROW, DD, DD);

    // 3. Attention (fp32) -> att_f
    dim3 ga(SS / QT, BB * HH);
    attn_tile_kernel<<<ga, 256, 0, stream>>>(q_f, k_f, v_f, att_f);

    // 4. attn out -> bf16
    cvt_bf16_kernel<<<(NROW * DD / 4) / 256, 256, 0, stream>>>(att_f, att_b);

    // 5. Output projection -> proj (fp32)
    gemm_bf16_kernel<0, false><<<g1, 256, 0, stream>>>(att_b, wo_t, bo, nullptr, proj, NROW, DD, DD);

    // 6. residual + LN2 -> o2 (bf16 + fp32)
    ln_res_kernel<<<NROW, 256, 0, stream>>>(proj, inputs, ln2_scale, ln2_shift, o2_b, o2_f);

    // 7. FFN up + relu -> h1 (bf16)
    dim3 g2(FFN / GBN, NROW / GBM);   // 32 x 32
    gemm_bf16_kernel<1, true><<<g2, 256, 0, stream>>>(o2_b, w1_t, b1, nullptr, h1_b, NROW, FFN, DD);

    // 8. FFN down + bias + o2 -> out (fp32)
    gemm_bf16_kernel<2, false><<<g1, 256, 0, stream>>>(h1_b, w2_t, b2, o2_f, out, NROW, DD, FFN);
}

// Round 4
// 402.965 us; speedup vs baseline: 15.4451x; 2.2765x over previous
//
#include <hip/hip_runtime.h>
#include <hip/hip_bf16.h>
#include <math.h>

// Problem constants
#define BB 2
#define SS 2048
#define DD 1024
#define HH 16
#define DH 64
#define NROW (BB*SS)          // 4096
#define FFN (4*DD)            // 4096

typedef __attribute__((ext_vector_type(8))) __bf16 bf16x8;
typedef __attribute__((ext_vector_type(4))) float f32x4;

__device__ __forceinline__ ushort f2b(float f) {
    union { float f; uint32_t u; } x; x.f = f;
    uint32_t r = x.u + 0x7FFF + ((x.u >> 16) & 1);
    return (ushort)(r >> 16);
}

// ---------------- LayerNorm (torch semantics: ddof=1, eps on std) -> bf16 ----
__global__ __launch_bounds__(256)
void ln_kernel(const float* __restrict__ x, const float* __restrict__ scale,
               const float* __restrict__ shift, ushort* __restrict__ y) {
    int row = blockIdx.x;
    const float* xr = x + (size_t)row * DD;
    ushort* yr = y + (size_t)row * DD;
    int t = threadIdx.x;
    float v[4];
    float s = 0.f, ss = 0.f;
#pragma unroll
    for (int i = 0; i < 4; ++i) {
        v[i] = xr[t + 256 * i];
        s += v[i];
        ss += v[i] * v[i];
    }
#pragma unroll
    for (int off = 32; off; off >>= 1) {
        s  += __shfl_xor(s, off);
        ss += __shfl_xor(ss, off);
    }
    __shared__ float red[8];
    int w = t >> 6;
    if ((t & 63) == 0) { red[w] = s; red[w + 4] = ss; }
    __syncthreads();
    float st  = red[0] + red[1] + red[2] + red[3];
    float sst = red[4] + red[5] + red[6] + red[7];
    float mu = st * (1.f / DD);
    float var = (sst - DD * mu * mu) * (1.f / (DD - 1));
    var = fmaxf(var, 0.f);
    float inv = 1.f / (sqrtf(var) + 1e-9f);
#pragma unroll
    for (int i = 0; i < 4; ++i) {
        int c = t + 256 * i;
        yr[c] = f2b(scale[c] * (v[i] - mu) * inv + shift[c]);
    }
}

// LN over (a + b): writes bf16 (for FFN GEMM) and fp32 (for final residual)
__global__ __launch_bounds__(256)
void ln_res_kernel(const float* __restrict__ xa, const float* __restrict__ xb,
                   const float* __restrict__ scale, const float* __restrict__ shift,
                   ushort* __restrict__ yb, float* __restrict__ yf) {
    int row = blockIdx.x;
    const float* ar = xa + (size_t)row * DD;
    const float* br = xb + (size_t)row * DD;
    ushort* ybr = yb + (size_t)row * DD;
    float* yfr = yf + (size_t)row * DD;
    int t = threadIdx.x;
    float v[4];
    float s = 0.f, ss = 0.f;
#pragma unroll
    for (int i = 0; i < 4; ++i) {
        int c = t + 256 * i;
        v[i] = ar[c] + br[c];
        s += v[i];
        ss += v[i] * v[i];
    }
#pragma unroll
    for (int off = 32; off; off >>= 1) {
        s  += __shfl_xor(s, off);
        ss += __shfl_xor(ss, off);
    }
    __shared__ float red[8];
    int w = t >> 6;
    if ((t & 63) == 0) { red[w] = s; red[w + 4] = ss; }
    __syncthreads();
    float st  = red[0] + red[1] + red[2] + red[3];
    float sst = red[4] + red[5] + red[6] + red[7];
    float mu = st * (1.f / DD);
    float var = (sst - DD * mu * mu) * (1.f / (DD - 1));
    var = fmaxf(var, 0.f);
    float inv = 1.f / (sqrtf(var) + 1e-9f);
#pragma unroll
    for (int i = 0; i < 4; ++i) {
        int c = t + 256 * i;
        float o = scale[c] * (v[i] - mu) * inv + shift[c];
        ybr[c] = f2b(o);
        yfr[c] = o;
    }
}

// ---------------- fp32 -> bf16 transpose-convert for weights -----------------
__global__ __launch_bounds__(256)
void transpose_bf16_kernel(const float* __restrict__ W, ushort* __restrict__ Wt,
                           int K, int N) {
    __shared__ ushort tile[32][33];
    int tx = threadIdx.x & 31;
    int ty = threadIdx.x >> 5;      // 0..7
    int n0 = blockIdx.x * 32;
    int k0 = blockIdx.y * 32;
#pragma unroll
    for (int i = 0; i < 32; i += 8)
        tile[ty + i][tx] = f2b(W[(size_t)(k0 + ty + i) * N + n0 + tx]);
    __syncthreads();
#pragma unroll
    for (int i = 0; i < 32; i += 8)
        Wt[(size_t)(n0 + ty + i) * K + k0 + tx] = tile[tx][ty + i];
}

// ---------------- bf16 MFMA GEMM: C = A(MxK) @ Wt(NxK)^T + bias --------------
// MODE 0: +bias; 1: +bias,relu; 2: +bias,+addsrc(fp32)
// BF16_OUT: write bf16. VTRANS: write V transposed per head [(b*16+h)*64+d][s]
#define GBM 128
#define GBN 128
#define GBK 32

template <int MODE, bool BF16_OUT, bool VTRANS>
__global__ __launch_bounds__(256)
void gemm_bf16_kernel(const ushort* __restrict__ A, const ushort* __restrict__ Wt,
                      const float* __restrict__ bias, const float* __restrict__ addsrc,
                      void* __restrict__ Cout, int M, int N, int K) {
    __shared__ ushort As[GBM * GBK];
    __shared__ ushort Bs[GBN * GBK];

    int tid = threadIdx.x;
    int lane = tid & 63;
    int wid = tid >> 6;
    int wr = wid >> 1, wc = wid & 1;
    int brow = blockIdx.y * GBM;
    int bcol = blockIdx.x * GBN;

    int lrow = lane & 15;
    int kgrp = lane >> 4;

    f32x4 acc[4][4] = {};

    int srow_base = wid * 32;
    int sgran = lane & 3;

    for (int k0 = 0; k0 < K; k0 += GBK) {
#pragma unroll
        for (int i = 0; i < 2; ++i) {
            int row = srow_base + i * 16 + (lane >> 2);
            int gran = sgran ^ ((row >> 1) & 3);
            const char* ga = (const char*)A +
                ((size_t)(brow + row) * K + k0) * 2 + gran * 16;
            __builtin_amdgcn_global_load_lds(
                (const __attribute__((address_space(1))) uint32_t*)ga,
                (__attribute__((address_space(3))) uint32_t*)(As + (srow_base + i * 16) * GBK),
                16, 0, 0);
            const char* gb = (const char*)Wt +
                ((size_t)(bcol + row) * K + k0) * 2 + gran * 16;
            __builtin_amdgcn_global_load_lds(
                (const __attribute__((address_space(1))) uint32_t*)gb,
                (__attribute__((address_space(3))) uint32_t*)(Bs + (srow_base + i * 16) * GBK),
                16, 0, 0);
        }
        __syncthreads();

        bf16x8 afrag[4], bfrag[4];
#pragma unroll
        for (int mi = 0; mi < 4; ++mi) {
            int row = wr * 64 + mi * 16 + lrow;
            int gran = kgrp ^ ((row >> 1) & 3);
            afrag[mi] = *(const bf16x8*)((const char*)As + row * 64 + gran * 16);
        }
#pragma unroll
        for (int ni = 0; ni < 4; ++ni) {
            int row = wc * 64 + ni * 16 + lrow;
            int gran = kgrp ^ ((row >> 1) & 3);
            bfrag[ni] = *(const bf16x8*)((const char*)Bs + row * 64 + gran * 16);
        }
#pragma unroll
        for (int mi = 0; mi < 4; ++mi)
#pragma unroll
            for (int ni = 0; ni < 4; ++ni)
                acc[mi][ni] = __builtin_amdgcn_mfma_f32_16x16x32_bf16(
                    afrag[mi], bfrag[ni], acc[mi][ni], 0, 0, 0);
        __syncthreads();
    }

#pragma unroll
    for (int ni = 0; ni < 4; ++ni) {
        int col = bcol + wc * 64 + ni * 16 + lrow;
        float bsv = bias[col];
#pragma unroll
        for (int mi = 0; mi < 4; ++mi) {
            f32x4 a = acc[mi][ni];
#pragma unroll
            for (int j = 0; j < 4; ++j) {
                int row = brow + wr * 64 + mi * 16 + kgrp * 4 + j;
                float val = a[j] + bsv;
                if (MODE == 1) val = fmaxf(val, 0.f);
                if (MODE == 2) val += addsrc[(size_t)row * N + col];
                if (VTRANS) {
                    // [(b*16+h)*64+d][s] == [col][s] per batch
                    size_t idx = (size_t)(row >> 11) * ((size_t)DD * SS)
                               + (size_t)col * SS + (row & (SS - 1));
                    ((ushort*)Cout)[idx] = f2b(val);
                } else if (BF16_OUT) {
                    ((ushort*)Cout)[(size_t)row * N + col] = f2b(val);
                } else {
                    ((float*)Cout)[(size_t)row * N + col] = val;
                }
            }
        }
    }
}

// ---------------- bf16 MFMA causal flash attention ---------------------------
// Block: 256 threads (4 waves) per (b, h, 64-query tile). Wave w owns q rows
// [w*16, w*16+16). K-tile/Vt-tile (64x64 bf16) staged via global_load_lds with
// XOR-swizzle (granule ^= row&7 on 128B rows); P is wave-private in LDS.
__global__ __launch_bounds__(256)
void attn_mfma_kernel(const ushort* __restrict__ Qg, const ushort* __restrict__ Kg,
                      const ushort* __restrict__ Vtg, ushort* __restrict__ Og) {
    __shared__ ushort Qs[64 * 64];   // [qrow][d]   8KB
    __shared__ ushort Ks[64 * 64];   // [key][d]    8KB
    __shared__ ushort Vs[64 * 64];   // [d][key]    8KB
    __shared__ ushort Ps[64 * 64];   // [qrow][key] 8KB (wave-private 16-row slabs)

    int tid = threadIdx.x;
    int lane = tid & 63;
    int wid = tid >> 6;
    int bh = blockIdx.y;
    int b = bh >> 4, h = bh & 15;
    int q0 = ((int)gridDim.x - 1 - (int)blockIdx.x) * 64;   // heavy tiles first

    const ushort* Qbase = Qg + ((size_t)(b * SS + q0)) * DD + h * DH;
    const ushort* Kbase = Kg + ((size_t)(b * SS)) * DD + h * DH;
    const ushort* Vbase = Vtg + (size_t)bh * DH * SS;        // rows: d, stride SS

    // ---- stage Q once (wave w: rows w*16..+15; 2 instrs of 8 rows) ----
    {
        int r0 = wid * 16;
        int rr0 = r0 + (lane >> 3);
        int g0 = lane & 7;
#pragma unroll
        for (int i = 0; i < 2; ++i) {
            int rr = rr0 + i * 8;
            int g = g0 ^ (rr & 7);
            const ushort* src = Qbase + (size_t)rr * DD + g * 8;
            __builtin_amdgcn_global_load_lds(
                (const __attribute__((address_space(1))) uint32_t*)src,
                (__attribute__((address_space(3))) uint32_t*)(Qs + (r0 + i * 8) * 64),
                16, 0, 0);
        }
    }
    __syncthreads();   // Q visible (vmcnt drained)

    // ---- hoist Q A-fragments (row = wid*16 + lane&15, k = (lane>>4)*8..) ----
    bf16x8 aq[2];
    {
        int r = wid * 16 + (lane & 15);
#pragma unroll
        for (int ks = 0; ks < 2; ++ks) {
            int lg = ks * 4 + (lane >> 4);
            aq[ks] = *(const bf16x8*)((const char*)Qs + r * 128 + ((lg ^ (r & 7)) << 4));
        }
    }

    f32x4 oacc[4] = {};
    float m[4] = {-INFINITY, -INFINITY, -INFINITY, -INFINITY};
    float l[4] = {0.f, 0.f, 0.f, 0.f};

    int nt = q0 / 64 + 1;
    for (int t = 0; t < nt; ++t) {
        int k0 = t * 64;
        __syncthreads();   // prev tile's Ks/Vs reads done
        // ---- stage K rows and Vt d-rows (wave w: rows w*16..+15 each) ----
        {
            int r0 = wid * 16;
            int rr0 = r0 + (lane >> 3);
            int g0 = lane & 7;
#pragma unroll
            for (int i = 0; i < 2; ++i) {
                int rr = rr0 + i * 8;
                int g = g0 ^ (rr & 7);
                const ushort* srck = Kbase + (size_t)(k0 + rr) * DD + g * 8;
                __builtin_amdgcn_global_load_lds(
                    (const __attribute__((address_space(1))) uint32_t*)srck,
                    (__attribute__((address_space(3))) uint32_t*)(Ks + (r0 + i * 8) * 64),
                    16, 0, 0);
                const ushort* srcv = Vbase + (size_t)rr * SS + k0 + g * 8;
                __builtin_amdgcn_global_load_lds(
                    (const __attribute__((address_space(1))) uint32_t*)srcv,
                    (__attribute__((address_space(3))) uint32_t*)(Vs + (r0 + i * 8) * 64),
                    16, 0, 0);
            }
        }
        __syncthreads();   // tile visible

        // ---- S = Q @ K^T (wave rows 16 x keys 64) ----
        f32x4 sacc[4] = {};
#pragma unroll
        for (int ni = 0; ni < 4; ++ni) {
            int r = ni * 16 + (lane & 15);
#pragma unroll
            for (int ks = 0; ks < 2; ++ks) {
                int lg = ks * 4 + (lane >> 4);
                bf16x8 bk = *(const bf16x8*)((const char*)Ks + r * 128 + ((lg ^ (r & 7)) << 4));
                sacc[ni] = __builtin_amdgcn_mfma_f32_16x16x32_bf16(aq[ks], bk, sacc[ni], 0, 0, 0);
            }
        }

        // ---- scale + causal mask (diagonal tile only) ----
        float sc[4][4];
#pragma unroll
        for (int ni = 0; ni < 4; ++ni)
#pragma unroll
            for (int j = 0; j < 4; ++j)
                sc[ni][j] = sacc[ni][j] * 0.125f;
        if (k0 == q0) {
            int rl = wid * 16 + ((lane >> 4) << 2);
#pragma unroll
            for (int ni = 0; ni < 4; ++ni) {
                int key = ni * 16 + (lane & 15);
#pragma unroll
                for (int j = 0; j < 4; ++j)
                    if (key > rl + j) sc[ni][j] = -INFINITY;
            }
        }

        // ---- online softmax (rows spread over 16 lanes) ----
        float p[4][4];
#pragma unroll
        for (int j = 0; j < 4; ++j) {
            float mx = fmaxf(fmaxf(sc[0][j], sc[1][j]), fmaxf(sc[2][j], sc[3][j]));
#pragma unroll
            for (int off = 1; off < 16; off <<= 1) mx = fmaxf(mx, __shfl_xor(mx, off));
            float mn = fmaxf(m[j], mx);
            float corr = __expf(m[j] - mn);
            m[j] = mn;
            float rs = 0.f;
#pragma unroll
            for (int ni = 0; ni < 4; ++ni) { p[ni][j] = __expf(sc[ni][j] - mn); rs += p[ni][j]; }
#pragma unroll
            for (int off = 1; off < 16; off <<= 1) rs += __shfl_xor(rs, off);
            l[j] = l[j] * corr + rs;
#pragma unroll
            for (int ni = 0; ni < 4; ++ni) oacc[ni][j] *= corr;
        }

        // ---- P -> bf16 -> wave-private LDS slab ----
        {
            int rbase = wid * 16 + ((lane >> 4) << 2);
            int cl = lane & 15;
#pragma unroll
            for (int ni = 0; ni < 4; ++ni) {
                int c = ni * 16 + cl;
                int gsh = (c >> 3);
                int blo = (c & 7) * 2;
#pragma unroll
                for (int j = 0; j < 4; ++j) {
                    int rl = rbase + j;
                    *(ushort*)((char*)Ps + rl * 128 + ((gsh ^ (rl & 7)) << 4) + blo) = f2b(p[ni][j]);
                }
            }
        }
        asm volatile("s_waitcnt lgkmcnt(0)" ::: "memory");   // P writes landed (wave-local)

        // ---- O += P @ V ----
        bf16x8 ap[2];
        {
            int r = wid * 16 + (lane & 15);
#pragma unroll
            for (int ks = 0; ks < 2; ++ks) {
                int lg = ks * 4 + (lane >> 4);
                ap[ks] = *(const bf16x8*)((const char*)Ps + r * 128 + ((lg ^ (r & 7)) << 4));
            }
        }
#pragma unroll
        for (int ni = 0; ni < 4; ++ni) {
            int r = ni * 16 + (lane & 15);
#pragma unroll
            for (int ks = 0; ks < 2; ++ks) {
                int lg = ks * 4 + (lane >> 4);
                bf16x8 bv = *(const bf16x8*)((const char*)Vs + r * 128 + ((lg ^ (r & 7)) << 4));
                oacc[ni] = __builtin_amdgcn_mfma_f32_16x16x32_bf16(ap[ks], bv, oacc[ni], 0, 0, 0);
            }
        }
    }

    // ---- epilogue: divide by l, write bf16 ----
#pragma unroll
    for (int j = 0; j < 4; ++j) {
        float inv = 1.f / l[j];
        int gr = q0 + wid * 16 + ((lane >> 4) << 2) + j;
#pragma unroll
        for (int ni = 0; ni < 4; ++ni) {
            int d = ni * 16 + (lane & 15);
            Og[((size_t)(b * SS + gr)) * DD + h * DH + d] = f2b(oacc[ni][j] * inv);
        }
    }
}

// ---------------- Launch ------------------------------------------------------
extern "C" void kernel_launch(void* const* d_in, const int* in_sizes, int n_in,
                              void* d_out, int out_size, void* d_ws, size_t ws_size,
                              hipStream_t stream) {
    const float* inputs    = (const float*)d_in[0];
    const float* ln1_scale = (const float*)d_in[1];
    const float* ln1_shift = (const float*)d_in[2];
    const float* Wq = (const float*)d_in[3];
    const float* bq = (const float*)d_in[4];
    const float* Wk = (const float*)d_in[5];
    const float* bk = (const float*)d_in[6];
    const float* Wv = (const float*)d_in[7];
    const float* bv = (const float*)d_in[8];
    const float* Wo = (const float*)d_in[9];
    const float* bo = (const float*)d_in[10];
    const float* W1 = (const float*)d_in[11];
    const float* b1 = (const float*)d_in[12];
    const float* W2 = (const float*)d_in[13];
    const float* b2 = (const float*)d_in[14];
    const float* ln2_scale = (const float*)d_in[15];
    const float* ln2_shift = (const float*)d_in[16];
    float* out = (float*)d_out;

    const size_t MB = 1024 * 1024;
    char* w = (char*)d_ws;
    ushort* q_b   = (ushort*)(w + 0 * MB);     // 8MB
    ushort* k_b   = (ushort*)(w + 8 * MB);     // 8MB
    ushort* vt_b  = (ushort*)(w + 16 * MB);    // 8MB
    ushort* att_b = (ushort*)(w + 24 * MB);    // 8MB
    float*  proj  = (float*)(w + 32 * MB);     // 16MB
    float*  o2_f  = (float*)(w + 48 * MB);     // 16MB
    ushort* h1_b  = (ushort*)(w + 64 * MB);    // 32MB
    ushort* wq_t  = (ushort*)(w + 96 * MB);    // 2MB
    ushort* wk_t  = (ushort*)(w + 98 * MB);
    ushort* wv_t  = (ushort*)(w + 100 * MB);
    ushort* wo_t  = (ushort*)(w + 102 * MB);
    ushort* w1_t  = (ushort*)(w + 104 * MB);   // 8MB
    ushort* w2_t  = (ushort*)(w + 112 * MB);   // 8MB
    ushort* xn_b  = (ushort*)(w + 120 * MB);   // 8MB
    ushort* o2_b  = q_b;                       // reuse (q dead after attention)

    // 0. weight convert+transpose
    transpose_bf16_kernel<<<dim3(DD / 32, DD / 32), 256, 0, stream>>>(Wq, wq_t, DD, DD);
    transpose_bf16_kernel<<<dim3(DD / 32, DD / 32), 256, 0, stream>>>(Wk, wk_t, DD, DD);
    transpose_bf16_kernel<<<dim3(DD / 32, DD / 32), 256, 0, stream>>>(Wv, wv_t, DD, DD);
    transpose_bf16_kernel<<<dim3(DD / 32, DD / 32), 256, 0, stream>>>(Wo, wo_t, DD, DD);
    transpose_bf16_kernel<<<dim3(FFN / 32, DD / 32), 256, 0, stream>>>(W1, w1_t, DD, FFN);
    transpose_bf16_kernel<<<dim3(DD / 32, FFN / 32), 256, 0, stream>>>(W2, w2_t, FFN, DD);

    // 1. LN1 -> bf16
    ln_kernel<<<NROW, 256, 0, stream>>>(inputs, ln1_scale, ln1_shift, xn_b);

    // 2. QKV projections (bf16 out; V transposed per head)
    dim3 g1(DD / GBN, NROW / GBM);
    gemm_bf16_kernel<0, true, false><<<g1, 256, 0, stream>>>(xn_b, wq_t, bq, nullptr, q_b, NROW, DD, DD);
    gemm_bf16_kernel<0, true, false><<<g1, 256, 0, stream>>>(xn_b, wk_t, bk, nullptr, k_b, NROW, DD, DD);
    gemm_bf16_kernel<0, true, true ><<<g1, 256, 0, stream>>>(xn_b, wv_t, bv, nullptr, vt_b, NROW, DD, DD);

    // 3. MFMA flash attention -> att_b (bf16)
    dim3 ga(SS / 64, BB * HH);
    attn_mfma_kernel<<<ga, 256, 0, stream>>>(q_b, k_b, vt_b, att_b);

    // 4. Output projection -> proj (fp32)
    gemm_bf16_kernel<0, false, false><<<g1, 256, 0, stream>>>(att_b, wo_t, bo, nullptr, proj, NROW, DD, DD);

    // 5. residual + LN2 -> o2 (bf16 + fp32)
    ln_res_kernel<<<NROW, 256, 0, stream>>>(proj, inputs, ln2_scale, ln2_shift, o2_b, o2_f);

    // 6. FFN up + relu -> h1 (bf16)
    dim3 g2(FFN / GBN, NROW / GBM);
    gemm_bf16_kernel<1, true, false><<<g2, 256, 0, stream>>>(o2_b, w1_t, b1, nullptr, h1_b, NROW, FFN, DD);

    // 7. FFN down + bias + o2 -> out (fp32)
    gemm_bf16_kernel<2, false, false><<<g1, 256, 0, stream>>>(h1_b, w2_t, b2, o2_f, out, NROW, DD, FFN);
}

// Round 5
// 297.098 us; speedup vs baseline: 20.9488x; 1.3563x over previous
//
#include <hip/hip_runtime.h>
#include <hip/hip_bf16.h>
#include <math.h>

// Problem constants
#define BB 2
#define SS 2048
#define DD 1024
#define HH 16
#define DH 64
#define NROW (BB*SS)          // 4096
#define FFN (4*DD)            // 4096

typedef __attribute__((ext_vector_type(8))) __bf16 bf16x8;
typedef __attribute__((ext_vector_type(4))) float f32x4;

__device__ __forceinline__ ushort f2b(float f) {
    union { float f; uint32_t u; } x; x.f = f;
    uint32_t r = x.u + 0x7FFF + ((x.u >> 16) & 1);
    return (ushort)(r >> 16);
}

// ---------------- LayerNorm (torch semantics: ddof=1, eps on std) -> bf16 ----
__global__ __launch_bounds__(256)
void ln_kernel(const float* __restrict__ x, const float* __restrict__ scale,
               const float* __restrict__ shift, ushort* __restrict__ y) {
    int row = blockIdx.x;
    const float* xr = x + (size_t)row * DD;
    ushort* yr = y + (size_t)row * DD;
    int t = threadIdx.x;
    float v[4];
    float s = 0.f, ss = 0.f;
#pragma unroll
    for (int i = 0; i < 4; ++i) {
        v[i] = xr[t + 256 * i];
        s += v[i];
        ss += v[i] * v[i];
    }
#pragma unroll
    for (int off = 32; off; off >>= 1) {
        s  += __shfl_xor(s, off);
        ss += __shfl_xor(ss, off);
    }
    __shared__ float red[8];
    int w = t >> 6;
    if ((t & 63) == 0) { red[w] = s; red[w + 4] = ss; }
    __syncthreads();
    float st  = red[0] + red[1] + red[2] + red[3];
    float sst = red[4] + red[5] + red[6] + red[7];
    float mu = st * (1.f / DD);
    float var = (sst - DD * mu * mu) * (1.f / (DD - 1));
    var = fmaxf(var, 0.f);
    float inv = 1.f / (sqrtf(var) + 1e-9f);
#pragma unroll
    for (int i = 0; i < 4; ++i) {
        int c = t + 256 * i;
        yr[c] = f2b(scale[c] * (v[i] - mu) * inv + shift[c]);
    }
}

// LN over (a + b): writes bf16 (for FFN GEMM) and fp32 (for final residual)
__global__ __launch_bounds__(256)
void ln_res_kernel(const float* __restrict__ xa, const float* __restrict__ xb,
                   const float* __restrict__ scale, const float* __restrict__ shift,
                   ushort* __restrict__ yb, float* __restrict__ yf) {
    int row = blockIdx.x;
    const float* ar = xa + (size_t)row * DD;
    const float* br = xb + (size_t)row * DD;
    ushort* ybr = yb + (size_t)row * DD;
    float* yfr = yf + (size_t)row * DD;
    int t = threadIdx.x;
    float v[4];
    float s = 0.f, ss = 0.f;
#pragma unroll
    for (int i = 0; i < 4; ++i) {
        int c = t + 256 * i;
        v[i] = ar[c] + br[c];
        s += v[i];
        ss += v[i] * v[i];
    }
#pragma unroll
    for (int off = 32; off; off >>= 1) {
        s  += __shfl_xor(s, off);
        ss += __shfl_xor(ss, off);
    }
    __shared__ float red[8];
    int w = t >> 6;
    if ((t & 63) == 0) { red[w] = s; red[w + 4] = ss; }
    __syncthreads();
    float st  = red[0] + red[1] + red[2] + red[3];
    float sst = red[4] + red[5] + red[6] + red[7];
    float mu = st * (1.f / DD);
    float var = (sst - DD * mu * mu) * (1.f / (DD - 1));
    var = fmaxf(var, 0.f);
    float inv = 1.f / (sqrtf(var) + 1e-9f);
#pragma unroll
    for (int i = 0; i < 4; ++i) {
        int c = t + 256 * i;
        float o = scale[c] * (v[i] - mu) * inv + shift[c];
        ybr[c] = f2b(o);
        yfr[c] = o;
    }
}

// ---------------- fp32 -> bf16 transpose-convert for weights -----------------
__global__ __launch_bounds__(256)
void transpose_bf16_kernel(const float* __restrict__ W, ushort* __restrict__ Wt,
                           int K, int N) {
    __shared__ ushort tile[32][33];
    int tx = threadIdx.x & 31;
    int ty = threadIdx.x >> 5;      // 0..7
    int n0 = blockIdx.x * 32;
    int k0 = blockIdx.y * 32;
#pragma unroll
    for (int i = 0; i < 32; i += 8)
        tile[ty + i][tx] = f2b(W[(size_t)(k0 + ty + i) * N + n0 + tx]);
    __syncthreads();
#pragma unroll
    for (int i = 0; i < 32; i += 8)
        Wt[(size_t)(n0 + ty + i) * K + k0 + tx] = tile[tx][ty + i];
}

// ---------------- bf16 MFMA GEMM (2-phase prefetch): C = A @ Wt^T + bias -----
// MODE 0: +bias (out per BF16_OUT); 1: +bias,relu; 2: +bias,+addsrc(fp32);
// MODE 3: fused QKV epilogue (Cout=q, out2=k, out3=v-transposed; bias/2/3)
#define GBM 128
#define GBN 128
#define GBK 32

template <int MODE, bool BF16_OUT>
__global__ __launch_bounds__(256)
void gemm_bf16_kernel(const ushort* __restrict__ A, const ushort* __restrict__ Wt,
                      const float* __restrict__ bias, const float* __restrict__ addsrc,
                      void* __restrict__ Cout, int M, int N, int K,
                      const float* __restrict__ bias2, const float* __restrict__ bias3,
                      void* __restrict__ out2, void* __restrict__ out3) {
    __shared__ ushort As[2][GBM * GBK];
    __shared__ ushort Bs[2][GBN * GBK];

    int tid = threadIdx.x;
    int lane = tid & 63;
    int wid = tid >> 6;
    int wr = wid >> 1, wc = wid & 1;
    int brow = blockIdx.y * GBM;
    int bcol = blockIdx.x * GBN;

    int lrow = lane & 15;
    int kgrp = lane >> 4;

    f32x4 acc[4][4] = {};

    int srow_base = wid * 32;
    int srow = srow_base + (lane >> 2);
    int sgran = lane & 3;

    auto stage = [&](int buf, int k0) {
#pragma unroll
        for (int i = 0; i < 2; ++i) {
            int row = srow + i * 16;
            int gran = sgran ^ ((row >> 1) & 3);
            const char* ga = (const char*)A +
                ((size_t)(brow + row) * K + k0) * 2 + gran * 16;
            __builtin_amdgcn_global_load_lds(
                (const __attribute__((address_space(1))) uint32_t*)ga,
                (__attribute__((address_space(3))) uint32_t*)(As[buf] + (srow_base + i * 16) * GBK),
                16, 0, 0);
            const char* gb = (const char*)Wt +
                ((size_t)(bcol + row) * K + k0) * 2 + gran * 16;
            __builtin_amdgcn_global_load_lds(
                (const __attribute__((address_space(1))) uint32_t*)gb,
                (__attribute__((address_space(3))) uint32_t*)(Bs[buf] + (srow_base + i * 16) * GBK),
                16, 0, 0);
        }
    };

    stage(0, 0);
    int cur = 0;
    int nk = K / GBK;
    for (int t = 0; t < nk; ++t) {
        __syncthreads();                       // buf[cur] ready; old reads done
        if (t + 1 < nk) stage(cur ^ 1, (t + 1) * GBK);   // overlap with compute

        bf16x8 afrag[4], bfrag[4];
#pragma unroll
        for (int mi = 0; mi < 4; ++mi) {
            int row = wr * 64 + mi * 16 + lrow;
            int gran = kgrp ^ ((row >> 1) & 3);
            afrag[mi] = *(const bf16x8*)((const char*)As[cur] + row * 64 + gran * 16);
        }
#pragma unroll
        for (int ni = 0; ni < 4; ++ni) {
            int row = wc * 64 + ni * 16 + lrow;
            int gran = kgrp ^ ((row >> 1) & 3);
            bfrag[ni] = *(const bf16x8*)((const char*)Bs[cur] + row * 64 + gran * 16);
        }
#pragma unroll
        for (int mi = 0; mi < 4; ++mi)
#pragma unroll
            for (int ni = 0; ni < 4; ++ni)
                acc[mi][ni] = __builtin_amdgcn_mfma_f32_16x16x32_bf16(
                    afrag[mi], bfrag[ni], acc[mi][ni], 0, 0, 0);
        cur ^= 1;
    }

    if (MODE == 3) {
        int which = bcol >> 10;   // 0=q, 1=k, 2=v (128-tile never straddles)
        const float* bs = which == 0 ? bias : (which == 1 ? bias2 : bias3);
#pragma unroll
        for (int ni = 0; ni < 4; ++ni) {
            int col = bcol + wc * 64 + ni * 16 + lrow;
            int lcol = col & 1023;
            float bsv = bs[lcol];
#pragma unroll
            for (int mi = 0; mi < 4; ++mi) {
                f32x4 a = acc[mi][ni];
#pragma unroll
                for (int j = 0; j < 4; ++j) {
                    int row = brow + wr * 64 + mi * 16 + kgrp * 4 + j;
                    float val = a[j] + bsv;
                    if (which == 2) {
                        size_t idx = (size_t)(row >> 11) * ((size_t)DD * SS)
                                   + (size_t)lcol * SS + (row & (SS - 1));
                        ((ushort*)out3)[idx] = f2b(val);
                    } else {
                        ushort* dst = which == 0 ? (ushort*)Cout : (ushort*)out2;
                        dst[(size_t)row * DD + lcol] = f2b(val);
                    }
                }
            }
        }
        return;
    }

#pragma unroll
    for (int ni = 0; ni < 4; ++ni) {
        int col = bcol + wc * 64 + ni * 16 + lrow;
        float bsv = bias[col];
#pragma unroll
        for (int mi = 0; mi < 4; ++mi) {
            f32x4 a = acc[mi][ni];
#pragma unroll
            for (int j = 0; j < 4; ++j) {
                int row = brow + wr * 64 + mi * 16 + kgrp * 4 + j;
                float val = a[j] + bsv;
                if (MODE == 1) val = fmaxf(val, 0.f);
                if (MODE == 2) val += addsrc[(size_t)row * N + col];
                if (BF16_OUT)
                    ((ushort*)Cout)[(size_t)row * N + col] = f2b(val);
                else
                    ((float*)Cout)[(size_t)row * N + col] = val;
            }
        }
    }
}

// ---------------- bf16 MFMA causal flash attention (2-phase prefetch) --------
// Block: 4 waves per (b, h, 64-query tile); wave w owns q rows [w*16, w*16+16).
// K/V double-buffered in LDS; stage(t+1) issued before compute(t); one barrier
// per k-step. Grid: x=bh, y=q-tile (reversed: heavy tiles dispatch first).
__global__ __launch_bounds__(256)
void attn_mfma_kernel(const ushort* __restrict__ Qg, const ushort* __restrict__ Kg,
                      const ushort* __restrict__ Vtg, ushort* __restrict__ Og) {
    __shared__ ushort Qs[64 * 64];        // [qrow][d]   8KB
    __shared__ ushort Ks[2][64 * 64];     // [key][d]    16KB
    __shared__ ushort Vs[2][64 * 64];     // [d][key]    16KB
    __shared__ ushort Ps[64 * 64];        // [qrow][key] 8KB (wave-private slabs)

    int tid = threadIdx.x;
    int lane = tid & 63;
    int wid = tid >> 6;
    int bh = blockIdx.x;
    int b = bh >> 4, h = bh & 15;
    int q0 = ((int)gridDim.y - 1 - (int)blockIdx.y) * 64;   // heavy tiles first

    const ushort* Qbase = Qg + ((size_t)(b * SS + q0)) * DD + h * DH;
    const ushort* Kbase = Kg + ((size_t)(b * SS)) * DD + h * DH;
    const ushort* Vbase = Vtg + (size_t)bh * DH * SS;        // rows: d, stride SS

    int r0 = wid * 16;
    int rr0 = r0 + (lane >> 3);
    int g0 = lane & 7;

    auto stageKV = [&](int buf, int k0) {
#pragma unroll
        for (int i = 0; i < 2; ++i) {
            int rr = rr0 + i * 8;
            int g = g0 ^ (rr & 7);
            const ushort* srck = Kbase + (size_t)(k0 + rr) * DD + g * 8;
            __builtin_amdgcn_global_load_lds(
                (const __attribute__((address_space(1))) uint32_t*)srck,
                (__attribute__((address_space(3))) uint32_t*)(Ks[buf] + (r0 + i * 8) * 64),
                16, 0, 0);
            const ushort* srcv = Vbase + (size_t)rr * SS + k0 + g * 8;
            __builtin_amdgcn_global_load_lds(
                (const __attribute__((address_space(1))) uint32_t*)srcv,
                (__attribute__((address_space(3))) uint32_t*)(Vs[buf] + (r0 + i * 8) * 64),
                16, 0, 0);
        }
    };

    // ---- stage Q + first K/V tile ----
    {
#pragma unroll
        for (int i = 0; i < 2; ++i) {
            int rr = rr0 + i * 8;
            int g = g0 ^ (rr & 7);
            const ushort* src = Qbase + (size_t)rr * DD + g * 8;
            __builtin_amdgcn_global_load_lds(
                (const __attribute__((address_space(1))) uint32_t*)src,
                (__attribute__((address_space(3))) uint32_t*)(Qs + (r0 + i * 8) * 64),
                16, 0, 0);
        }
    }
    stageKV(0, 0);
    __syncthreads();   // Q + tile0 visible

    // ---- hoist Q A-fragments ----
    bf16x8 aq[2];
    {
        int r = wid * 16 + (lane & 15);
#pragma unroll
        for (int ks = 0; ks < 2; ++ks) {
            int lg = ks * 4 + (lane >> 4);
            aq[ks] = *(const bf16x8*)((const char*)Qs + r * 128 + ((lg ^ (r & 7)) << 4));
        }
    }

    f32x4 oacc[4] = {};
    float m[4] = {-INFINITY, -INFINITY, -INFINITY, -INFINITY};
    float l[4] = {0.f, 0.f, 0.f, 0.f};

    int nt = q0 / 64 + 1;
    int cur = 0;
    for (int t = 0; t < nt; ++t) {
        if (t) __syncthreads();                    // buf[cur] ready; old reads done
        if (t + 1 < nt) stageKV(cur ^ 1, (t + 1) * 64);   // overlap with compute
        int k0 = t * 64;

        // ---- S = Q @ K^T ----
        f32x4 sacc[4] = {};
#pragma unroll
        for (int ni = 0; ni < 4; ++ni) {
            int r = ni * 16 + (lane & 15);
#pragma unroll
            for (int ks = 0; ks < 2; ++ks) {
                int lg = ks * 4 + (lane >> 4);
                bf16x8 bk = *(const bf16x8*)((const char*)Ks[cur] + r * 128 + ((lg ^ (r & 7)) << 4));
                sacc[ni] = __builtin_amdgcn_mfma_f32_16x16x32_bf16(aq[ks], bk, sacc[ni], 0, 0, 0);
            }
        }

        // ---- scale + causal mask (diagonal tile only) ----
        float sc[4][4];
#pragma unroll
        for (int ni = 0; ni < 4; ++ni)
#pragma unroll
            for (int j = 0; j < 4; ++j)
                sc[ni][j] = sacc[ni][j] * 0.125f;
        if (k0 == q0) {
            int rl = wid * 16 + ((lane >> 4) << 2);
#pragma unroll
            for (int ni = 0; ni < 4; ++ni) {
                int key = ni * 16 + (lane & 15);
#pragma unroll
                for (int j = 0; j < 4; ++j)
                    if (key > rl + j) sc[ni][j] = -INFINITY;
            }
        }

        // ---- online softmax (rows spread over 16 lanes) ----
        float p[4][4];
#pragma unroll
        for (int j = 0; j < 4; ++j) {
            float mx = fmaxf(fmaxf(sc[0][j], sc[1][j]), fmaxf(sc[2][j], sc[3][j]));
#pragma unroll
            for (int off = 1; off < 16; off <<= 1) mx = fmaxf(mx, __shfl_xor(mx, off));
            float mn = fmaxf(m[j], mx);
            float corr = __expf(m[j] - mn);
            m[j] = mn;
            float rs = 0.f;
#pragma unroll
            for (int ni = 0; ni < 4; ++ni) { p[ni][j] = __expf(sc[ni][j] - mn); rs += p[ni][j]; }
#pragma unroll
            for (int off = 1; off < 16; off <<= 1) rs += __shfl_xor(rs, off);
            l[j] = l[j] * corr + rs;
#pragma unroll
            for (int ni = 0; ni < 4; ++ni) oacc[ni][j] *= corr;
        }

        // ---- P -> bf16 -> wave-private LDS slab ----
        {
            int rbase = wid * 16 + ((lane >> 4) << 2);
            int cl = lane & 15;
#pragma unroll
            for (int ni = 0; ni < 4; ++ni) {
                int c = ni * 16 + cl;
                int gsh = (c >> 3);
                int blo = (c & 7) * 2;
#pragma unroll
                for (int j = 0; j < 4; ++j) {
                    int rl = rbase + j;
                    *(ushort*)((char*)Ps + rl * 128 + ((gsh ^ (rl & 7)) << 4) + blo) = f2b(p[ni][j]);
                }
            }
        }
        asm volatile("s_waitcnt lgkmcnt(0)" ::: "memory");   // wave-local P landed

        // ---- O += P @ V ----
        bf16x8 ap[2];
        {
            int r = wid * 16 + (lane & 15);
#pragma unroll
            for (int ks = 0; ks < 2; ++ks) {
                int lg = ks * 4 + (lane >> 4);
                ap[ks] = *(const bf16x8*)((const char*)Ps + r * 128 + ((lg ^ (r & 7)) << 4));
            }
        }
#pragma unroll
        for (int ni = 0; ni < 4; ++ni) {
            int r = ni * 16 + (lane & 15);
#pragma unroll
            for (int ks = 0; ks < 2; ++ks) {
                int lg = ks * 4 + (lane >> 4);
                bf16x8 bv = *(const bf16x8*)((const char*)Vs[cur] + r * 128 + ((lg ^ (r & 7)) << 4));
                oacc[ni] = __builtin_amdgcn_mfma_f32_16x16x32_bf16(ap[ks], bv, oacc[ni], 0, 0, 0);
            }
        }
        cur ^= 1;
    }

    // ---- epilogue: divide by l, write bf16 ----
#pragma unroll
    for (int j = 0; j < 4; ++j) {
        float inv = 1.f / l[j];
        int gr = q0 + wid * 16 + ((lane >> 4) << 2) + j;
#pragma unroll
        for (int ni = 0; ni < 4; ++ni) {
            int d = ni * 16 + (lane & 15);
            Og[((size_t)(b * SS + gr)) * DD + h * DH + d] = f2b(oacc[ni][j] * inv);
        }
    }
}

// ---------------- Launch ------------------------------------------------------
extern "C" void kernel_launch(void* const* d_in, const int* in_sizes, int n_in,
                              void* d_out, int out_size, void* d_ws, size_t ws_size,
                              hipStream_t stream) {
    const float* inputs    = (const float*)d_in[0];
    const float* ln1_scale = (const float*)d_in[1];
    const float* ln1_shift = (const float*)d_in[2];
    const float* Wq = (const float*)d_in[3];
    const float* bq = (const float*)d_in[4];
    const float* Wk = (const float*)d_in[5];
    const float* bk = (const float*)d_in[6];
    const float* Wv = (const float*)d_in[7];
    const float* bv = (const float*)d_in[8];
    const float* Wo = (const float*)d_in[9];
    const float* bo = (const float*)d_in[10];
    const float* W1 = (const float*)d_in[11];
    const float* b1 = (const float*)d_in[12];
    const float* W2 = (const float*)d_in[13];
    const float* b2 = (const float*)d_in[14];
    const float* ln2_scale = (const float*)d_in[15];
    const float* ln2_shift = (const float*)d_in[16];
    float* out = (float*)d_out;

    const size_t MB = 1024 * 1024;
    char* w = (char*)d_ws;
    ushort* q_b   = (ushort*)(w + 0 * MB);     // 8MB
    ushort* k_b   = (ushort*)(w + 8 * MB);     // 8MB
    ushort* vt_b  = (ushort*)(w + 16 * MB);    // 8MB
    ushort* att_b = (ushort*)(w + 24 * MB);    // 8MB
    float*  proj  = (float*)(w + 32 * MB);     // 16MB
    float*  o2_f  = (float*)(w + 48 * MB);     // 16MB
    ushort* h1_b  = (ushort*)(w + 64 * MB);    // 32MB
    ushort* wq_t  = (ushort*)(w + 96 * MB);    // 2MB  (q/k/v contiguous = fused 3072xK)
    ushort* wk_t  = (ushort*)(w + 98 * MB);
    ushort* wv_t  = (ushort*)(w + 100 * MB);
    ushort* wo_t  = (ushort*)(w + 102 * MB);
    ushort* w1_t  = (ushort*)(w + 104 * MB);   // 8MB
    ushort* w2_t  = (ushort*)(w + 112 * MB);   // 8MB
    ushort* xn_b  = (ushort*)(w + 120 * MB);   // 8MB
    ushort* o2_b  = q_b;                       // reuse (q dead after attention)

    // 0. weight convert+transpose
    transpose_bf16_kernel<<<dim3(DD / 32, DD / 32), 256, 0, stream>>>(Wq, wq_t, DD, DD);
    transpose_bf16_kernel<<<dim3(DD / 32, DD / 32), 256, 0, stream>>>(Wk, wk_t, DD, DD);
    transpose_bf16_kernel<<<dim3(DD / 32, DD / 32), 256, 0, stream>>>(Wv, wv_t, DD, DD);
    transpose_bf16_kernel<<<dim3(DD / 32, DD / 32), 256, 0, stream>>>(Wo, wo_t, DD, DD);
    transpose_bf16_kernel<<<dim3(FFN / 32, DD / 32), 256, 0, stream>>>(W1, w1_t, DD, FFN);
    transpose_bf16_kernel<<<dim3(DD / 32, FFN / 32), 256, 0, stream>>>(W2, w2_t, FFN, DD);

    // 1. LN1 -> bf16
    ln_kernel<<<NROW, 256, 0, stream>>>(inputs, ln1_scale, ln1_shift, xn_b);

    // 2. Fused QKV projection (N=3072; V written transposed per head)
    dim3 gqkv(3 * DD / GBN, NROW / GBM);   // 24 x 32
    gemm_bf16_kernel<3, true><<<gqkv, 256, 0, stream>>>(
        xn_b, wq_t, bq, nullptr, q_b, NROW, 3 * DD, DD, bk, bv, k_b, vt_b);

    // 3. MFMA flash attention -> att_b (bf16)
    dim3 ga(BB * HH, SS / 64);
    attn_mfma_kernel<<<ga, 256, 0, stream>>>(q_b, k_b, vt_b, att_b);

    // 4. Output projection -> proj (fp32)
    dim3 g1(DD / GBN, NROW / GBM);
    gemm_bf16_kernel<0, false><<<g1, 256, 0, stream>>>(
        att_b, wo_t, bo, nullptr, proj, NROW, DD, DD, nullptr, nullptr, nullptr, nullptr);

    // 5. residual + LN2 -> o2 (bf16 + fp32)
    ln_res_kernel<<<NROW, 256, 0, stream>>>(proj, inputs, ln2_scale, ln2_shift, o2_b, o2_f);

    // 6. FFN up + relu -> h1 (bf16)
    dim3 g2(FFN / GBN, NROW / GBM);
    gemm_bf16_kernel<1, true><<<g2, 256, 0, stream>>>(
        o2_b, w1_t, b1, nullptr, h1_b, NROW, FFN, DD, nullptr, nullptr, nullptr, nullptr);

    // 7. FFN down + bias + o2 -> out (fp32)
    gemm_bf16_kernel<2, false><<<g1, 256, 0, stream>>>(
        h1_b, w2_t, b2, o2_f, out, NROW, DD, FFN, nullptr, nullptr, nullptr, nullptr);
}

// Round 6
// 294.031 us; speedup vs baseline: 21.1673x; 1.0104x over previous
//
#include <hip/hip_runtime.h>
#include <hip/hip_bf16.h>
#include <math.h>

// Problem constants
#define BB 2
#define SS 2048
#define DD 1024
#define HH 16
#define DH 64
#define NROW (BB*SS)          // 4096
#define FFN (4*DD)            // 4096

typedef __attribute__((ext_vector_type(8))) __bf16 bf16x8;
typedef __attribute__((ext_vector_type(4))) float f32x4;

__device__ __forceinline__ ushort f2b(float f) {
    union { float f; uint32_t u; } x; x.f = f;
    uint32_t r = x.u + 0x7FFF + ((x.u >> 16) & 1);
    return (ushort)(r >> 16);
}
__device__ __forceinline__ float b2f(ushort u) {
    union { uint32_t u; float f; } x; x.u = (uint32_t)u << 16;
    return x.f;
}

// ---------------- LayerNorm (torch semantics: ddof=1, eps on std) -> bf16 ----
__global__ __launch_bounds__(256)
void ln_kernel(const float* __restrict__ x, const float* __restrict__ scale,
               const float* __restrict__ shift, ushort* __restrict__ y) {
    int row = blockIdx.x;
    const float* xr = x + (size_t)row * DD;
    ushort* yr = y + (size_t)row * DD;
    int t = threadIdx.x;
    float v[4];
    float s = 0.f, ss = 0.f;
#pragma unroll
    for (int i = 0; i < 4; ++i) {
        v[i] = xr[t + 256 * i];
        s += v[i];
        ss += v[i] * v[i];
    }
#pragma unroll
    for (int off = 32; off; off >>= 1) {
        s  += __shfl_xor(s, off);
        ss += __shfl_xor(ss, off);
    }
    __shared__ float red[8];
    int w = t >> 6;
    if ((t & 63) == 0) { red[w] = s; red[w + 4] = ss; }
    __syncthreads();
    float st  = red[0] + red[1] + red[2] + red[3];
    float sst = red[4] + red[5] + red[6] + red[7];
    float mu = st * (1.f / DD);
    float var = (sst - DD * mu * mu) * (1.f / (DD - 1));
    var = fmaxf(var, 0.f);
    float inv = 1.f / (sqrtf(var) + 1e-9f);
#pragma unroll
    for (int i = 0; i < 4; ++i) {
        int c = t + 256 * i;
        yr[c] = f2b(scale[c] * (v[i] - mu) * inv + shift[c]);
    }
}

// LN over (a_bf16 + b_fp32): writes bf16 (for FFN GEMM input AND residual)
__global__ __launch_bounds__(256)
void ln_res_kernel(const ushort* __restrict__ xa, const float* __restrict__ xb,
                   const float* __restrict__ scale, const float* __restrict__ shift,
                   ushort* __restrict__ yb) {
    int row = blockIdx.x;
    const ushort* ar = xa + (size_t)row * DD;
    const float* br = xb + (size_t)row * DD;
    ushort* ybr = yb + (size_t)row * DD;
    int t = threadIdx.x;
    float v[4];
    float s = 0.f, ss = 0.f;
#pragma unroll
    for (int i = 0; i < 4; ++i) {
        int c = t + 256 * i;
        v[i] = b2f(ar[c]) + br[c];
        s += v[i];
        ss += v[i] * v[i];
    }
#pragma unroll
    for (int off = 32; off; off >>= 1) {
        s  += __shfl_xor(s, off);
        ss += __shfl_xor(ss, off);
    }
    __shared__ float red[8];
    int w = t >> 6;
    if ((t & 63) == 0) { red[w] = s; red[w + 4] = ss; }
    __syncthreads();
    float st  = red[0] + red[1] + red[2] + red[3];
    float sst = red[4] + red[5] + red[6] + red[7];
    float mu = st * (1.f / DD);
    float var = (sst - DD * mu * mu) * (1.f / (DD - 1));
    var = fmaxf(var, 0.f);
    float inv = 1.f / (sqrtf(var) + 1e-9f);
#pragma unroll
    for (int i = 0; i < 4; ++i) {
        int c = t + 256 * i;
        ybr[c] = f2b(scale[c] * (v[i] - mu) * inv + shift[c]);
    }
}

// ---------------- fp32 -> bf16 transpose-convert for weights -----------------
__global__ __launch_bounds__(256)
void transpose_bf16_kernel(const float* __restrict__ W, ushort* __restrict__ Wt,
                           int K, int N) {
    __shared__ ushort tile[32][33];
    int tx = threadIdx.x & 31;
    int ty = threadIdx.x >> 5;      // 0..7
    int n0 = blockIdx.x * 32;
    int k0 = blockIdx.y * 32;
#pragma unroll
    for (int i = 0; i < 32; i += 8)
        tile[ty + i][tx] = f2b(W[(size_t)(k0 + ty + i) * N + n0 + tx]);
    __syncthreads();
#pragma unroll
    for (int i = 0; i < 32; i += 8)
        Wt[(size_t)(n0 + ty + i) * K + k0 + tx] = tile[tx][ty + i];
}

// ---------------- bf16 MFMA GEMM (3-deep counted-vmcnt ring) -----------------
// C = A(MxK) @ Wt(NxK)^T + bias.
// MODE 0: +bias (out per BF16_OUT); 1: +bias,relu; 2: +bias,+addsrc(bf16),fp32 out
// MODE 3: fused QKV epilogue (Cout=q, out2=k, out3=v-transposed; bias/2/3)
#define GBM 128
#define GBN 128
#define GBK 32

template <int MODE, bool BF16_OUT>
__global__ __launch_bounds__(256)
void gemm_bf16_kernel(const ushort* __restrict__ A, const ushort* __restrict__ Wt,
                      const float* __restrict__ bias, const ushort* __restrict__ addsrc,
                      void* __restrict__ Cout, int M, int N, int K,
                      const float* __restrict__ bias2, const float* __restrict__ bias3,
                      void* __restrict__ out2, void* __restrict__ out3) {
    __shared__ ushort As[3][GBM * GBK];   // 3 x 8KB
    __shared__ ushort Bs[3][GBN * GBK];   // 3 x 8KB

    int tid = threadIdx.x;
    int lane = tid & 63;
    int wid = tid >> 6;
    int wr = wid >> 1, wc = wid & 1;
    int brow = blockIdx.y * GBM;
    int bcol = blockIdx.x * GBN;

    int lrow = lane & 15;
    int kgrp = lane >> 4;

    f32x4 acc[4][4] = {};

    int srow_base = wid * 32;
    int srow = srow_base + (lane >> 2);
    int sgran = lane & 3;

    // each wave issues exactly 4 global_load_lds per stage
    auto stage = [&](int buf, int k0) {
#pragma unroll
        for (int i = 0; i < 2; ++i) {
            int row = srow + i * 16;
            int gran = sgran ^ ((row >> 1) & 3);
            const char* ga = (const char*)A +
                ((size_t)(brow + row) * K + k0) * 2 + gran * 16;
            __builtin_amdgcn_global_load_lds(
                (const __attribute__((address_space(1))) uint32_t*)ga,
                (__attribute__((address_space(3))) uint32_t*)(&As[buf][0] + (srow_base + i * 16) * GBK),
                16, 0, 0);
            const char* gb = (const char*)Wt +
                ((size_t)(bcol + row) * K + k0) * 2 + gran * 16;
            __builtin_amdgcn_global_load_lds(
                (const __attribute__((address_space(1))) uint32_t*)gb,
                (__attribute__((address_space(3))) uint32_t*)(&Bs[buf][0] + (srow_base + i * 16) * GBK),
                16, 0, 0);
        }
    };

    int nk = K / GBK;
    stage(0, 0);
    if (nk > 1) stage(1, GBK);

    int cur = 0, stg = 2;
    for (int t = 0; t < nk; ++t) {
        __builtin_amdgcn_sched_barrier(0);   // pin prev iter's ds_reads/MFMAs
        if (t + 1 < nk) asm volatile("s_waitcnt vmcnt(4)" ::: "memory");  // buf[cur] landed; next stage in flight
        else            asm volatile("s_waitcnt vmcnt(0)" ::: "memory");
        asm volatile("s_barrier" ::: "memory");                           // no vmcnt drain
        if (t + 2 < nk) stage(stg, (t + 2) * GBK);

        bf16x8 afrag[4], bfrag[4];
#pragma unroll
        for (int mi = 0; mi < 4; ++mi) {
            int row = wr * 64 + mi * 16 + lrow;
            int gran = kgrp ^ ((row >> 1) & 3);
            afrag[mi] = *(const bf16x8*)((const char*)&As[cur][0] + row * 64 + gran * 16);
        }
#pragma unroll
        for (int ni = 0; ni < 4; ++ni) {
            int row = wc * 64 + ni * 16 + lrow;
            int gran = kgrp ^ ((row >> 1) & 3);
            bfrag[ni] = *(const bf16x8*)((const char*)&Bs[cur][0] + row * 64 + gran * 16);
        }
#pragma unroll
        for (int mi = 0; mi < 4; ++mi)
#pragma unroll
            for (int ni = 0; ni < 4; ++ni)
                acc[mi][ni] = __builtin_amdgcn_mfma_f32_16x16x32_bf16(
                    afrag[mi], bfrag[ni], acc[mi][ni], 0, 0, 0);

        cur = (cur == 2) ? 0 : cur + 1;
        stg = (stg == 2) ? 0 : stg + 1;
    }

    if (MODE == 3) {
        int which = bcol >> 10;   // 0=q, 1=k, 2=v (128-tile never straddles)
        const float* bs = which == 0 ? bias : (which == 1 ? bias2 : bias3);
#pragma unroll
        for (int ni = 0; ni < 4; ++ni) {
            int col = bcol + wc * 64 + ni * 16 + lrow;
            int lcol = col & 1023;
            float bsv = bs[lcol];
#pragma unroll
            for (int mi = 0; mi < 4; ++mi) {
                f32x4 a = acc[mi][ni];
#pragma unroll
                for (int j = 0; j < 4; ++j) {
                    int row = brow + wr * 64 + mi * 16 + kgrp * 4 + j;
                    float val = a[j] + bsv;
                    if (which == 2) {
                        size_t idx = (size_t)(row >> 11) * ((size_t)DD * SS)
                                   + (size_t)lcol * SS + (row & (SS - 1));
                        ((ushort*)out3)[idx] = f2b(val);
                    } else {
                        ushort* dst = which == 0 ? (ushort*)Cout : (ushort*)out2;
                        dst[(size_t)row * DD + lcol] = f2b(val);
                    }
                }
            }
        }
        return;
    }

#pragma unroll
    for (int ni = 0; ni < 4; ++ni) {
        int col = bcol + wc * 64 + ni * 16 + lrow;
        float bsv = bias[col];
#pragma unroll
        for (int mi = 0; mi < 4; ++mi) {
            f32x4 a = acc[mi][ni];
#pragma unroll
            for (int j = 0; j < 4; ++j) {
                int row = brow + wr * 64 + mi * 16 + kgrp * 4 + j;
                float val = a[j] + bsv;
                if (MODE == 1) val = fmaxf(val, 0.f);
                if (MODE == 2) val += b2f(addsrc[(size_t)row * N + col]);
                if (BF16_OUT)
                    ((ushort*)Cout)[(size_t)row * N + col] = f2b(val);
                else
                    ((float*)Cout)[(size_t)row * N + col] = val;
            }
        }
    }
}

// ---------------- bf16 MFMA causal flash attention (3-deep ring) -------------
// Block: 4 waves per (b, h, 64-query tile); wave w owns q rows [w*16, w*16+16).
// K/V in a 3-buffer LDS ring; counted vmcnt keeps 1 stage in flight across the
// raw s_barrier. Grid: x=bh, y=q-tile (reversed: heavy tiles dispatch first).
__global__ __launch_bounds__(256)
void attn_mfma_kernel(const ushort* __restrict__ Qg, const ushort* __restrict__ Kg,
                      const ushort* __restrict__ Vtg, ushort* __restrict__ Og) {
    __shared__ ushort Qs[64 * 64];        // 8KB
    __shared__ ushort Ks[3][64 * 64];     // 24KB
    __shared__ ushort Vs[3][64 * 64];     // 24KB
    __shared__ ushort Ps[64 * 64];        // 8KB (wave-private slabs)

    int tid = threadIdx.x;
    int lane = tid & 63;
    int wid = tid >> 6;
    int bh = blockIdx.x;
    int b = bh >> 4, h = bh & 15;
    int q0 = ((int)gridDim.y - 1 - (int)blockIdx.y) * 64;   // heavy tiles first

    const ushort* Qbase = Qg + ((size_t)(b * SS + q0)) * DD + h * DH;
    const ushort* Kbase = Kg + ((size_t)(b * SS)) * DD + h * DH;
    const ushort* Vbase = Vtg + (size_t)bh * DH * SS;        // rows: d, stride SS

    int r0 = wid * 16;
    int rr0 = r0 + (lane >> 3);
    int g0 = lane & 7;

    // each wave issues exactly 4 global_load_lds per stage
    auto stageKV = [&](int buf, int k0) {
#pragma unroll
        for (int i = 0; i < 2; ++i) {
            int rr = rr0 + i * 8;
            int g = g0 ^ (rr & 7);
            const ushort* srck = Kbase + (size_t)(k0 + rr) * DD + g * 8;
            __builtin_amdgcn_global_load_lds(
                (const __attribute__((address_space(1))) uint32_t*)srck,
                (__attribute__((address_space(3))) uint32_t*)(&Ks[buf][0] + (r0 + i * 8) * 64),
                16, 0, 0);
            const ushort* srcv = Vbase + (size_t)rr * SS + k0 + g * 8;
            __builtin_amdgcn_global_load_lds(
                (const __attribute__((address_space(1))) uint32_t*)srcv,
                (__attribute__((address_space(3))) uint32_t*)(&Vs[buf][0] + (r0 + i * 8) * 64),
                16, 0, 0);
        }
    };

    int nt = q0 / 64 + 1;

    // ---- prologue: Q (2 loads/wave) + up to 2 K/V stages ----
    {
#pragma unroll
        for (int i = 0; i < 2; ++i) {
            int rr = rr0 + i * 8;
            int g = g0 ^ (rr & 7);
            const ushort* src = Qbase + (size_t)rr * DD + g * 8;
            __builtin_amdgcn_global_load_lds(
                (const __attribute__((address_space(1))) uint32_t*)src,
                (__attribute__((address_space(3))) uint32_t*)(Qs + (r0 + i * 8) * 64),
                16, 0, 0);
        }
    }
    stageKV(0, 0);
    if (nt > 1) stageKV(1, 64);
    __builtin_amdgcn_sched_barrier(0);
    if (nt > 1) asm volatile("s_waitcnt vmcnt(8)" ::: "memory");   // Q landed
    else        asm volatile("s_waitcnt vmcnt(4)" ::: "memory");
    asm volatile("s_barrier" ::: "memory");

    // ---- hoist Q A-fragments ----
    bf16x8 aq[2];
    {
        int r = wid * 16 + (lane & 15);
#pragma unroll
        for (int ks = 0; ks < 2; ++ks) {
            int lg = ks * 4 + (lane >> 4);
            aq[ks] = *(const bf16x8*)((const char*)Qs + r * 128 + ((lg ^ (r & 7)) << 4));
        }
    }

    f32x4 oacc[4] = {};
    float m[4] = {-INFINITY, -INFINITY, -INFINITY, -INFINITY};
    float l[4] = {0.f, 0.f, 0.f, 0.f};

    int cur = 0, stg = 2;
    for (int t = 0; t < nt; ++t) {
        __builtin_amdgcn_sched_barrier(0);
        if (t + 1 < nt) asm volatile("s_waitcnt vmcnt(4)" ::: "memory");
        else            asm volatile("s_waitcnt vmcnt(0)" ::: "memory");
        asm volatile("s_barrier" ::: "memory");
        if (t + 2 < nt) stageKV(stg, (t + 2) * 64);
        int k0 = t * 64;

        // ---- S = Q @ K^T ----
        f32x4 sacc[4] = {};
#pragma unroll
        for (int ni = 0; ni < 4; ++ni) {
            int r = ni * 16 + (lane & 15);
#pragma unroll
            for (int ks = 0; ks < 2; ++ks) {
                int lg = ks * 4 + (lane >> 4);
                bf16x8 bk = *(const bf16x8*)((const char*)&Ks[cur][0] + r * 128 + ((lg ^ (r & 7)) << 4));
                sacc[ni] = __builtin_amdgcn_mfma_f32_16x16x32_bf16(aq[ks], bk, sacc[ni], 0, 0, 0);
            }
        }

        // ---- scale + causal mask (diagonal tile only) ----
        float sc[4][4];
#pragma unroll
        for (int ni = 0; ni < 4; ++ni)
#pragma unroll
            for (int j = 0; j < 4; ++j)
                sc[ni][j] = sacc[ni][j] * 0.125f;
        if (k0 == q0) {
            int rl = wid * 16 + ((lane >> 4) << 2);
#pragma unroll
            for (int ni = 0; ni < 4; ++ni) {
                int key = ni * 16 + (lane & 15);
#pragma unroll
                for (int j = 0; j < 4; ++j)
                    if (key > rl + j) sc[ni][j] = -INFINITY;
            }
        }

        // ---- online softmax (rows spread over 16 lanes) ----
        float p[4][4];
#pragma unroll
        for (int j = 0; j < 4; ++j) {
            float mx = fmaxf(fmaxf(sc[0][j], sc[1][j]), fmaxf(sc[2][j], sc[3][j]));
#pragma unroll
            for (int off = 1; off < 16; off <<= 1) mx = fmaxf(mx, __shfl_xor(mx, off));
            float mn = fmaxf(m[j], mx);
            float corr = __expf(m[j] - mn);
            m[j] = mn;
            float rs = 0.f;
#pragma unroll
            for (int ni = 0; ni < 4; ++ni) { p[ni][j] = __expf(sc[ni][j] - mn); rs += p[ni][j]; }
#pragma unroll
            for (int off = 1; off < 16; off <<= 1) rs += __shfl_xor(rs, off);
            l[j] = l[j] * corr + rs;
#pragma unroll
            for (int ni = 0; ni < 4; ++ni) oacc[ni][j] *= corr;
        }

        // ---- P -> bf16 -> wave-private LDS slab ----
        {
            int rbase = wid * 16 + ((lane >> 4) << 2);
            int cl = lane & 15;
#pragma unroll
            for (int ni = 0; ni < 4; ++ni) {
                int c = ni * 16 + cl;
                int gsh = (c >> 3);
                int blo = (c & 7) * 2;
#pragma unroll
                for (int j = 0; j < 4; ++j) {
                    int rl = rbase + j;
                    *(ushort*)((char*)Ps + rl * 128 + ((gsh ^ (rl & 7)) << 4) + blo) = f2b(p[ni][j]);
                }
            }
        }
        asm volatile("s_waitcnt lgkmcnt(0)" ::: "memory");   // wave-local P landed

        // ---- O += P @ V ----
        bf16x8 ap[2];
        {
            int r = wid * 16 + (lane & 15);
#pragma unroll
            for (int ks = 0; ks < 2; ++ks) {
                int lg = ks * 4 + (lane >> 4);
                ap[ks] = *(const bf16x8*)((const char*)Ps + r * 128 + ((lg ^ (r & 7)) << 4));
            }
        }
#pragma unroll
        for (int ni = 0; ni < 4; ++ni) {
            int r = ni * 16 + (lane & 15);
#pragma unroll
            for (int ks = 0; ks < 2; ++ks) {
                int lg = ks * 4 + (lane >> 4);
                bf16x8 bv = *(const bf16x8*)((const char*)&Vs[cur][0] + r * 128 + ((lg ^ (r & 7)) << 4));
                oacc[ni] = __builtin_amdgcn_mfma_f32_16x16x32_bf16(ap[ks], bv, oacc[ni], 0, 0, 0);
            }
        }
        cur = (cur == 2) ? 0 : cur + 1;
        stg = (stg == 2) ? 0 : stg + 1;
    }

    // ---- epilogue: divide by l, write bf16 ----
#pragma unroll
    for (int j = 0; j < 4; ++j) {
        float inv = 1.f / l[j];
        int gr = q0 + wid * 16 + ((lane >> 4) << 2) + j;
#pragma unroll
        for (int ni = 0; ni < 4; ++ni) {
            int d = ni * 16 + (lane & 15);
            Og[((size_t)(b * SS + gr)) * DD + h * DH + d] = f2b(oacc[ni][j] * inv);
        }
    }
}

// ---------------- Launch ------------------------------------------------------
extern "C" void kernel_launch(void* const* d_in, const int* in_sizes, int n_in,
                              void* d_out, int out_size, void* d_ws, size_t ws_size,
                              hipStream_t stream) {
    const float* inputs    = (const float*)d_in[0];
    const float* ln1_scale = (const float*)d_in[1];
    const float* ln1_shift = (const float*)d_in[2];
    const float* Wq = (const float*)d_in[3];
    const float* bq = (const float*)d_in[4];
    const float* Wk = (const float*)d_in[5];
    const float* bk = (const float*)d_in[6];
    const float* Wv = (const float*)d_in[7];
    const float* bv = (const float*)d_in[8];
    const float* Wo = (const float*)d_in[9];
    const float* bo = (const float*)d_in[10];
    const float* W1 = (const float*)d_in[11];
    const float* b1 = (const float*)d_in[12];
    const float* W2 = (const float*)d_in[13];
    const float* b2 = (const float*)d_in[14];
    const float* ln2_scale = (const float*)d_in[15];
    const float* ln2_shift = (const float*)d_in[16];
    float* out = (float*)d_out;

    const size_t MB = 1024 * 1024;
    char* w = (char*)d_ws;
    ushort* q_b   = (ushort*)(w + 0 * MB);     // 8MB
    ushort* k_b   = (ushort*)(w + 8 * MB);     // 8MB
    ushort* vt_b  = (ushort*)(w + 16 * MB);    // 8MB
    ushort* att_b = (ushort*)(w + 24 * MB);    // 8MB
    ushort* proj_b= (ushort*)(w + 32 * MB);    // 8MB
    ushort* o2_b  = (ushort*)(w + 48 * MB);    // 8MB
    ushort* h1_b  = (ushort*)(w + 64 * MB);    // 32MB
    ushort* wq_t  = (ushort*)(w + 96 * MB);    // 2MB  (q/k/v contiguous = fused 3072xK)
    ushort* wk_t  = (ushort*)(w + 98 * MB);
    ushort* wv_t  = (ushort*)(w + 100 * MB);
    ushort* wo_t  = (ushort*)(w + 102 * MB);
    ushort* w1_t  = (ushort*)(w + 104 * MB);   // 8MB
    ushort* w2_t  = (ushort*)(w + 112 * MB);   // 8MB
    ushort* xn_b  = (ushort*)(w + 120 * MB);   // 8MB

    // 0. weight convert+transpose
    transpose_bf16_kernel<<<dim3(DD / 32, DD / 32), 256, 0, stream>>>(Wq, wq_t, DD, DD);
    transpose_bf16_kernel<<<dim3(DD / 32, DD / 32), 256, 0, stream>>>(Wk, wk_t, DD, DD);
    transpose_bf16_kernel<<<dim3(DD / 32, DD / 32), 256, 0, stream>>>(Wv, wv_t, DD, DD);
    transpose_bf16_kernel<<<dim3(DD / 32, DD / 32), 256, 0, stream>>>(Wo, wo_t, DD, DD);
    transpose_bf16_kernel<<<dim3(FFN / 32, DD / 32), 256, 0, stream>>>(W1, w1_t, DD, FFN);
    transpose_bf16_kernel<<<dim3(DD / 32, FFN / 32), 256, 0, stream>>>(W2, w2_t, FFN, DD);

    // 1. LN1 -> bf16
    ln_kernel<<<NROW, 256, 0, stream>>>(inputs, ln1_scale, ln1_shift, xn_b);

    // 2. Fused QKV projection (N=3072; V written transposed per head)
    dim3 gqkv(3 * DD / GBN, NROW / GBM);   // 24 x 32
    gemm_bf16_kernel<3, true><<<gqkv, 256, 0, stream>>>(
        xn_b, wq_t, bq, nullptr, q_b, NROW, 3 * DD, DD, bk, bv, k_b, vt_b);

    // 3. MFMA flash attention -> att_b (bf16)
    dim3 ga(BB * HH, SS / 64);
    attn_mfma_kernel<<<ga, 256, 0, stream>>>(q_b, k_b, vt_b, att_b);

    // 4. Output projection -> proj (bf16)
    dim3 g1(DD / GBN, NROW / GBM);
    gemm_bf16_kernel<0, true><<<g1, 256, 0, stream>>>(
        att_b, wo_t, bo, nullptr, proj_b, NROW, DD, DD, nullptr, nullptr, nullptr, nullptr);

    // 5. residual + LN2 -> o2 (bf16, serves as GEMM input AND final residual)
    ln_res_kernel<<<NROW, 256, 0, stream>>>(proj_b, inputs, ln2_scale, ln2_shift, o2_b);

    // 6. FFN up + relu -> h1 (bf16)
    dim3 g2(FFN / GBN, NROW / GBM);
    gemm_bf16_kernel<1, true><<<g2, 256, 0, stream>>>(
        o2_b, w1_t, b1, nullptr, h1_b, NROW, FFN, DD, nullptr, nullptr, nullptr, nullptr);

    // 7. FFN down + bias + o2 -> out (fp32)
    gemm_bf16_kernel<2, false><<<g1, 256, 0, stream>>>(
        h1_b, w2_t, b2, o2_b, out, NROW, DD, FFN, nullptr, nullptr, nullptr, nullptr);
}

// Round 7
// 292.521 us; speedup vs baseline: 21.2766x; 1.0052x over previous
//
#include <hip/hip_runtime.h>
#include <hip/hip_bf16.h>
#include <math.h>

// Problem constants
#define BB 2
#define SS 2048
#define DD 1024
#define HH 16
#define DH 64
#define NROW (BB*SS)          // 4096
#define FFN (4*DD)            // 4096

typedef __attribute__((ext_vector_type(8))) __bf16 bf16x8;
typedef __attribute__((ext_vector_type(4))) float f32x4;

__device__ __forceinline__ ushort f2b(float f) {
    union { float f; uint32_t u; } x; x.f = f;
    uint32_t r = x.u + 0x7FFF + ((x.u >> 16) & 1);
    return (ushort)(r >> 16);
}
__device__ __forceinline__ float b2f(ushort u) {
    union { uint32_t u; float f; } x; x.u = (uint32_t)u << 16;
    return x.f;
}

// ---------------- LayerNorm (torch semantics: ddof=1, eps on std) -> bf16 ----
__global__ __launch_bounds__(256)
void ln_kernel(const float* __restrict__ x, const float* __restrict__ scale,
               const float* __restrict__ shift, ushort* __restrict__ y) {
    int row = blockIdx.x;
    const float* xr = x + (size_t)row * DD;
    ushort* yr = y + (size_t)row * DD;
    int t = threadIdx.x;
    float v[4];
    float s = 0.f, ss = 0.f;
#pragma unroll
    for (int i = 0; i < 4; ++i) {
        v[i] = xr[t + 256 * i];
        s += v[i];
        ss += v[i] * v[i];
    }
#pragma unroll
    for (int off = 32; off; off >>= 1) {
        s  += __shfl_xor(s, off);
        ss += __shfl_xor(ss, off);
    }
    __shared__ float red[8];
    int w = t >> 6;
    if ((t & 63) == 0) { red[w] = s; red[w + 4] = ss; }
    __syncthreads();
    float st  = red[0] + red[1] + red[2] + red[3];
    float sst = red[4] + red[5] + red[6] + red[7];
    float mu = st * (1.f / DD);
    float var = (sst - DD * mu * mu) * (1.f / (DD - 1));
    var = fmaxf(var, 0.f);
    float inv = 1.f / (sqrtf(var) + 1e-9f);
#pragma unroll
    for (int i = 0; i < 4; ++i) {
        int c = t + 256 * i;
        yr[c] = f2b(scale[c] * (v[i] - mu) * inv + shift[c]);
    }
}

// LN over (a_bf16 + b_fp32): writes bf16 (for FFN GEMM input AND residual)
__global__ __launch_bounds__(256)
void ln_res_kernel(const ushort* __restrict__ xa, const float* __restrict__ xb,
                   const float* __restrict__ scale, const float* __restrict__ shift,
                   ushort* __restrict__ yb) {
    int row = blockIdx.x;
    const ushort* ar = xa + (size_t)row * DD;
    const float* br = xb + (size_t)row * DD;
    ushort* ybr = yb + (size_t)row * DD;
    int t = threadIdx.x;
    float v[4];
    float s = 0.f, ss = 0.f;
#pragma unroll
    for (int i = 0; i < 4; ++i) {
        int c = t + 256 * i;
        v[i] = b2f(ar[c]) + br[c];
        s += v[i];
        ss += v[i] * v[i];
    }
#pragma unroll
    for (int off = 32; off; off >>= 1) {
        s  += __shfl_xor(s, off);
        ss += __shfl_xor(ss, off);
    }
    __shared__ float red[8];
    int w = t >> 6;
    if ((t & 63) == 0) { red[w] = s; red[w + 4] = ss; }
    __syncthreads();
    float st  = red[0] + red[1] + red[2] + red[3];
    float sst = red[4] + red[5] + red[6] + red[7];
    float mu = st * (1.f / DD);
    float var = (sst - DD * mu * mu) * (1.f / (DD - 1));
    var = fmaxf(var, 0.f);
    float inv = 1.f / (sqrtf(var) + 1e-9f);
#pragma unroll
    for (int i = 0; i < 4; ++i) {
        int c = t + 256 * i;
        ybr[c] = f2b(scale[c] * (v[i] - mu) * inv + shift[c]);
    }
}

// ---------------- fp32 -> bf16 transpose-convert for weights -----------------
__global__ __launch_bounds__(256)
void transpose_bf16_kernel(const float* __restrict__ W, ushort* __restrict__ Wt,
                           int K, int N) {
    __shared__ ushort tile[32][33];
    int tx = threadIdx.x & 31;
    int ty = threadIdx.x >> 5;      // 0..7
    int n0 = blockIdx.x * 32;
    int k0 = blockIdx.y * 32;
#pragma unroll
    for (int i = 0; i < 32; i += 8)
        tile[ty + i][tx] = f2b(W[(size_t)(k0 + ty + i) * N + n0 + tx]);
    __syncthreads();
#pragma unroll
    for (int i = 0; i < 32; i += 8)
        Wt[(size_t)(n0 + ty + i) * K + k0 + tx] = tile[tx][ty + i];
}

// ---------------- bf16 MFMA GEMM (DEPTH-deep counted-vmcnt ring) -------------
// C = A(MxK) @ Wt(NxK)^T + bias.  XCD-swizzled block ids (requires nwg%8==0).
// MODE 0: +bias (out per BF16_OUT); 1: +bias,relu; 2: +bias,+addsrc(bf16),fp32 out
// MODE 3: fused QKV epilogue (Cout=q, out2=k, out3=v-transposed; bias/2/3)
#define GBM 128
#define GBN 128
#define GBK 32

template <int MODE, bool BF16_OUT, int DEPTH>
__global__ __launch_bounds__(256)
void gemm_bf16_kernel(const ushort* __restrict__ A, const ushort* __restrict__ Wt,
                      const float* __restrict__ bias, const ushort* __restrict__ addsrc,
                      void* __restrict__ Cout, int M, int N, int K,
                      const float* __restrict__ bias2, const float* __restrict__ bias3,
                      void* __restrict__ out2, void* __restrict__ out3) {
    __shared__ ushort As[DEPTH][GBM * GBK];   // DEPTH x 8KB
    __shared__ ushort Bs[DEPTH][GBN * GBK];   // DEPTH x 8KB

    int tid = threadIdx.x;
    int lane = tid & 63;
    int wid = tid >> 6;
    int wr = wid >> 1, wc = wid & 1;

    // ---- bijective XCD swizzle: each XCD gets a contiguous chunk of rows ----
    int gx = gridDim.x;
    int nwg = gx * gridDim.y;
    int orig = blockIdx.y * gx + blockIdx.x;
    int q8 = nwg >> 3;                       // nwg % 8 == 0 guaranteed by launch
    int swz = (orig & 7) * q8 + (orig >> 3);
    int bx = swz % gx, by = swz / gx;

    int brow = by * GBM;
    int bcol = bx * GBN;

    int lrow = lane & 15;
    int kgrp = lane >> 4;

    f32x4 acc[4][4] = {};

    int srow_base = wid * 32;
    int srow = srow_base + (lane >> 2);
    int sgran = lane & 3;

    // each wave issues exactly 4 global_load_lds per stage
    auto stage = [&](int buf, int k0) {
#pragma unroll
        for (int i = 0; i < 2; ++i) {
            int row = srow + i * 16;
            int gran = sgran ^ ((row >> 1) & 3);
            const char* ga = (const char*)A +
                ((size_t)(brow + row) * K + k0) * 2 + gran * 16;
            __builtin_amdgcn_global_load_lds(
                (const __attribute__((address_space(1))) uint32_t*)ga,
                (__attribute__((address_space(3))) uint32_t*)(&As[buf][0] + (srow_base + i * 16) * GBK),
                16, 0, 0);
            const char* gb = (const char*)Wt +
                ((size_t)(bcol + row) * K + k0) * 2 + gran * 16;
            __builtin_amdgcn_global_load_lds(
                (const __attribute__((address_space(1))) uint32_t*)gb,
                (__attribute__((address_space(3))) uint32_t*)(&Bs[buf][0] + (srow_base + i * 16) * GBK),
                16, 0, 0);
        }
    };

    int nk = K / GBK;
    constexpr int PRE = DEPTH - 1;           // stages in flight ahead of compute
#pragma unroll
    for (int s = 0; s < PRE; ++s)
        if (s < nk) stage(s, s * GBK);

    int cur = 0, stg = PRE;
    for (int t = 0; t < nk; ++t) {
        __builtin_amdgcn_sched_barrier(0);   // pin prev iter's ds_reads/MFMAs
        int rem = nk - 1 - t;                // stages still in flight beyond cur
        if constexpr (DEPTH == 5) {
            if (rem >= 3)      asm volatile("s_waitcnt vmcnt(12)" ::: "memory");
            else if (rem == 2) asm volatile("s_waitcnt vmcnt(8)"  ::: "memory");
            else if (rem == 1) asm volatile("s_waitcnt vmcnt(4)"  ::: "memory");
            else               asm volatile("s_waitcnt vmcnt(0)"  ::: "memory");
        } else {
            if (rem >= 1)      asm volatile("s_waitcnt vmcnt(4)"  ::: "memory");
            else               asm volatile("s_waitcnt vmcnt(0)"  ::: "memory");
        }
        asm volatile("s_barrier" ::: "memory");          // no vmcnt drain
        if (t + PRE < nk) stage(stg, (t + PRE) * GBK);

        bf16x8 afrag[4], bfrag[4];
#pragma unroll
        for (int mi = 0; mi < 4; ++mi) {
            int row = wr * 64 + mi * 16 + lrow;
            int gran = kgrp ^ ((row >> 1) & 3);
            afrag[mi] = *(const bf16x8*)((const char*)&As[cur][0] + row * 64 + gran * 16);
        }
#pragma unroll
        for (int ni = 0; ni < 4; ++ni) {
            int row = wc * 64 + ni * 16 + lrow;
            int gran = kgrp ^ ((row >> 1) & 3);
            bfrag[ni] = *(const bf16x8*)((const char*)&Bs[cur][0] + row * 64 + gran * 16);
        }
#pragma unroll
        for (int mi = 0; mi < 4; ++mi)
#pragma unroll
            for (int ni = 0; ni < 4; ++ni)
                acc[mi][ni] = __builtin_amdgcn_mfma_f32_16x16x32_bf16(
                    afrag[mi], bfrag[ni], acc[mi][ni], 0, 0, 0);

        cur = (cur == DEPTH - 1) ? 0 : cur + 1;
        stg = (stg == DEPTH - 1) ? 0 : stg + 1;
    }

    if (MODE == 3) {
        int which = bcol >> 10;   // 0=q, 1=k, 2=v (128-tile never straddles)
        const float* bs = which == 0 ? bias : (which == 1 ? bias2 : bias3);
#pragma unroll
        for (int ni = 0; ni < 4; ++ni) {
            int col = bcol + wc * 64 + ni * 16 + lrow;
            int lcol = col & 1023;
            float bsv = bs[lcol];
#pragma unroll
            for (int mi = 0; mi < 4; ++mi) {
                f32x4 a = acc[mi][ni];
#pragma unroll
                for (int j = 0; j < 4; ++j) {
                    int row = brow + wr * 64 + mi * 16 + kgrp * 4 + j;
                    float val = a[j] + bsv;
                    if (which == 2) {
                        size_t idx = (size_t)(row >> 11) * ((size_t)DD * SS)
                                   + (size_t)lcol * SS + (row & (SS - 1));
                        ((ushort*)out3)[idx] = f2b(val);
                    } else {
                        ushort* dst = which == 0 ? (ushort*)Cout : (ushort*)out2;
                        dst[(size_t)row * DD + lcol] = f2b(val);
                    }
                }
            }
        }
        return;
    }

#pragma unroll
    for (int ni = 0; ni < 4; ++ni) {
        int col = bcol + wc * 64 + ni * 16 + lrow;
        float bsv = bias[col];
#pragma unroll
        for (int mi = 0; mi < 4; ++mi) {
            f32x4 a = acc[mi][ni];
#pragma unroll
            for (int j = 0; j < 4; ++j) {
                int row = brow + wr * 64 + mi * 16 + kgrp * 4 + j;
                float val = a[j] + bsv;
                if (MODE == 1) val = fmaxf(val, 0.f);
                if (MODE == 2) val += b2f(addsrc[(size_t)row * N + col]);
                if (BF16_OUT)
                    ((ushort*)Cout)[(size_t)row * N + col] = f2b(val);
                else
                    ((float*)Cout)[(size_t)row * N + col] = val;
            }
        }
    }
}

// ---------------- bf16 MFMA causal flash attention (3-deep ring) -------------
// Block: 4 waves per (b, h, 64-query tile); wave w owns q rows [w*16, w*16+16).
// K/V in a 3-buffer LDS ring; counted vmcnt keeps 1 stage in flight across the
// raw s_barrier. Grid: x=bh, y=q-tile (reversed: heavy tiles dispatch first).
__global__ __launch_bounds__(256)
void attn_mfma_kernel(const ushort* __restrict__ Qg, const ushort* __restrict__ Kg,
                      const ushort* __restrict__ Vtg, ushort* __restrict__ Og) {
    __shared__ ushort Qs[64 * 64];        // 8KB
    __shared__ ushort Ks[3][64 * 64];     // 24KB
    __shared__ ushort Vs[3][64 * 64];     // 24KB
    __shared__ ushort Ps[64 * 64];        // 8KB (wave-private slabs)

    int tid = threadIdx.x;
    int lane = tid & 63;
    int wid = tid >> 6;
    int bh = blockIdx.x;
    int b = bh >> 4, h = bh & 15;
    int q0 = ((int)gridDim.y - 1 - (int)blockIdx.y) * 64;   // heavy tiles first

    const ushort* Qbase = Qg + ((size_t)(b * SS + q0)) * DD + h * DH;
    const ushort* Kbase = Kg + ((size_t)(b * SS)) * DD + h * DH;
    const ushort* Vbase = Vtg + (size_t)bh * DH * SS;        // rows: d, stride SS

    int r0 = wid * 16;
    int rr0 = r0 + (lane >> 3);
    int g0 = lane & 7;

    // each wave issues exactly 4 global_load_lds per stage
    auto stageKV = [&](int buf, int k0) {
#pragma unroll
        for (int i = 0; i < 2; ++i) {
            int rr = rr0 + i * 8;
            int g = g0 ^ (rr & 7);
            const ushort* srck = Kbase + (size_t)(k0 + rr) * DD + g * 8;
            __builtin_amdgcn_global_load_lds(
                (const __attribute__((address_space(1))) uint32_t*)srck,
                (__attribute__((address_space(3))) uint32_t*)(&Ks[buf][0] + (r0 + i * 8) * 64),
                16, 0, 0);
            const ushort* srcv = Vbase + (size_t)rr * SS + k0 + g * 8;
            __builtin_amdgcn_global_load_lds(
                (const __attribute__((address_space(1))) uint32_t*)srcv,
                (__attribute__((address_space(3))) uint32_t*)(&Vs[buf][0] + (r0 + i * 8) * 64),
                16, 0, 0);
        }
    };

    int nt = q0 / 64 + 1;

    // ---- prologue: Q (2 loads/wave) + up to 2 K/V stages ----
    {
#pragma unroll
        for (int i = 0; i < 2; ++i) {
            int rr = rr0 + i * 8;
            int g = g0 ^ (rr & 7);
            const ushort* src = Qbase + (size_t)rr * DD + g * 8;
            __builtin_amdgcn_global_load_lds(
                (const __attribute__((address_space(1))) uint32_t*)src,
                (__attribute__((address_space(3))) uint32_t*)(Qs + (r0 + i * 8) * 64),
                16, 0, 0);
        }
    }
    stageKV(0, 0);
    if (nt > 1) stageKV(1, 64);
    __builtin_amdgcn_sched_barrier(0);
    if (nt > 1) asm volatile("s_waitcnt vmcnt(8)" ::: "memory");   // Q landed
    else        asm volatile("s_waitcnt vmcnt(4)" ::: "memory");
    asm volatile("s_barrier" ::: "memory");

    // ---- hoist Q A-fragments ----
    bf16x8 aq[2];
    {
        int r = wid * 16 + (lane & 15);
#pragma unroll
        for (int ks = 0; ks < 2; ++ks) {
            int lg = ks * 4 + (lane >> 4);
            aq[ks] = *(const bf16x8*)((const char*)Qs + r * 128 + ((lg ^ (r & 7)) << 4));
        }
    }

    f32x4 oacc[4] = {};
    float m[4] = {-INFINITY, -INFINITY, -INFINITY, -INFINITY};
    float l[4] = {0.f, 0.f, 0.f, 0.f};

    int cur = 0, stg = 2;
    for (int t = 0; t < nt; ++t) {
        __builtin_amdgcn_sched_barrier(0);
        if (t + 1 < nt) asm volatile("s_waitcnt vmcnt(4)" ::: "memory");
        else            asm volatile("s_waitcnt vmcnt(0)" ::: "memory");
        asm volatile("s_barrier" ::: "memory");
        if (t + 2 < nt) stageKV(stg, (t + 2) * 64);
        int k0 = t * 64;

        // ---- S = Q @ K^T ----
        f32x4 sacc[4] = {};
#pragma unroll
        for (int ni = 0; ni < 4; ++ni) {
            int r = ni * 16 + (lane & 15);
#pragma unroll
            for (int ks = 0; ks < 2; ++ks) {
                int lg = ks * 4 + (lane >> 4);
                bf16x8 bk = *(const bf16x8*)((const char*)&Ks[cur][0] + r * 128 + ((lg ^ (r & 7)) << 4));
                sacc[ni] = __builtin_amdgcn_mfma_f32_16x16x32_bf16(aq[ks], bk, sacc[ni], 0, 0, 0);
            }
        }

        // ---- scale + causal mask (diagonal tile only) ----
        float sc[4][4];
#pragma unroll
        for (int ni = 0; ni < 4; ++ni)
#pragma unroll
            for (int j = 0; j < 4; ++j)
                sc[ni][j] = sacc[ni][j] * 0.125f;
        if (k0 == q0) {
            int rl = wid * 16 + ((lane >> 4) << 2);
#pragma unroll
            for (int ni = 0; ni < 4; ++ni) {
                int key = ni * 16 + (lane & 15);
#pragma unroll
                for (int j = 0; j < 4; ++j)
                    if (key > rl + j) sc[ni][j] = -INFINITY;
            }
        }

        // ---- online softmax (rows spread over 16 lanes) ----
        float p[4][4];
#pragma unroll
        for (int j = 0; j < 4; ++j) {
            float mx = fmaxf(fmaxf(sc[0][j], sc[1][j]), fmaxf(sc[2][j], sc[3][j]));
#pragma unroll
            for (int off = 1; off < 16; off <<= 1) mx = fmaxf(mx, __shfl_xor(mx, off));
            float mn = fmaxf(m[j], mx);
            float corr = __expf(m[j] - mn);
            m[j] = mn;
            float rs = 0.f;
#pragma unroll
            for (int ni = 0; ni < 4; ++ni) { p[ni][j] = __expf(sc[ni][j] - mn); rs += p[ni][j]; }
#pragma unroll
            for (int off = 1; off < 16; off <<= 1) rs += __shfl_xor(rs, off);
            l[j] = l[j] * corr + rs;
#pragma unroll
            for (int ni = 0; ni < 4; ++ni) oacc[ni][j] *= corr;
        }

        // ---- P -> bf16 -> wave-private LDS slab ----
        {
            int rbase = wid * 16 + ((lane >> 4) << 2);
            int cl = lane & 15;
#pragma unroll
            for (int ni = 0; ni < 4; ++ni) {
                int c = ni * 16 + cl;
                int gsh = (c >> 3);
                int blo = (c & 7) * 2;
#pragma unroll
                for (int j = 0; j < 4; ++j) {
                    int rl = rbase + j;
                    *(ushort*)((char*)Ps + rl * 128 + ((gsh ^ (rl & 7)) << 4) + blo) = f2b(p[ni][j]);
                }
            }
        }
        asm volatile("s_waitcnt lgkmcnt(0)" ::: "memory");   // wave-local P landed

        // ---- O += P @ V ----
        bf16x8 ap[2];
        {
            int r = wid * 16 + (lane & 15);
#pragma unroll
            for (int ks = 0; ks < 2; ++ks) {
                int lg = ks * 4 + (lane >> 4);
                ap[ks] = *(const bf16x8*)((const char*)Ps + r * 128 + ((lg ^ (r & 7)) << 4));
            }
        }
#pragma unroll
        for (int ni = 0; ni < 4; ++ni) {
            int r = ni * 16 + (lane & 15);
#pragma unroll
            for (int ks = 0; ks < 2; ++ks) {
                int lg = ks * 4 + (lane >> 4);
                bf16x8 bv = *(const bf16x8*)((const char*)&Vs[cur][0] + r * 128 + ((lg ^ (r & 7)) << 4));
                oacc[ni] = __builtin_amdgcn_mfma_f32_16x16x32_bf16(ap[ks], bv, oacc[ni], 0, 0, 0);
            }
        }
        cur = (cur == 2) ? 0 : cur + 1;
        stg = (stg == 2) ? 0 : stg + 1;
    }

    // ---- epilogue: divide by l, write bf16 ----
#pragma unroll
    for (int j = 0; j < 4; ++j) {
        float inv = 1.f / l[j];
        int gr = q0 + wid * 16 + ((lane >> 4) << 2) + j;
#pragma unroll
        for (int ni = 0; ni < 4; ++ni) {
            int d = ni * 16 + (lane & 15);
            Og[((size_t)(b * SS + gr)) * DD + h * DH + d] = f2b(oacc[ni][j] * inv);
        }
    }
}

// ---------------- Launch ------------------------------------------------------
extern "C" void kernel_launch(void* const* d_in, const int* in_sizes, int n_in,
                              void* d_out, int out_size, void* d_ws, size_t ws_size,
                              hipStream_t stream) {
    const float* inputs    = (const float*)d_in[0];
    const float* ln1_scale = (const float*)d_in[1];
    const float* ln1_shift = (const float*)d_in[2];
    const float* Wq = (const float*)d_in[3];
    const float* bq = (const float*)d_in[4];
    const float* Wk = (const float*)d_in[5];
    const float* bk = (const float*)d_in[6];
    const float* Wv = (const float*)d_in[7];
    const float* bv = (const float*)d_in[8];
    const float* Wo = (const float*)d_in[9];
    const float* bo = (const float*)d_in[10];
    const float* W1 = (const float*)d_in[11];
    const float* b1 = (const float*)d_in[12];
    const float* W2 = (const float*)d_in[13];
    const float* b2 = (const float*)d_in[14];
    const float* ln2_scale = (const float*)d_in[15];
    const float* ln2_shift = (const float*)d_in[16];
    float* out = (float*)d_out;

    const size_t MB = 1024 * 1024;
    char* w = (char*)d_ws;
    ushort* q_b   = (ushort*)(w + 0 * MB);     // 8MB
    ushort* k_b   = (ushort*)(w + 8 * MB);     // 8MB
    ushort* vt_b  = (ushort*)(w + 16 * MB);    // 8MB
    ushort* att_b = (ushort*)(w + 24 * MB);    // 8MB
    ushort* proj_b= (ushort*)(w + 32 * MB);    // 8MB
    ushort* o2_b  = (ushort*)(w + 48 * MB);    // 8MB
    ushort* h1_b  = (ushort*)(w + 64 * MB);    // 32MB
    ushort* wq_t  = (ushort*)(w + 96 * MB);    // 2MB  (q/k/v contiguous = fused 3072xK)
    ushort* wk_t  = (ushort*)(w + 98 * MB);
    ushort* wv_t  = (ushort*)(w + 100 * MB);
    ushort* wo_t  = (ushort*)(w + 102 * MB);
    ushort* w1_t  = (ushort*)(w + 104 * MB);   // 8MB
    ushort* w2_t  = (ushort*)(w + 112 * MB);   // 8MB
    ushort* xn_b  = (ushort*)(w + 120 * MB);   // 8MB

    // 0. weight convert+transpose
    transpose_bf16_kernel<<<dim3(DD / 32, DD / 32), 256, 0, stream>>>(Wq, wq_t, DD, DD);
    transpose_bf16_kernel<<<dim3(DD / 32, DD / 32), 256, 0, stream>>>(Wk, wk_t, DD, DD);
    transpose_bf16_kernel<<<dim3(DD / 32, DD / 32), 256, 0, stream>>>(Wv, wv_t, DD, DD);
    transpose_bf16_kernel<<<dim3(DD / 32, DD / 32), 256, 0, stream>>>(Wo, wo_t, DD, DD);
    transpose_bf16_kernel<<<dim3(FFN / 32, DD / 32), 256, 0, stream>>>(W1, w1_t, DD, FFN);
    transpose_bf16_kernel<<<dim3(DD / 32, FFN / 32), 256, 0, stream>>>(W2, w2_t, FFN, DD);

    // 1. LN1 -> bf16
    ln_kernel<<<NROW, 256, 0, stream>>>(inputs, ln1_scale, ln1_shift, xn_b);

    // 2. Fused QKV projection (N=3072; V written transposed per head). 768 blk.
    dim3 gqkv(3 * DD / GBN, NROW / GBM);   // 24 x 32
    gemm_bf16_kernel<3, true, 3><<<gqkv, 256, 0, stream>>>(
        xn_b, wq_t, bq, nullptr, q_b, NROW, 3 * DD, DD, bk, bv, k_b, vt_b);

    // 3. MFMA flash attention -> att_b (bf16)
    dim3 ga(BB * HH, SS / 64);
    attn_mfma_kernel<<<ga, 256, 0, stream>>>(q_b, k_b, vt_b, att_b);

    // 4. Output projection -> proj (bf16). 256 blocks -> depth-5 ring.
    dim3 g1(DD / GBN, NROW / GBM);
    gemm_bf16_kernel<0, true, 5><<<g1, 256, 0, stream>>>(
        att_b, wo_t, bo, nullptr, proj_b, NROW, DD, DD, nullptr, nullptr, nullptr, nullptr);

    // 5. residual + LN2 -> o2 (bf16, serves as GEMM input AND final residual)
    ln_res_kernel<<<NROW, 256, 0, stream>>>(proj_b, inputs, ln2_scale, ln2_shift, o2_b);

    // 6. FFN up + relu -> h1 (bf16). 1024 blocks -> depth-3.
    dim3 g2(FFN / GBN, NROW / GBM);
    gemm_bf16_kernel<1, true, 3><<<g2, 256, 0, stream>>>(
        o2_b, w1_t, b1, nullptr, h1_b, NROW, FFN, DD, nullptr, nullptr, nullptr, nullptr);

    // 7. FFN down + bias + o2 -> out (fp32). 256 blocks -> depth-5 ring.
    gemm_bf16_kernel<2, false, 5><<<g1, 256, 0, stream>>>(
        h1_b, w2_t, b2, o2_b, out, NROW, DD, FFN, nullptr, nullptr, nullptr, nullptr);
}

// Round 8
// 283.341 us; speedup vs baseline: 21.9659x; 1.0324x over previous
//
#include <hip/hip_runtime.h>
#include <hip/hip_bf16.h>
#include <math.h>

// Problem constants
#define BB 2
#define SS 2048
#define DD 1024
#define HH 16
#define DH 64
#define NROW (BB*SS)          // 4096
#define FFN (4*DD)            // 4096

typedef __attribute__((ext_vector_type(8))) __bf16 bf16x8;
typedef __attribute__((ext_vector_type(4))) float f32x4;

__device__ __forceinline__ ushort f2b(float f) {
    union { float f; uint32_t u; } x; x.f = f;
    uint32_t r = x.u + 0x7FFF + ((x.u >> 16) & 1);
    return (ushort)(r >> 16);
}
__device__ __forceinline__ float b2f(ushort u) {
    union { uint32_t u; float f; } x; x.u = (uint32_t)u << 16;
    return x.f;
}

// ---------------- LayerNorm (torch semantics: ddof=1, eps on std) -> bf16 ----
__global__ __launch_bounds__(256)
void ln_kernel(const float* __restrict__ x, const float* __restrict__ scale,
               const float* __restrict__ shift, ushort* __restrict__ y) {
    int row = blockIdx.x;
    const float* xr = x + (size_t)row * DD;
    ushort* yr = y + (size_t)row * DD;
    int t = threadIdx.x;
    float v[4];
    float s = 0.f, ss = 0.f;
#pragma unroll
    for (int i = 0; i < 4; ++i) {
        v[i] = xr[t + 256 * i];
        s += v[i];
        ss += v[i] * v[i];
    }
#pragma unroll
    for (int off = 32; off; off >>= 1) {
        s  += __shfl_xor(s, off);
        ss += __shfl_xor(ss, off);
    }
    __shared__ float red[8];
    int w = t >> 6;
    if ((t & 63) == 0) { red[w] = s; red[w + 4] = ss; }
    __syncthreads();
    float st  = red[0] + red[1] + red[2] + red[3];
    float sst = red[4] + red[5] + red[6] + red[7];
    float mu = st * (1.f / DD);
    float var = (sst - DD * mu * mu) * (1.f / (DD - 1));
    var = fmaxf(var, 0.f);
    float inv = 1.f / (sqrtf(var) + 1e-9f);
#pragma unroll
    for (int i = 0; i < 4; ++i) {
        int c = t + 256 * i;
        yr[c] = f2b(scale[c] * (v[i] - mu) * inv + shift[c]);
    }
}

// LN over (a_bf16 + b_fp32): writes bf16 (for FFN GEMM input AND residual)
__global__ __launch_bounds__(256)
void ln_res_kernel(const ushort* __restrict__ xa, const float* __restrict__ xb,
                   const float* __restrict__ scale, const float* __restrict__ shift,
                   ushort* __restrict__ yb) {
    int row = blockIdx.x;
    const ushort* ar = xa + (size_t)row * DD;
    const float* br = xb + (size_t)row * DD;
    ushort* ybr = yb + (size_t)row * DD;
    int t = threadIdx.x;
    float v[4];
    float s = 0.f, ss = 0.f;
#pragma unroll
    for (int i = 0; i < 4; ++i) {
        int c = t + 256 * i;
        v[i] = b2f(ar[c]) + br[c];
        s += v[i];
        ss += v[i] * v[i];
    }
#pragma unroll
    for (int off = 32; off; off >>= 1) {
        s  += __shfl_xor(s, off);
        ss += __shfl_xor(ss, off);
    }
    __shared__ float red[8];
    int w = t >> 6;
    if ((t & 63) == 0) { red[w] = s; red[w + 4] = ss; }
    __syncthreads();
    float st  = red[0] + red[1] + red[2] + red[3];
    float sst = red[4] + red[5] + red[6] + red[7];
    float mu = st * (1.f / DD);
    float var = (sst - DD * mu * mu) * (1.f / (DD - 1));
    var = fmaxf(var, 0.f);
    float inv = 1.f / (sqrtf(var) + 1e-9f);
#pragma unroll
    for (int i = 0; i < 4; ++i) {
        int c = t + 256 * i;
        ybr[c] = f2b(scale[c] * (v[i] - mu) * inv + shift[c]);
    }
}

// ---------------- fp32 -> bf16 transpose-convert for weights -----------------
__global__ __launch_bounds__(256)
void transpose_bf16_kernel(const float* __restrict__ W, ushort* __restrict__ Wt,
                           int K, int N) {
    __shared__ ushort tile[32][33];
    int tx = threadIdx.x & 31;
    int ty = threadIdx.x >> 5;      // 0..7
    int n0 = blockIdx.x * 32;
    int k0 = blockIdx.y * 32;
#pragma unroll
    for (int i = 0; i < 32; i += 8)
        tile[ty + i][tx] = f2b(W[(size_t)(k0 + ty + i) * N + n0 + tx]);
    __syncthreads();
#pragma unroll
    for (int i = 0; i < 32; i += 8)
        Wt[(size_t)(n0 + ty + i) * K + k0 + tx] = tile[tx][ty + i];
}

// ---------------- bf16 MFMA GEMM: 8 waves, DEPTH-deep counted-vmcnt ring -----
// C = A(MxK) @ Wt(NxK)^T + bias.  512 threads; wave grid 2x4, wave-tile 64x32.
// XCD-swizzled block ids (requires nwg%8==0).
// MODE 0: +bias (out per BF16_OUT); 1: +bias,relu; 2: +bias,+addsrc(bf16),fp32 out
// MODE 3: fused QKV epilogue (Cout=q, out2=k, out3=v-transposed; bias/2/3)
#define GBM 128
#define GBN 128
#define GBK 32

template <int MODE, bool BF16_OUT, int DEPTH>
__global__ __launch_bounds__(512)
void gemm_bf16_kernel(const ushort* __restrict__ A, const ushort* __restrict__ Wt,
                      const float* __restrict__ bias, const ushort* __restrict__ addsrc,
                      void* __restrict__ Cout, int M, int N, int K,
                      const float* __restrict__ bias2, const float* __restrict__ bias3,
                      void* __restrict__ out2, void* __restrict__ out3) {
    __shared__ ushort As[DEPTH][GBM * GBK];   // DEPTH x 8KB
    __shared__ ushort Bs[DEPTH][GBN * GBK];   // DEPTH x 8KB

    int tid = threadIdx.x;
    int lane = tid & 63;
    int wid = tid >> 6;              // 0..7
    int wr = wid >> 2, wc = wid & 3; // 2 x 4 wave grid

    // ---- bijective XCD swizzle ----
    int gx = gridDim.x;
    int nwg = gx * gridDim.y;
    int orig = blockIdx.y * gx + blockIdx.x;
    int q8 = nwg >> 3;                       // nwg % 8 == 0 guaranteed by launch
    int swz = (orig & 7) * q8 + (orig >> 3);
    int bx = swz % gx, by = swz / gx;

    int brow = by * GBM;
    int bcol = bx * GBN;

    int lrow = lane & 15;
    int kgrp = lane >> 4;

    f32x4 acc[4][2] = {};

    // staging: whole block loads A-tile with 1 instr, B-tile with 1 instr.
    // thread -> (row = tid>>2, gran = tid&3); wave w covers rows w*16..+15.
    int srow = tid >> 2;
    int sgran = (tid & 3) ^ ((srow >> 1) & 3);

    auto stage = [&](int buf, int k0) {
        const char* ga = (const char*)A +
            ((size_t)(brow + srow) * K + k0) * 2 + sgran * 16;
        __builtin_amdgcn_global_load_lds(
            (const __attribute__((address_space(1))) uint32_t*)ga,
            (__attribute__((address_space(3))) uint32_t*)(&As[buf][0] + (wid * 16) * GBK),
            16, 0, 0);
        const char* gb = (const char*)Wt +
            ((size_t)(bcol + srow) * K + k0) * 2 + sgran * 16;
        __builtin_amdgcn_global_load_lds(
            (const __attribute__((address_space(1))) uint32_t*)gb,
            (__attribute__((address_space(3))) uint32_t*)(&Bs[buf][0] + (wid * 16) * GBK),
            16, 0, 0);
    };

    int nk = K / GBK;
    constexpr int PRE = DEPTH - 1;           // stages in flight ahead of compute
#pragma unroll
    for (int s = 0; s < PRE; ++s)
        if (s < nk) stage(s, s * GBK);

    int cur = 0, stg = PRE;
    for (int t = 0; t < nk; ++t) {
        __builtin_amdgcn_sched_barrier(0);   // pin prev iter's ds_reads/MFMAs
        int rem = nk - 1 - t;                // stages still in flight beyond cur
        if constexpr (DEPTH == 5) {
            if (rem >= 3)      asm volatile("s_waitcnt vmcnt(6)" ::: "memory");
            else if (rem == 2) asm volatile("s_waitcnt vmcnt(4)" ::: "memory");
            else if (rem == 1) asm volatile("s_waitcnt vmcnt(2)" ::: "memory");
            else               asm volatile("s_waitcnt vmcnt(0)" ::: "memory");
        } else {
            if (rem >= 1)      asm volatile("s_waitcnt vmcnt(2)" ::: "memory");
            else               asm volatile("s_waitcnt vmcnt(0)" ::: "memory");
        }
        asm volatile("s_barrier" ::: "memory");          // no vmcnt drain
        if (t + PRE < nk) stage(stg, (t + PRE) * GBK);

        bf16x8 afrag[4], bfrag[2];
#pragma unroll
        for (int mi = 0; mi < 4; ++mi) {
            int row = wr * 64 + mi * 16 + lrow;
            int gran = kgrp ^ ((row >> 1) & 3);
            afrag[mi] = *(const bf16x8*)((const char*)&As[cur][0] + row * 64 + gran * 16);
        }
#pragma unroll
        for (int ni = 0; ni < 2; ++ni) {
            int row = wc * 32 + ni * 16 + lrow;
            int gran = kgrp ^ ((row >> 1) & 3);
            bfrag[ni] = *(const bf16x8*)((const char*)&Bs[cur][0] + row * 64 + gran * 16);
        }
#pragma unroll
        for (int mi = 0; mi < 4; ++mi)
#pragma unroll
            for (int ni = 0; ni < 2; ++ni)
                acc[mi][ni] = __builtin_amdgcn_mfma_f32_16x16x32_bf16(
                    afrag[mi], bfrag[ni], acc[mi][ni], 0, 0, 0);

        cur = (cur == DEPTH - 1) ? 0 : cur + 1;
        stg = (stg == DEPTH - 1) ? 0 : stg + 1;
    }

    if (MODE == 3) {
        int which = bcol >> 10;   // 0=q, 1=k, 2=v (128-tile never straddles)
        const float* bs = which == 0 ? bias : (which == 1 ? bias2 : bias3);
#pragma unroll
        for (int ni = 0; ni < 2; ++ni) {
            int col = bcol + wc * 32 + ni * 16 + lrow;
            int lcol = col & 1023;
            float bsv = bs[lcol];
#pragma unroll
            for (int mi = 0; mi < 4; ++mi) {
                f32x4 a = acc[mi][ni];
#pragma unroll
                for (int j = 0; j < 4; ++j) {
                    int row = brow + wr * 64 + mi * 16 + kgrp * 4 + j;
                    float val = a[j] + bsv;
                    if (which == 2) {
                        size_t idx = (size_t)(row >> 11) * ((size_t)DD * SS)
                                   + (size_t)lcol * SS + (row & (SS - 1));
                        ((ushort*)out3)[idx] = f2b(val);
                    } else {
                        ushort* dst = which == 0 ? (ushort*)Cout : (ushort*)out2;
                        dst[(size_t)row * DD + lcol] = f2b(val);
                    }
                }
            }
        }
        return;
    }

#pragma unroll
    for (int ni = 0; ni < 2; ++ni) {
        int col = bcol + wc * 32 + ni * 16 + lrow;
        float bsv = bias[col];
#pragma unroll
        for (int mi = 0; mi < 4; ++mi) {
            f32x4 a = acc[mi][ni];
#pragma unroll
            for (int j = 0; j < 4; ++j) {
                int row = brow + wr * 64 + mi * 16 + kgrp * 4 + j;
                float val = a[j] + bsv;
                if (MODE == 1) val = fmaxf(val, 0.f);
                if (MODE == 2) val += b2f(addsrc[(size_t)row * N + col]);
                if (BF16_OUT)
                    ((ushort*)Cout)[(size_t)row * N + col] = f2b(val);
                else
                    ((float*)Cout)[(size_t)row * N + col] = val;
            }
        }
    }
}

// ---------------- bf16 MFMA causal flash attention (3-deep ring) -------------
// Block: 4 waves per (b, h, 64-query tile); wave w owns q rows [w*16, w*16+16).
// K/V in a 3-buffer LDS ring; counted vmcnt keeps 1 stage in flight across the
// raw s_barrier. Grid: x=bh, y=q-tile (reversed: heavy tiles dispatch first).
__global__ __launch_bounds__(256)
void attn_mfma_kernel(const ushort* __restrict__ Qg, const ushort* __restrict__ Kg,
                      const ushort* __restrict__ Vtg, ushort* __restrict__ Og) {
    __shared__ ushort Qs[64 * 64];        // 8KB
    __shared__ ushort Ks[3][64 * 64];     // 24KB
    __shared__ ushort Vs[3][64 * 64];     // 24KB
    __shared__ ushort Ps[64 * 64];        // 8KB (wave-private slabs)

    int tid = threadIdx.x;
    int lane = tid & 63;
    int wid = tid >> 6;
    int bh = blockIdx.x;
    int b = bh >> 4, h = bh & 15;
    int q0 = ((int)gridDim.y - 1 - (int)blockIdx.y) * 64;   // heavy tiles first

    const ushort* Qbase = Qg + ((size_t)(b * SS + q0)) * DD + h * DH;
    const ushort* Kbase = Kg + ((size_t)(b * SS)) * DD + h * DH;
    const ushort* Vbase = Vtg + (size_t)bh * DH * SS;        // rows: d, stride SS

    int r0 = wid * 16;
    int rr0 = r0 + (lane >> 3);
    int g0 = lane & 7;

    // each wave issues exactly 4 global_load_lds per stage
    auto stageKV = [&](int buf, int k0) {
#pragma unroll
        for (int i = 0; i < 2; ++i) {
            int rr = rr0 + i * 8;
            int g = g0 ^ (rr & 7);
            const ushort* srck = Kbase + (size_t)(k0 + rr) * DD + g * 8;
            __builtin_amdgcn_global_load_lds(
                (const __attribute__((address_space(1))) uint32_t*)srck,
                (__attribute__((address_space(3))) uint32_t*)(&Ks[buf][0] + (r0 + i * 8) * 64),
                16, 0, 0);
            const ushort* srcv = Vbase + (size_t)rr * SS + k0 + g * 8;
            __builtin_amdgcn_global_load_lds(
                (const __attribute__((address_space(1))) uint32_t*)srcv,
                (__attribute__((address_space(3))) uint32_t*)(&Vs[buf][0] + (r0 + i * 8) * 64),
                16, 0, 0);
        }
    };

    int nt = q0 / 64 + 1;

    // ---- prologue: Q (2 loads/wave) + up to 2 K/V stages ----
    {
#pragma unroll
        for (int i = 0; i < 2; ++i) {
            int rr = rr0 + i * 8;
            int g = g0 ^ (rr & 7);
            const ushort* src = Qbase + (size_t)rr * DD + g * 8;
            __builtin_amdgcn_global_load_lds(
                (const __attribute__((address_space(1))) uint32_t*)src,
                (__attribute__((address_space(3))) uint32_t*)(Qs + (r0 + i * 8) * 64),
                16, 0, 0);
        }
    }
    stageKV(0, 0);
    if (nt > 1) stageKV(1, 64);
    __builtin_amdgcn_sched_barrier(0);
    if (nt > 1) asm volatile("s_waitcnt vmcnt(8)" ::: "memory");   // Q landed
    else        asm volatile("s_waitcnt vmcnt(4)" ::: "memory");
    asm volatile("s_barrier" ::: "memory");

    // ---- hoist Q A-fragments ----
    bf16x8 aq[2];
    {
        int r = wid * 16 + (lane & 15);
#pragma unroll
        for (int ks = 0; ks < 2; ++ks) {
            int lg = ks * 4 + (lane >> 4);
            aq[ks] = *(const bf16x8*)((const char*)Qs + r * 128 + ((lg ^ (r & 7)) << 4));
        }
    }

    f32x4 oacc[4] = {};
    float m[4] = {-INFINITY, -INFINITY, -INFINITY, -INFINITY};
    float l[4] = {0.f, 0.f, 0.f, 0.f};

    int cur = 0, stg = 2;
    for (int t = 0; t < nt; ++t) {
        __builtin_amdgcn_sched_barrier(0);
        if (t + 1 < nt) asm volatile("s_waitcnt vmcnt(4)" ::: "memory");
        else            asm volatile("s_waitcnt vmcnt(0)" ::: "memory");
        asm volatile("s_barrier" ::: "memory");
        if (t + 2 < nt) stageKV(stg, (t + 2) * 64);
        int k0 = t * 64;

        // ---- S = Q @ K^T ----
        f32x4 sacc[4] = {};
#pragma unroll
        for (int ni = 0; ni < 4; ++ni) {
            int r = ni * 16 + (lane & 15);
#pragma unroll
            for (int ks = 0; ks < 2; ++ks) {
                int lg = ks * 4 + (lane >> 4);
                bf16x8 bk = *(const bf16x8*)((const char*)&Ks[cur][0] + r * 128 + ((lg ^ (r & 7)) << 4));
                sacc[ni] = __builtin_amdgcn_mfma_f32_16x16x32_bf16(aq[ks], bk, sacc[ni], 0, 0, 0);
            }
        }

        // ---- scale + causal mask (diagonal tile only) ----
        float sc[4][4];
#pragma unroll
        for (int ni = 0; ni < 4; ++ni)
#pragma unroll
            for (int j = 0; j < 4; ++j)
                sc[ni][j] = sacc[ni][j] * 0.125f;
        if (k0 == q0) {
            int rl = wid * 16 + ((lane >> 4) << 2);
#pragma unroll
            for (int ni = 0; ni < 4; ++ni) {
                int key = ni * 16 + (lane & 15);
#pragma unroll
                for (int j = 0; j < 4; ++j)
                    if (key > rl + j) sc[ni][j] = -INFINITY;
            }
        }

        // ---- online softmax (rows spread over 16 lanes) ----
        float p[4][4];
#pragma unroll
        for (int j = 0; j < 4; ++j) {
            float mx = fmaxf(fmaxf(sc[0][j], sc[1][j]), fmaxf(sc[2][j], sc[3][j]));
#pragma unroll
            for (int off = 1; off < 16; off <<= 1) mx = fmaxf(mx, __shfl_xor(mx, off));
            float mn = fmaxf(m[j], mx);
            float corr = __expf(m[j] - mn);
            m[j] = mn;
            float rs = 0.f;
#pragma unroll
            for (int ni = 0; ni < 4; ++ni) { p[ni][j] = __expf(sc[ni][j] - mn); rs += p[ni][j]; }
#pragma unroll
            for (int off = 1; off < 16; off <<= 1) rs += __shfl_xor(rs, off);
            l[j] = l[j] * corr + rs;
#pragma unroll
            for (int ni = 0; ni < 4; ++ni) oacc[ni][j] *= corr;
        }

        // ---- P -> bf16 -> wave-private LDS slab ----
        {
            int rbase = wid * 16 + ((lane >> 4) << 2);
            int cl = lane & 15;
#pragma unroll
            for (int ni = 0; ni < 4; ++ni) {
                int c = ni * 16 + cl;
                int gsh = (c >> 3);
                int blo = (c & 7) * 2;
#pragma unroll
                for (int j = 0; j < 4; ++j) {
                    int rl = rbase + j;
                    *(ushort*)((char*)Ps + rl * 128 + ((gsh ^ (rl & 7)) << 4) + blo) = f2b(p[ni][j]);
                }
            }
        }
        asm volatile("s_waitcnt lgkmcnt(0)" ::: "memory");   // wave-local P landed

        // ---- O += P @ V ----
        bf16x8 ap[2];
        {
            int r = wid * 16 + (lane & 15);
#pragma unroll
            for (int ks = 0; ks < 2; ++ks) {
                int lg = ks * 4 + (lane >> 4);
                ap[ks] = *(const bf16x8*)((const char*)Ps + r * 128 + ((lg ^ (r & 7)) << 4));
            }
        }
#pragma unroll
        for (int ni = 0; ni < 4; ++ni) {
            int r = ni * 16 + (lane & 15);
#pragma unroll
            for (int ks = 0; ks < 2; ++ks) {
                int lg = ks * 4 + (lane >> 4);
                bf16x8 bv = *(const bf16x8*)((const char*)&Vs[cur][0] + r * 128 + ((lg ^ (r & 7)) << 4));
                oacc[ni] = __builtin_amdgcn_mfma_f32_16x16x32_bf16(ap[ks], bv, oacc[ni], 0, 0, 0);
            }
        }
        cur = (cur == 2) ? 0 : cur + 1;
        stg = (stg == 2) ? 0 : stg + 1;
    }

    // ---- epilogue: divide by l, write bf16 ----
#pragma unroll
    for (int j = 0; j < 4; ++j) {
        float inv = 1.f / l[j];
        int gr = q0 + wid * 16 + ((lane >> 4) << 2) + j;
#pragma unroll
        for (int ni = 0; ni < 4; ++ni) {
            int d = ni * 16 + (lane & 15);
            Og[((size_t)(b * SS + gr)) * DD + h * DH + d] = f2b(oacc[ni][j] * inv);
        }
    }
}

// ---------------- Launch ------------------------------------------------------
extern "C" void kernel_launch(void* const* d_in, const int* in_sizes, int n_in,
                              void* d_out, int out_size, void* d_ws, size_t ws_size,
                              hipStream_t stream) {
    const float* inputs    = (const float*)d_in[0];
    const float* ln1_scale = (const float*)d_in[1];
    const float* ln1_shift = (const float*)d_in[2];
    const float* Wq = (const float*)d_in[3];
    const float* bq = (const float*)d_in[4];
    const float* Wk = (const float*)d_in[5];
    const float* bk = (const float*)d_in[6];
    const float* Wv = (const float*)d_in[7];
    const float* bv = (const float*)d_in[8];
    const float* Wo = (const float*)d_in[9];
    const float* bo = (const float*)d_in[10];
    const float* W1 = (const float*)d_in[11];
    const float* b1 = (const float*)d_in[12];
    const float* W2 = (const float*)d_in[13];
    const float* b2 = (const float*)d_in[14];
    const float* ln2_scale = (const float*)d_in[15];
    const float* ln2_shift = (const float*)d_in[16];
    float* out = (float*)d_out;

    const size_t MB = 1024 * 1024;
    char* w = (char*)d_ws;
    ushort* q_b   = (ushort*)(w + 0 * MB);     // 8MB
    ushort* k_b   = (ushort*)(w + 8 * MB);     // 8MB
    ushort* vt_b  = (ushort*)(w + 16 * MB);    // 8MB
    ushort* att_b = (ushort*)(w + 24 * MB);    // 8MB
    ushort* proj_b= (ushort*)(w + 32 * MB);    // 8MB
    ushort* o2_b  = (ushort*)(w + 48 * MB);    // 8MB
    ushort* h1_b  = (ushort*)(w + 64 * MB);    // 32MB
    ushort* wq_t  = (ushort*)(w + 96 * MB);    // 2MB  (q/k/v contiguous = fused 3072xK)
    ushort* wk_t  = (ushort*)(w + 98 * MB);
    ushort* wv_t  = (ushort*)(w + 100 * MB);
    ushort* wo_t  = (ushort*)(w + 102 * MB);
    ushort* w1_t  = (ushort*)(w + 104 * MB);   // 8MB
    ushort* w2_t  = (ushort*)(w + 112 * MB);   // 8MB
    ushort* xn_b  = (ushort*)(w + 120 * MB);   // 8MB

    // 0. weight convert+transpose
    transpose_bf16_kernel<<<dim3(DD / 32, DD / 32), 256, 0, stream>>>(Wq, wq_t, DD, DD);
    transpose_bf16_kernel<<<dim3(DD / 32, DD / 32), 256, 0, stream>>>(Wk, wk_t, DD, DD);
    transpose_bf16_kernel<<<dim3(DD / 32, DD / 32), 256, 0, stream>>>(Wv, wv_t, DD, DD);
    transpose_bf16_kernel<<<dim3(DD / 32, DD / 32), 256, 0, stream>>>(Wo, wo_t, DD, DD);
    transpose_bf16_kernel<<<dim3(FFN / 32, DD / 32), 256, 0, stream>>>(W1, w1_t, DD, FFN);
    transpose_bf16_kernel<<<dim3(DD / 32, FFN / 32), 256, 0, stream>>>(W2, w2_t, FFN, DD);

    // 1. LN1 -> bf16
    ln_kernel<<<NROW, 256, 0, stream>>>(inputs, ln1_scale, ln1_shift, xn_b);

    // 2. Fused QKV projection (N=3072; V written transposed per head). 768 blk.
    dim3 gqkv(3 * DD / GBN, NROW / GBM);   // 24 x 32
    gemm_bf16_kernel<3, true, 3><<<gqkv, 512, 0, stream>>>(
        xn_b, wq_t, bq, nullptr, q_b, NROW, 3 * DD, DD, bk, bv, k_b, vt_b);

    // 3. MFMA flash attention -> att_b (bf16)
    dim3 ga(BB * HH, SS / 64);
    attn_mfma_kernel<<<ga, 256, 0, stream>>>(q_b, k_b, vt_b, att_b);

    // 4. Output projection -> proj (bf16). 256 blocks -> depth-5 ring.
    dim3 g1(DD / GBN, NROW / GBM);
    gemm_bf16_kernel<0, true, 5><<<g1, 512, 0, stream>>>(
        att_b, wo_t, bo, nullptr, proj_b, NROW, DD, DD, nullptr, nullptr, nullptr, nullptr);

    // 5. residual + LN2 -> o2 (bf16, serves as GEMM input AND final residual)
    ln_res_kernel<<<NROW, 256, 0, stream>>>(proj_b, inputs, ln2_scale, ln2_shift, o2_b);

    // 6. FFN up + relu -> h1 (bf16). 1024 blocks -> depth-3.
    dim3 g2(FFN / GBN, NROW / GBM);
    gemm_bf16_kernel<1, true, 3><<<g2, 512, 0, stream>>>(
        o2_b, w1_t, b1, nullptr, h1_b, NROW, FFN, DD, nullptr, nullptr, nullptr, nullptr);

    // 7. FFN down + bias + o2 -> out (fp32). 256 blocks -> depth-5 ring.
    gemm_bf16_kernel<2, false, 5><<<g1, 512, 0, stream>>>(
        h1_b, w2_t, b2, o2_b, out, NROW, DD, FFN, nullptr, nullptr, nullptr, nullptr);
}

// Round 9
// 267.968 us; speedup vs baseline: 23.2260x; 1.0574x over previous
//
#include <hip/hip_runtime.h>
#include <hip/hip_bf16.h>
#include <math.h>

// Problem constants
#define BB 2
#define SS 2048
#define DD 1024
#define HH 16
#define DH 64
#define NROW (BB*SS)          // 4096
#define FFN (4*DD)            // 4096

typedef __attribute__((ext_vector_type(8))) __bf16 bf16x8;
typedef __attribute__((ext_vector_type(4))) float f32x4;

__device__ __forceinline__ ushort f2b(float f) {
    union { float f; uint32_t u; } x; x.f = f;
    uint32_t r = x.u + 0x7FFF + ((x.u >> 16) & 1);
    return (ushort)(r >> 16);
}
__device__ __forceinline__ float b2f(ushort u) {
    union { uint32_t u; float f; } x; x.u = (uint32_t)u << 16;
    return x.f;
}

// ---------------- LayerNorm (torch semantics: ddof=1, eps on std) -> bf16 ----
__global__ __launch_bounds__(256)
void ln_kernel(const float* __restrict__ x, const float* __restrict__ scale,
               const float* __restrict__ shift, ushort* __restrict__ y) {
    int row = blockIdx.x;
    const float* xr = x + (size_t)row * DD;
    ushort* yr = y + (size_t)row * DD;
    int t = threadIdx.x;
    float v[4];
    float s = 0.f, ss = 0.f;
#pragma unroll
    for (int i = 0; i < 4; ++i) {
        v[i] = xr[t + 256 * i];
        s += v[i];
        ss += v[i] * v[i];
    }
#pragma unroll
    for (int off = 32; off; off >>= 1) {
        s  += __shfl_xor(s, off);
        ss += __shfl_xor(ss, off);
    }
    __shared__ float red[8];
    int w = t >> 6;
    if ((t & 63) == 0) { red[w] = s; red[w + 4] = ss; }
    __syncthreads();
    float st  = red[0] + red[1] + red[2] + red[3];
    float sst = red[4] + red[5] + red[6] + red[7];
    float mu = st * (1.f / DD);
    float var = (sst - DD * mu * mu) * (1.f / (DD - 1));
    var = fmaxf(var, 0.f);
    float inv = 1.f / (sqrtf(var) + 1e-9f);
#pragma unroll
    for (int i = 0; i < 4; ++i) {
        int c = t + 256 * i;
        yr[c] = f2b(scale[c] * (v[i] - mu) * inv + shift[c]);
    }
}

// LN over (a_bf16 + b_fp32): writes bf16 (for FFN GEMM input AND residual)
__global__ __launch_bounds__(256)
void ln_res_kernel(const ushort* __restrict__ xa, const float* __restrict__ xb,
                   const float* __restrict__ scale, const float* __restrict__ shift,
                   ushort* __restrict__ yb) {
    int row = blockIdx.x;
    const ushort* ar = xa + (size_t)row * DD;
    const float* br = xb + (size_t)row * DD;
    ushort* ybr = yb + (size_t)row * DD;
    int t = threadIdx.x;
    float v[4];
    float s = 0.f, ss = 0.f;
#pragma unroll
    for (int i = 0; i < 4; ++i) {
        int c = t + 256 * i;
        v[i] = b2f(ar[c]) + br[c];
        s += v[i];
        ss += v[i] * v[i];
    }
#pragma unroll
    for (int off = 32; off; off >>= 1) {
        s  += __shfl_xor(s, off);
        ss += __shfl_xor(ss, off);
    }
    __shared__ float red[8];
    int w = t >> 6;
    if ((t & 63) == 0) { red[w] = s; red[w + 4] = ss; }
    __syncthreads();
    float st  = red[0] + red[1] + red[2] + red[3];
    float sst = red[4] + red[5] + red[6] + red[7];
    float mu = st * (1.f / DD);
    float var = (sst - DD * mu * mu) * (1.f / (DD - 1));
    var = fmaxf(var, 0.f);
    float inv = 1.f / (sqrtf(var) + 1e-9f);
#pragma unroll
    for (int i = 0; i < 4; ++i) {
        int c = t + 256 * i;
        ybr[c] = f2b(scale[c] * (v[i] - mu) * inv + shift[c]);
    }
}

// ---------------- fp32 -> bf16 transpose-convert for weights -----------------
__global__ __launch_bounds__(256)
void transpose_bf16_kernel(const float* __restrict__ W, ushort* __restrict__ Wt,
                           int K, int N) {
    __shared__ ushort tile[32][33];
    int tx = threadIdx.x & 31;
    int ty = threadIdx.x >> 5;      // 0..7
    int n0 = blockIdx.x * 32;
    int k0 = blockIdx.y * 32;
#pragma unroll
    for (int i = 0; i < 32; i += 8)
        tile[ty + i][tx] = f2b(W[(size_t)(k0 + ty + i) * N + n0 + tx]);
    __syncthreads();
#pragma unroll
    for (int i = 0; i < 32; i += 8)
        Wt[(size_t)(n0 + ty + i) * K + k0 + tx] = tile[tx][ty + i];
}

// ---------------- bf16 MFMA GEMM: 8 waves, DEPTH-deep counted-vmcnt ring -----
// C = A(MxK) @ Wt(NxK)^T + bias.  512 threads; wave grid 2x4, wave-tile 64x32.
// XCD-swizzled block ids (requires nwg%8==0).
// MODE 0: +bias (out per BF16_OUT); 1: +bias,relu; 2: +bias,+addsrc(bf16),fp32 out
// MODE 3: fused QKV epilogue (Cout=q, out2=k, out3=v-transposed; bias/2/3)
#define GBM 128
#define GBN 128
#define GBK 32

template <int MODE, bool BF16_OUT, int DEPTH>
__global__ __launch_bounds__(512)
void gemm_bf16_kernel(const ushort* __restrict__ A, const ushort* __restrict__ Wt,
                      const float* __restrict__ bias, const ushort* __restrict__ addsrc,
                      void* __restrict__ Cout, int M, int N, int K,
                      const float* __restrict__ bias2, const float* __restrict__ bias3,
                      void* __restrict__ out2, void* __restrict__ out3) {
    __shared__ ushort As[DEPTH][GBM * GBK];   // DEPTH x 8KB
    __shared__ ushort Bs[DEPTH][GBN * GBK];   // DEPTH x 8KB

    int tid = threadIdx.x;
    int lane = tid & 63;
    int wid = tid >> 6;              // 0..7
    int wr = wid >> 2, wc = wid & 3; // 2 x 4 wave grid

    // ---- bijective XCD swizzle ----
    int gx = gridDim.x;
    int nwg = gx * gridDim.y;
    int orig = blockIdx.y * gx + blockIdx.x;
    int q8 = nwg >> 3;                       // nwg % 8 == 0 guaranteed by launch
    int swz = (orig & 7) * q8 + (orig >> 3);
    int bx = swz % gx, by = swz / gx;

    int brow = by * GBM;
    int bcol = bx * GBN;

    int lrow = lane & 15;
    int kgrp = lane >> 4;

    f32x4 acc[4][2] = {};

    // staging: whole block loads A-tile with 1 instr, B-tile with 1 instr.
    // thread -> (row = tid>>2, gran = tid&3); wave w covers rows w*16..+15.
    int srow = tid >> 2;
    int sgran = (tid & 3) ^ ((srow >> 1) & 3);

    auto stage = [&](int buf, int k0) {
        const char* ga = (const char*)A +
            ((size_t)(brow + srow) * K + k0) * 2 + sgran * 16;
        __builtin_amdgcn_global_load_lds(
            (const __attribute__((address_space(1))) uint32_t*)ga,
            (__attribute__((address_space(3))) uint32_t*)(&As[buf][0] + (wid * 16) * GBK),
            16, 0, 0);
        const char* gb = (const char*)Wt +
            ((size_t)(bcol + srow) * K + k0) * 2 + sgran * 16;
        __builtin_amdgcn_global_load_lds(
            (const __attribute__((address_space(1))) uint32_t*)gb,
            (__attribute__((address_space(3))) uint32_t*)(&Bs[buf][0] + (wid * 16) * GBK),
            16, 0, 0);
    };

    int nk = K / GBK;
    constexpr int PRE = DEPTH - 1;           // stages in flight ahead of compute
#pragma unroll
    for (int s = 0; s < PRE; ++s)
        if (s < nk) stage(s, s * GBK);

    int cur = 0, stg = PRE;
    for (int t = 0; t < nk; ++t) {
        __builtin_amdgcn_sched_barrier(0);   // pin prev iter's ds_reads/MFMAs
        int rem = nk - 1 - t;                // stages still in flight beyond cur
        if constexpr (DEPTH == 5) {
            if (rem >= 3)      asm volatile("s_waitcnt vmcnt(6)" ::: "memory");
            else if (rem == 2) asm volatile("s_waitcnt vmcnt(4)" ::: "memory");
            else if (rem == 1) asm volatile("s_waitcnt vmcnt(2)" ::: "memory");
            else               asm volatile("s_waitcnt vmcnt(0)" ::: "memory");
        } else {
            if (rem >= 1)      asm volatile("s_waitcnt vmcnt(2)" ::: "memory");
            else               asm volatile("s_waitcnt vmcnt(0)" ::: "memory");
        }
        asm volatile("s_barrier" ::: "memory");          // no vmcnt drain
        if (t + PRE < nk) stage(stg, (t + PRE) * GBK);

        bf16x8 afrag[4], bfrag[2];
#pragma unroll
        for (int mi = 0; mi < 4; ++mi) {
            int row = wr * 64 + mi * 16 + lrow;
            int gran = kgrp ^ ((row >> 1) & 3);
            afrag[mi] = *(const bf16x8*)((const char*)&As[cur][0] + row * 64 + gran * 16);
        }
#pragma unroll
        for (int ni = 0; ni < 2; ++ni) {
            int row = wc * 32 + ni * 16 + lrow;
            int gran = kgrp ^ ((row >> 1) & 3);
            bfrag[ni] = *(const bf16x8*)((const char*)&Bs[cur][0] + row * 64 + gran * 16);
        }
#pragma unroll
        for (int mi = 0; mi < 4; ++mi)
#pragma unroll
            for (int ni = 0; ni < 2; ++ni)
                acc[mi][ni] = __builtin_amdgcn_mfma_f32_16x16x32_bf16(
                    afrag[mi], bfrag[ni], acc[mi][ni], 0, 0, 0);

        cur = (cur == DEPTH - 1) ? 0 : cur + 1;
        stg = (stg == DEPTH - 1) ? 0 : stg + 1;
    }

    if (MODE == 3) {
        int which = bcol >> 10;   // 0=q, 1=k, 2=v (128-tile never straddles)
        const float* bs = which == 0 ? bias : (which == 1 ? bias2 : bias3);
#pragma unroll
        for (int ni = 0; ni < 2; ++ni) {
            int col = bcol + wc * 32 + ni * 16 + lrow;
            int lcol = col & 1023;
            float bsv = bs[lcol];
#pragma unroll
            for (int mi = 0; mi < 4; ++mi) {
                f32x4 a = acc[mi][ni];
#pragma unroll
                for (int j = 0; j < 4; ++j) {
                    int row = brow + wr * 64 + mi * 16 + kgrp * 4 + j;
                    float val = a[j] + bsv;
                    if (which == 2) {
                        size_t idx = (size_t)(row >> 11) * ((size_t)DD * SS)
                                   + (size_t)lcol * SS + (row & (SS - 1));
                        ((ushort*)out3)[idx] = f2b(val);
                    } else {
                        ushort* dst = which == 0 ? (ushort*)Cout : (ushort*)out2;
                        dst[(size_t)row * DD + lcol] = f2b(val);
                    }
                }
            }
        }
        return;
    }

#pragma unroll
    for (int ni = 0; ni < 2; ++ni) {
        int col = bcol + wc * 32 + ni * 16 + lrow;
        float bsv = bias[col];
#pragma unroll
        for (int mi = 0; mi < 4; ++mi) {
            f32x4 a = acc[mi][ni];
#pragma unroll
            for (int j = 0; j < 4; ++j) {
                int row = brow + wr * 64 + mi * 16 + kgrp * 4 + j;
                float val = a[j] + bsv;
                if (MODE == 1) val = fmaxf(val, 0.f);
                if (MODE == 2) val += b2f(addsrc[(size_t)row * N + col]);
                if (BF16_OUT)
                    ((ushort*)Cout)[(size_t)row * N + col] = f2b(val);
                else
                    ((float*)Cout)[(size_t)row * N + col] = val;
            }
        }
    }
}

// ---------------- bf16 MFMA causal flash attention (swapped QK^T) ------------
// Block: 4 waves per (b, h, 64-query tile); wave w owns q rows [w*16, w*16+16).
// S^T = mfma(K, Q): lane&15 = q-row -> softmax row stats are per-lane scalars
// (in-thread reduce over 16 keys + xor16/xor32). K/V double-buffered (depth-2);
// Ps overlays dead Qs. LDS = 40KB -> 4 blocks/CU.
__global__ __launch_bounds__(256)
void attn_mfma_kernel(const ushort* __restrict__ Qg, const ushort* __restrict__ Kg,
                      const ushort* __restrict__ Vtg, ushort* __restrict__ Og) {
    __shared__ ushort Qs[64 * 64];        // 8KB; reused as Ps after Q hoist
    __shared__ ushort Ks[2][64 * 64];     // 16KB
    __shared__ ushort Vs[2][64 * 64];     // 16KB

    int tid = threadIdx.x;
    int lane = tid & 63;
    int wid = tid >> 6;
    int bh = blockIdx.x;
    int b = bh >> 4, h = bh & 15;
    int q0 = ((int)gridDim.y - 1 - (int)blockIdx.y) * 64;   // heavy tiles first

    const ushort* Qbase = Qg + ((size_t)(b * SS + q0)) * DD + h * DH;
    const ushort* Kbase = Kg + ((size_t)(b * SS)) * DD + h * DH;
    const ushort* Vbase = Vtg + (size_t)bh * DH * SS;        // rows: d, stride SS

    int r0 = wid * 16;
    int rr0 = r0 + (lane >> 3);
    int g0 = lane & 7;
    int g = lane >> 4;               // 0..3 lane group
    int lr = lane & 15;              // q-row within wave (swapped layout)

    // each wave issues exactly 4 global_load_lds per stage
    auto stageKV = [&](int buf, int k0) {
#pragma unroll
        for (int i = 0; i < 2; ++i) {
            int rr = rr0 + i * 8;
            int gg = g0 ^ (rr & 7);
            const ushort* srck = Kbase + (size_t)(k0 + rr) * DD + gg * 8;
            __builtin_amdgcn_global_load_lds(
                (const __attribute__((address_space(1))) uint32_t*)srck,
                (__attribute__((address_space(3))) uint32_t*)(&Ks[buf][0] + (r0 + i * 8) * 64),
                16, 0, 0);
            const ushort* srcv = Vbase + (size_t)rr * SS + k0 + gg * 8;
            __builtin_amdgcn_global_load_lds(
                (const __attribute__((address_space(1))) uint32_t*)srcv,
                (__attribute__((address_space(3))) uint32_t*)(&Vs[buf][0] + (r0 + i * 8) * 64),
                16, 0, 0);
        }
    };

    int nt = q0 / 64 + 1;

    // ---- prologue: Q (2 loads/wave, wave-local) + first K/V stage ----
    {
#pragma unroll
        for (int i = 0; i < 2; ++i) {
            int rr = rr0 + i * 8;
            int gg = g0 ^ (rr & 7);
            const ushort* src = Qbase + (size_t)rr * DD + gg * 8;
            __builtin_amdgcn_global_load_lds(
                (const __attribute__((address_space(1))) uint32_t*)src,
                (__attribute__((address_space(3))) uint32_t*)(Qs + (r0 + i * 8) * 64),
                16, 0, 0);
        }
    }
    stageKV(0, 0);
    asm volatile("s_waitcnt vmcnt(4)" ::: "memory");   // own Q rows landed (wave-local)

    // ---- hoist Q B-fragments (rows=q, k-major) ----
    bf16x8 aq[2];
    {
        int r = wid * 16 + lr;
#pragma unroll
        for (int ks = 0; ks < 2; ++ks) {
            int lg = ks * 4 + g;
            aq[ks] = *(const bf16x8*)((const char*)Qs + r * 128 + ((lg ^ (r & 7)) << 4));
        }
    }
    ushort* Ps = Qs;                 // Q dead in LDS from here

    f32x4 oacc[4] = {};
    float m = -INFINITY, l = 0.f;
    int qa = q0 + wid * 16 + lr;     // absolute q row for this lane

    int cur = 0;
    for (int t = 0; t < nt; ++t) {
        __builtin_amdgcn_sched_barrier(0);
        asm volatile("s_waitcnt vmcnt(0)" ::: "memory");   // stage(t) landed
        asm volatile("s_barrier" ::: "memory");
        if (t + 1 < nt) stageKV(cur ^ 1, (t + 1) * 64);
        int k0 = t * 64;

        // ---- S^T = K @ Q^T : col(lane&15)=q-row, row=key ----
        f32x4 sacc[4] = {};
        __builtin_amdgcn_s_setprio(1);
#pragma unroll
        for (int ni = 0; ni < 4; ++ni) {
            int r = ni * 16 + lr;    // key row in K tile
#pragma unroll
            for (int ks = 0; ks < 2; ++ks) {
                int lg = ks * 4 + g;
                bf16x8 bk = *(const bf16x8*)((const char*)&Ks[cur][0] + r * 128 + ((lg ^ (r & 7)) << 4));
                sacc[ni] = __builtin_amdgcn_mfma_f32_16x16x32_bf16(bk, aq[ks], sacc[ni], 0, 0, 0);
            }
        }
        __builtin_amdgcn_s_setprio(0);

        // ---- scale + causal mask (diagonal tile only) ----
        float sc[4][4];
#pragma unroll
        for (int ni = 0; ni < 4; ++ni)
#pragma unroll
            for (int j = 0; j < 4; ++j)
                sc[ni][j] = sacc[ni][j] * 0.125f;
        if (k0 == q0) {
#pragma unroll
            for (int ni = 0; ni < 4; ++ni) {
#pragma unroll
                for (int j = 0; j < 4; ++j) {
                    int key = q0 + ni * 16 + g * 4 + j;
                    if (key > qa) sc[ni][j] = -INFINITY;
                }
            }
        }

        // ---- online softmax: per-lane scalar row stats ----
        float mx = sc[0][0];
#pragma unroll
        for (int ni = 0; ni < 4; ++ni)
#pragma unroll
            for (int j = 0; j < 4; ++j) mx = fmaxf(mx, sc[ni][j]);
        mx = fmaxf(mx, __shfl_xor(mx, 16));
        mx = fmaxf(mx, __shfl_xor(mx, 32));
        float mn = fmaxf(m, mx);
        float corr = __expf(m - mn);
        m = mn;
        float p[4][4];
        float rs = 0.f;
#pragma unroll
        for (int ni = 0; ni < 4; ++ni)
#pragma unroll
            for (int j = 0; j < 4; ++j) { p[ni][j] = __expf(sc[ni][j] - mn); rs += p[ni][j]; }
        rs += __shfl_xor(rs, 16);
        rs += __shfl_xor(rs, 32);
        l = l * corr + rs;

        // broadcast corr to oacc row layout (row = g*4+j held as q=lane&15)
        float cj[4];
#pragma unroll
        for (int j = 0; j < 4; ++j)
            cj[j] = __shfl(corr, (lane & 48) | (g * 4 + j));
#pragma unroll
        for (int ni = 0; ni < 4; ++ni)
#pragma unroll
            for (int j = 0; j < 4; ++j) oacc[ni][j] *= cj[j];

        // ---- P -> bf16 -> wave-private LDS slab (4 x ds_write_b64) ----
        {
            int row = wid * 16 + lr;
#pragma unroll
            for (int ni = 0; ni < 4; ++ni) {
                ushort4 w4;
                w4.x = f2b(p[ni][0]); w4.y = f2b(p[ni][1]);
                w4.z = f2b(p[ni][2]); w4.w = f2b(p[ni][3]);
                int gran = (ni * 2 + (g >> 1)) ^ (row & 7);
                *(ushort4*)((char*)Ps + row * 128 + (gran << 4) + (g & 1) * 8) = w4;
            }
        }
        asm volatile("s_waitcnt lgkmcnt(0)" ::: "memory");   // wave-local P landed

        // ---- O += P @ V ----
        bf16x8 ap[2];
        {
            int r = wid * 16 + lr;
#pragma unroll
            for (int ks = 0; ks < 2; ++ks) {
                int lg = ks * 4 + g;
                ap[ks] = *(const bf16x8*)((const char*)Ps + r * 128 + ((lg ^ (r & 7)) << 4));
            }
        }
        __builtin_amdgcn_s_setprio(1);
#pragma unroll
        for (int ni = 0; ni < 4; ++ni) {
            int r = ni * 16 + lr;    // d row in Vt tile
#pragma unroll
            for (int ks = 0; ks < 2; ++ks) {
                int lg = ks * 4 + g;
                bf16x8 bv = *(const bf16x8*)((const char*)&Vs[cur][0] + r * 128 + ((lg ^ (r & 7)) << 4));
                oacc[ni] = __builtin_amdgcn_mfma_f32_16x16x32_bf16(ap[ks], bv, oacc[ni], 0, 0, 0);
            }
        }
        __builtin_amdgcn_s_setprio(0);
        cur ^= 1;
    }

    // ---- epilogue: divide by l (broadcast per row), write bf16 ----
#pragma unroll
    for (int j = 0; j < 4; ++j) {
        float lj = __shfl(l, (lane & 48) | (g * 4 + j));
        float inv = 1.f / lj;
        int gr = q0 + wid * 16 + g * 4 + j;
#pragma unroll
        for (int ni = 0; ni < 4; ++ni) {
            int d = ni * 16 + lr;
            Og[((size_t)(b * SS + gr)) * DD + h * DH + d] = f2b(oacc[ni][j] * inv);
        }
    }
}

// ---------------- Launch ------------------------------------------------------
extern "C" void kernel_launch(void* const* d_in, const int* in_sizes, int n_in,
                              void* d_out, int out_size, void* d_ws, size_t ws_size,
                              hipStream_t stream) {
    const float* inputs    = (const float*)d_in[0];
    const float* ln1_scale = (const float*)d_in[1];
    const float* ln1_shift = (const float*)d_in[2];
    const float* Wq = (const float*)d_in[3];
    const float* bq = (const float*)d_in[4];
    const float* Wk = (const float*)d_in[5];
    const float* bk = (const float*)d_in[6];
    const float* Wv = (const float*)d_in[7];
    const float* bv = (const float*)d_in[8];
    const float* Wo = (const float*)d_in[9];
    const float* bo = (const float*)d_in[10];
    const float* W1 = (const float*)d_in[11];
    const float* b1 = (const float*)d_in[12];
    const float* W2 = (const float*)d_in[13];
    const float* b2 = (const float*)d_in[14];
    const float* ln2_scale = (const float*)d_in[15];
    const float* ln2_shift = (const float*)d_in[16];
    float* out = (float*)d_out;

    const size_t MB = 1024 * 1024;
    char* w = (char*)d_ws;
    ushort* q_b   = (ushort*)(w + 0 * MB);     // 8MB
    ushort* k_b   = (ushort*)(w + 8 * MB);     // 8MB
    ushort* vt_b  = (ushort*)(w + 16 * MB);    // 8MB
    ushort* att_b = (ushort*)(w + 24 * MB);    // 8MB
    ushort* proj_b= (ushort*)(w + 32 * MB);    // 8MB
    ushort* o2_b  = (ushort*)(w + 48 * MB);    // 8MB
    ushort* h1_b  = (ushort*)(w + 64 * MB);    // 32MB
    ushort* wq_t  = (ushort*)(w + 96 * MB);    // 2MB  (q/k/v contiguous = fused 3072xK)
    ushort* wk_t  = (ushort*)(w + 98 * MB);
    ushort* wv_t  = (ushort*)(w + 100 * MB);
    ushort* wo_t  = (ushort*)(w + 102 * MB);
    ushort* w1_t  = (ushort*)(w + 104 * MB);   // 8MB
    ushort* w2_t  = (ushort*)(w + 112 * MB);   // 8MB
    ushort* xn_b  = (ushort*)(w + 120 * MB);   // 8MB

    // 0. weight convert+transpose
    transpose_bf16_kernel<<<dim3(DD / 32, DD / 32), 256, 0, stream>>>(Wq, wq_t, DD, DD);
    transpose_bf16_kernel<<<dim3(DD / 32, DD / 32), 256, 0, stream>>>(Wk, wk_t, DD, DD);
    transpose_bf16_kernel<<<dim3(DD / 32, DD / 32), 256, 0, stream>>>(Wv, wv_t, DD, DD);
    transpose_bf16_kernel<<<dim3(DD / 32, DD / 32), 256, 0, stream>>>(Wo, wo_t, DD, DD);
    transpose_bf16_kernel<<<dim3(FFN / 32, DD / 32), 256, 0, stream>>>(W1, w1_t, DD, FFN);
    transpose_bf16_kernel<<<dim3(DD / 32, FFN / 32), 256, 0, stream>>>(W2, w2_t, FFN, DD);

    // 1. LN1 -> bf16
    ln_kernel<<<NROW, 256, 0, stream>>>(inputs, ln1_scale, ln1_shift, xn_b);

    // 2. Fused QKV projection (N=3072; V written transposed per head). 768 blk.
    dim3 gqkv(3 * DD / GBN, NROW / GBM);   // 24 x 32
    gemm_bf16_kernel<3, true, 3><<<gqkv, 512, 0, stream>>>(
        xn_b, wq_t, bq, nullptr, q_b, NROW, 3 * DD, DD, bk, bv, k_b, vt_b);

    // 3. MFMA flash attention -> att_b (bf16)
    dim3 ga(BB * HH, SS / 64);
    attn_mfma_kernel<<<ga, 256, 0, stream>>>(q_b, k_b, vt_b, att_b);

    // 4. Output projection -> proj (bf16). 256 blocks -> depth-5 ring.
    dim3 g1(DD / GBN, NROW / GBM);
    gemm_bf16_kernel<0, true, 5><<<g1, 512, 0, stream>>>(
        att_b, wo_t, bo, nullptr, proj_b, NROW, DD, DD, nullptr, nullptr, nullptr, nullptr);

    // 5. residual + LN2 -> o2 (bf16, serves as GEMM input AND final residual)
    ln_res_kernel<<<NROW, 256, 0, stream>>>(proj_b, inputs, ln2_scale, ln2_shift, o2_b);

    // 6. FFN up + relu -> h1 (bf16). 1024 blocks -> depth-3.
    dim3 g2(FFN / GBN, NROW / GBM);
    gemm_bf16_kernel<1, true, 3><<<g2, 512, 0, stream>>>(
        o2_b, w1_t, b1, nullptr, h1_b, NROW, FFN, DD, nullptr, nullptr, nullptr, nullptr);

    // 7. FFN down + bias + o2 -> out (fp32). 256 blocks -> depth-5 ring.
    gemm_bf16_kernel<2, false, 5><<<g1, 512, 0, stream>>>(
        h1_b, w2_t, b2, o2_b, out, NROW, DD, FFN, nullptr, nullptr, nullptr, nullptr);
}

// Round 10
// 257.023 us; speedup vs baseline: 24.2151x; 1.0426x over previous
//
#include <hip/hip_runtime.h>
#include <hip/hip_bf16.h>
#include <math.h>

// Problem constants
#define BB 2
#define SS 2048
#define DD 1024
#define HH 16
#define DH 64
#define NROW (BB*SS)          // 4096
#define FFN (4*DD)            // 4096

typedef __attribute__((ext_vector_type(8))) __bf16 bf16x8;
typedef __attribute__((ext_vector_type(4))) float f32x4;

__device__ __forceinline__ ushort f2b(float f) {
    union { float f; uint32_t u; } x; x.f = f;
    uint32_t r = x.u + 0x7FFF + ((x.u >> 16) & 1);
    return (ushort)(r >> 16);
}
__device__ __forceinline__ float b2f(ushort u) {
    union { uint32_t u; float f; } x; x.u = (uint32_t)u << 16;
    return x.f;
}

// ---------------- LayerNorm (torch semantics: ddof=1, eps on std) -> bf16 ----
__global__ __launch_bounds__(256)
void ln_kernel(const float* __restrict__ x, const float* __restrict__ scale,
               const float* __restrict__ shift, ushort* __restrict__ y) {
    int row = blockIdx.x;
    const float* xr = x + (size_t)row * DD;
    ushort* yr = y + (size_t)row * DD;
    int t = threadIdx.x;
    float v[4];
    float s = 0.f, ss = 0.f;
#pragma unroll
    for (int i = 0; i < 4; ++i) {
        v[i] = xr[t + 256 * i];
        s += v[i];
        ss += v[i] * v[i];
    }
#pragma unroll
    for (int off = 32; off; off >>= 1) {
        s  += __shfl_xor(s, off);
        ss += __shfl_xor(ss, off);
    }
    __shared__ float red[8];
    int w = t >> 6;
    if ((t & 63) == 0) { red[w] = s; red[w + 4] = ss; }
    __syncthreads();
    float st  = red[0] + red[1] + red[2] + red[3];
    float sst = red[4] + red[5] + red[6] + red[7];
    float mu = st * (1.f / DD);
    float var = (sst - DD * mu * mu) * (1.f / (DD - 1));
    var = fmaxf(var, 0.f);
    float inv = 1.f / (sqrtf(var) + 1e-9f);
#pragma unroll
    for (int i = 0; i < 4; ++i) {
        int c = t + 256 * i;
        yr[c] = f2b(scale[c] * (v[i] - mu) * inv + shift[c]);
    }
}

// LN over (a_bf16 + b_fp32): writes bf16 (for FFN GEMM input AND residual)
__global__ __launch_bounds__(256)
void ln_res_kernel(const ushort* __restrict__ xa, const float* __restrict__ xb,
                   const float* __restrict__ scale, const float* __restrict__ shift,
                   ushort* __restrict__ yb) {
    int row = blockIdx.x;
    const ushort* ar = xa + (size_t)row * DD;
    const float* br = xb + (size_t)row * DD;
    ushort* ybr = yb + (size_t)row * DD;
    int t = threadIdx.x;
    float v[4];
    float s = 0.f, ss = 0.f;
#pragma unroll
    for (int i = 0; i < 4; ++i) {
        int c = t + 256 * i;
        v[i] = b2f(ar[c]) + br[c];
        s += v[i];
        ss += v[i] * v[i];
    }
#pragma unroll
    for (int off = 32; off; off >>= 1) {
        s  += __shfl_xor(s, off);
        ss += __shfl_xor(ss, off);
    }
    __shared__ float red[8];
    int w = t >> 6;
    if ((t & 63) == 0) { red[w] = s; red[w + 4] = ss; }
    __syncthreads();
    float st  = red[0] + red[1] + red[2] + red[3];
    float sst = red[4] + red[5] + red[6] + red[7];
    float mu = st * (1.f / DD);
    float var = (sst - DD * mu * mu) * (1.f / (DD - 1));
    var = fmaxf(var, 0.f);
    float inv = 1.f / (sqrtf(var) + 1e-9f);
#pragma unroll
    for (int i = 0; i < 4; ++i) {
        int c = t + 256 * i;
        ybr[c] = f2b(scale[c] * (v[i] - mu) * inv + shift[c]);
    }
}

// ---------------- fp32 -> bf16 transpose-convert for weights -----------------
__global__ __launch_bounds__(256)
void transpose_bf16_kernel(const float* __restrict__ W, ushort* __restrict__ Wt,
                           int K, int N) {
    __shared__ ushort tile[32][33];
    int tx = threadIdx.x & 31;
    int ty = threadIdx.x >> 5;      // 0..7
    int n0 = blockIdx.x * 32;
    int k0 = blockIdx.y * 32;
#pragma unroll
    for (int i = 0; i < 32; i += 8)
        tile[ty + i][tx] = f2b(W[(size_t)(k0 + ty + i) * N + n0 + tx]);
    __syncthreads();
#pragma unroll
    for (int i = 0; i < 32; i += 8)
        Wt[(size_t)(n0 + ty + i) * K + k0 + tx] = tile[tx][ty + i];
}

// ---------------- split-K reduce kernels -------------------------------------
// proj = bf16(p0 + p1 + bias[col])
__global__ __launch_bounds__(256)
void reduce_wo_kernel(const float* __restrict__ p0, const float* __restrict__ p1,
                      const float* __restrict__ bias, ushort* __restrict__ yb) {
    int i = (blockIdx.x * 256 + threadIdx.x) * 4;
    float4 a = *reinterpret_cast<const float4*>(p0 + i);
    float4 b = *reinterpret_cast<const float4*>(p1 + i);
    int c = i & (DD - 1);
    float4 bs = *reinterpret_cast<const float4*>(bias + c);
    ushort4 o;
    o.x = f2b(a.x + b.x + bs.x);
    o.y = f2b(a.y + b.y + bs.y);
    o.z = f2b(a.z + b.z + bs.z);
    o.w = f2b(a.w + b.w + bs.w);
    *reinterpret_cast<ushort4*>(yb + i) = o;
}

// out = p0 + p1 + bias[col] + bf16_residual
__global__ __launch_bounds__(256)
void reduce_ffn2_kernel(const float* __restrict__ p0, const float* __restrict__ p1,
                        const float* __restrict__ bias, const ushort* __restrict__ res,
                        float* __restrict__ out) {
    int i = (blockIdx.x * 256 + threadIdx.x) * 4;
    float4 a = *reinterpret_cast<const float4*>(p0 + i);
    float4 b = *reinterpret_cast<const float4*>(p1 + i);
    ushort4 r = *reinterpret_cast<const ushort4*>(res + i);
    int c = i & (DD - 1);
    float4 bs = *reinterpret_cast<const float4*>(bias + c);
    float4 o;
    o.x = a.x + b.x + bs.x + b2f(r.x);
    o.y = a.y + b.y + bs.y + b2f(r.y);
    o.z = a.z + b.z + bs.z + b2f(r.z);
    o.w = a.w + b.w + bs.w + b2f(r.w);
    *reinterpret_cast<float4*>(out + i) = o;
}

// ---------------- bf16 MFMA GEMM: 8 waves, DEPTH-deep counted-vmcnt ring -----
// C = A(M x lda) @ Wt(N x lda)^T over K-slice [z*K, z*K+K) + epilogue.
// 512 threads; wave grid 2x4, wave-tile 64x32. XCD-swizzled (nwg%8==0).
// MODE 0: +bias (per BF16_OUT); 1: +bias,relu; 3: fused QKV epilogue;
// MODE 4: raw fp32 partial store at Cout + z*M*N (split-K).
#define GBM 128
#define GBN 128
#define GBK 32

template <int MODE, bool BF16_OUT, int DEPTH>
__global__ __launch_bounds__(512)
void gemm_bf16_kernel(const ushort* __restrict__ A, const ushort* __restrict__ Wt,
                      const float* __restrict__ bias, const ushort* __restrict__ addsrc,
                      void* __restrict__ Cout, int M, int N, int K, int lda,
                      const float* __restrict__ bias2, const float* __restrict__ bias3,
                      void* __restrict__ out2, void* __restrict__ out3) {
    __shared__ ushort As[DEPTH][GBM * GBK];   // DEPTH x 8KB
    __shared__ ushort Bs[DEPTH][GBN * GBK];   // DEPTH x 8KB

    int tid = threadIdx.x;
    int lane = tid & 63;
    int wid = tid >> 6;              // 0..7
    int wr = wid >> 2, wc = wid & 3; // 2 x 4 wave grid

    // ---- bijective XCD swizzle (x,y only; z = K-slice) ----
    int gx = gridDim.x;
    int nwg = gx * gridDim.y;
    int orig = blockIdx.y * gx + blockIdx.x;
    int q8 = nwg >> 3;                       // nwg % 8 == 0 guaranteed by launch
    int swz = (orig & 7) * q8 + (orig >> 3);
    int bx = swz % gx, by = swz / gx;

    int brow = by * GBM;
    int bcol = bx * GBN;
    size_t koff = (size_t)blockIdx.z * K;

    int lrow = lane & 15;
    int kgrp = lane >> 4;

    f32x4 acc[4][2] = {};

    // staging: whole block loads A-tile with 1 instr, B-tile with 1 instr.
    int srow = tid >> 2;
    int sgran = (tid & 3) ^ ((srow >> 1) & 3);

    auto stage = [&](int buf, int k0) {
        const char* ga = (const char*)A +
            ((size_t)(brow + srow) * lda + koff + k0) * 2 + sgran * 16;
        __builtin_amdgcn_global_load_lds(
            (const __attribute__((address_space(1))) uint32_t*)ga,
            (__attribute__((address_space(3))) uint32_t*)(&As[buf][0] + (wid * 16) * GBK),
            16, 0, 0);
        const char* gb = (const char*)Wt +
            ((size_t)(bcol + srow) * lda + koff + k0) * 2 + sgran * 16;
        __builtin_amdgcn_global_load_lds(
            (const __attribute__((address_space(1))) uint32_t*)gb,
            (__attribute__((address_space(3))) uint32_t*)(&Bs[buf][0] + (wid * 16) * GBK),
            16, 0, 0);
    };

    int nk = K / GBK;
    constexpr int PRE = DEPTH - 1;           // stages in flight ahead of compute
#pragma unroll
    for (int s = 0; s < PRE; ++s)
        if (s < nk) stage(s, s * GBK);

    int cur = 0, stg = PRE;
    for (int t = 0; t < nk; ++t) {
        __builtin_amdgcn_sched_barrier(0);   // pin prev iter's ds_reads/MFMAs
        int rem = nk - 1 - t;                // stages still in flight beyond cur
        if constexpr (DEPTH == 5) {
            if (rem >= 3)      asm volatile("s_waitcnt vmcnt(6)" ::: "memory");
            else if (rem == 2) asm volatile("s_waitcnt vmcnt(4)" ::: "memory");
            else if (rem == 1) asm volatile("s_waitcnt vmcnt(2)" ::: "memory");
            else               asm volatile("s_waitcnt vmcnt(0)" ::: "memory");
        } else {
            if (rem >= 1)      asm volatile("s_waitcnt vmcnt(2)" ::: "memory");
            else               asm volatile("s_waitcnt vmcnt(0)" ::: "memory");
        }
        asm volatile("s_barrier" ::: "memory");          // no vmcnt drain
        if (t + PRE < nk) stage(stg, (t + PRE) * GBK);

        bf16x8 afrag[4], bfrag[2];
#pragma unroll
        for (int mi = 0; mi < 4; ++mi) {
            int row = wr * 64 + mi * 16 + lrow;
            int gran = kgrp ^ ((row >> 1) & 3);
            afrag[mi] = *(const bf16x8*)((const char*)&As[cur][0] + row * 64 + gran * 16);
        }
#pragma unroll
        for (int ni = 0; ni < 2; ++ni) {
            int row = wc * 32 + ni * 16 + lrow;
            int gran = kgrp ^ ((row >> 1) & 3);
            bfrag[ni] = *(const bf16x8*)((const char*)&Bs[cur][0] + row * 64 + gran * 16);
        }
#pragma unroll
        for (int mi = 0; mi < 4; ++mi)
#pragma unroll
            for (int ni = 0; ni < 2; ++ni)
                acc[mi][ni] = __builtin_amdgcn_mfma_f32_16x16x32_bf16(
                    afrag[mi], bfrag[ni], acc[mi][ni], 0, 0, 0);

        cur = (cur == DEPTH - 1) ? 0 : cur + 1;
        stg = (stg == DEPTH - 1) ? 0 : stg + 1;
    }

    if (MODE == 3) {
        int which = bcol >> 10;   // 0=q, 1=k, 2=v (128-tile never straddles)
        const float* bs = which == 0 ? bias : (which == 1 ? bias2 : bias3);
#pragma unroll
        for (int ni = 0; ni < 2; ++ni) {
            int col = bcol + wc * 32 + ni * 16 + lrow;
            int lcol = col & 1023;
            float bsv = bs[lcol];
#pragma unroll
            for (int mi = 0; mi < 4; ++mi) {
                f32x4 a = acc[mi][ni];
#pragma unroll
                for (int j = 0; j < 4; ++j) {
                    int row = brow + wr * 64 + mi * 16 + kgrp * 4 + j;
                    float val = a[j] + bsv;
                    if (which == 2) {
                        size_t idx = (size_t)(row >> 11) * ((size_t)DD * SS)
                                   + (size_t)lcol * SS + (row & (SS - 1));
                        ((ushort*)out3)[idx] = f2b(val);
                    } else {
                        ushort* dst = which == 0 ? (ushort*)Cout : (ushort*)out2;
                        dst[(size_t)row * DD + lcol] = f2b(val);
                    }
                }
            }
        }
        return;
    }

    if (MODE == 4) {
        float* dst = (float*)Cout + (size_t)blockIdx.z * ((size_t)M * N);
#pragma unroll
        for (int ni = 0; ni < 2; ++ni) {
            int col = bcol + wc * 32 + ni * 16 + lrow;
#pragma unroll
            for (int mi = 0; mi < 4; ++mi) {
                f32x4 a = acc[mi][ni];
#pragma unroll
                for (int j = 0; j < 4; ++j) {
                    int row = brow + wr * 64 + mi * 16 + kgrp * 4 + j;
                    dst[(size_t)row * N + col] = a[j];
                }
            }
        }
        return;
    }

#pragma unroll
    for (int ni = 0; ni < 2; ++ni) {
        int col = bcol + wc * 32 + ni * 16 + lrow;
        float bsv = bias[col];
#pragma unroll
        for (int mi = 0; mi < 4; ++mi) {
            f32x4 a = acc[mi][ni];
#pragma unroll
            for (int j = 0; j < 4; ++j) {
                int row = brow + wr * 64 + mi * 16 + kgrp * 4 + j;
                float val = a[j] + bsv;
                if (MODE == 1) val = fmaxf(val, 0.f);
                if (BF16_OUT)
                    ((ushort*)Cout)[(size_t)row * N + col] = f2b(val);
                else
                    ((float*)Cout)[(size_t)row * N + col] = val;
            }
        }
    }
}

// ---------------- bf16 MFMA causal flash attention (swapped QK^T) ------------
// Block: 4 waves per (b, h, 64-query tile); wave w owns q rows [w*16, w*16+16).
// S^T = mfma(K, Q): lane&15 = q-row -> softmax row stats are per-lane scalars.
// K/V double-buffered (depth-2); Ps overlays dead Qs. LDS = 40KB -> 4 blocks/CU.
__global__ __launch_bounds__(256)
void attn_mfma_kernel(const ushort* __restrict__ Qg, const ushort* __restrict__ Kg,
                      const ushort* __restrict__ Vtg, ushort* __restrict__ Og) {
    __shared__ ushort Qs[64 * 64];        // 8KB; reused as Ps after Q hoist
    __shared__ ushort Ks[2][64 * 64];     // 16KB
    __shared__ ushort Vs[2][64 * 64];     // 16KB

    int tid = threadIdx.x;
    int lane = tid & 63;
    int wid = tid >> 6;
    int bh = blockIdx.x;
    int b = bh >> 4, h = bh & 15;
    int q0 = ((int)gridDim.y - 1 - (int)blockIdx.y) * 64;   // heavy tiles first

    const ushort* Qbase = Qg + ((size_t)(b * SS + q0)) * DD + h * DH;
    const ushort* Kbase = Kg + ((size_t)(b * SS)) * DD + h * DH;
    const ushort* Vbase = Vtg + (size_t)bh * DH * SS;        // rows: d, stride SS

    int r0 = wid * 16;
    int rr0 = r0 + (lane >> 3);
    int g0 = lane & 7;
    int g = lane >> 4;               // 0..3 lane group
    int lr = lane & 15;              // q-row within wave (swapped layout)

    auto stageKV = [&](int buf, int k0) {
#pragma unroll
        for (int i = 0; i < 2; ++i) {
            int rr = rr0 + i * 8;
            int gg = g0 ^ (rr & 7);
            const ushort* srck = Kbase + (size_t)(k0 + rr) * DD + gg * 8;
            __builtin_amdgcn_global_load_lds(
                (const __attribute__((address_space(1))) uint32_t*)srck,
                (__attribute__((address_space(3))) uint32_t*)(&Ks[buf][0] + (r0 + i * 8) * 64),
                16, 0, 0);
            const ushort* srcv = Vbase + (size_t)rr * SS + k0 + gg * 8;
            __builtin_amdgcn_global_load_lds(
                (const __attribute__((address_space(1))) uint32_t*)srcv,
                (__attribute__((address_space(3))) uint32_t*)(&Vs[buf][0] + (r0 + i * 8) * 64),
                16, 0, 0);
        }
    };

    int nt = q0 / 64 + 1;

    // ---- prologue: Q (2 loads/wave, wave-local) + first K/V stage ----
    {
#pragma unroll
        for (int i = 0; i < 2; ++i) {
            int rr = rr0 + i * 8;
            int gg = g0 ^ (rr & 7);
            const ushort* src = Qbase + (size_t)rr * DD + gg * 8;
            __builtin_amdgcn_global_load_lds(
                (const __attribute__((address_space(1))) uint32_t*)src,
                (__attribute__((address_space(3))) uint32_t*)(Qs + (r0 + i * 8) * 64),
                16, 0, 0);
        }
    }
    stageKV(0, 0);
    asm volatile("s_waitcnt vmcnt(4)" ::: "memory");   // own Q rows landed (wave-local)

    // ---- hoist Q B-fragments (rows=q, k-major) ----
    bf16x8 aq[2];
    {
        int r = wid * 16 + lr;
#pragma unroll
        for (int ks = 0; ks < 2; ++ks) {
            int lg = ks * 4 + g;
            aq[ks] = *(const bf16x8*)((const char*)Qs + r * 128 + ((lg ^ (r & 7)) << 4));
        }
    }
    ushort* Ps = Qs;                 // Q dead in LDS from here

    f32x4 oacc[4] = {};
    float m = -INFINITY, l = 0.f;
    int qa = q0 + wid * 16 + lr;     // absolute q row for this lane

    int cur = 0;
    for (int t = 0; t < nt; ++t) {
        __builtin_amdgcn_sched_barrier(0);
        asm volatile("s_waitcnt vmcnt(0)" ::: "memory");   // stage(t) landed
        asm volatile("s_barrier" ::: "memory");
        if (t + 1 < nt) stageKV(cur ^ 1, (t + 1) * 64);
        int k0 = t * 64;

        // ---- S^T = K @ Q^T : col(lane&15)=q-row, row=key ----
        f32x4 sacc[4] = {};
        __builtin_amdgcn_s_setprio(1);
#pragma unroll
        for (int ni = 0; ni < 4; ++ni) {
            int r = ni * 16 + lr;    // key row in K tile
#pragma unroll
            for (int ks = 0; ks < 2; ++ks) {
                int lg = ks * 4 + g;
                bf16x8 bk = *(const bf16x8*)((const char*)&Ks[cur][0] + r * 128 + ((lg ^ (r & 7)) << 4));
                sacc[ni] = __builtin_amdgcn_mfma_f32_16x16x32_bf16(bk, aq[ks], sacc[ni], 0, 0, 0);
            }
        }
        __builtin_amdgcn_s_setprio(0);

        // ---- scale + causal mask (diagonal tile only) ----
        float sc[4][4];
#pragma unroll
        for (int ni = 0; ni < 4; ++ni)
#pragma unroll
            for (int j = 0; j < 4; ++j)
                sc[ni][j] = sacc[ni][j] * 0.125f;
        if (k0 == q0) {
#pragma unroll
            for (int ni = 0; ni < 4; ++ni) {
#pragma unroll
                for (int j = 0; j < 4; ++j) {
                    int key = q0 + ni * 16 + g * 4 + j;
                    if (key > qa) sc[ni][j] = -INFINITY;
                }
            }
        }

        // ---- online softmax: per-lane scalar row stats ----
        float mx = sc[0][0];
#pragma unroll
        for (int ni = 0; ni < 4; ++ni)
#pragma unroll
            for (int j = 0; j < 4; ++j) mx = fmaxf(mx, sc[ni][j]);
        mx = fmaxf(mx, __shfl_xor(mx, 16));
        mx = fmaxf(mx, __shfl_xor(mx, 32));
        float mn = fmaxf(m, mx);
        float corr = __expf(m - mn);
        m = mn;
        float p[4][4];
        float rs = 0.f;
#pragma unroll
        for (int ni = 0; ni < 4; ++ni)
#pragma unroll
            for (int j = 0; j < 4; ++j) { p[ni][j] = __expf(sc[ni][j] - mn); rs += p[ni][j]; }
        rs += __shfl_xor(rs, 16);
        rs += __shfl_xor(rs, 32);
        l = l * corr + rs;

        // broadcast corr to oacc row layout (row = g*4+j held as q=lane&15)
        float cj[4];
#pragma unroll
        for (int j = 0; j < 4; ++j)
            cj[j] = __shfl(corr, (lane & 48) | (g * 4 + j));
#pragma unroll
        for (int ni = 0; ni < 4; ++ni)
#pragma unroll
            for (int j = 0; j < 4; ++j) oacc[ni][j] *= cj[j];

        // ---- P -> bf16 -> wave-private LDS slab (4 x ds_write_b64) ----
        {
            int row = wid * 16 + lr;
#pragma unroll
            for (int ni = 0; ni < 4; ++ni) {
                ushort4 w4;
                w4.x = f2b(p[ni][0]); w4.y = f2b(p[ni][1]);
                w4.z = f2b(p[ni][2]); w4.w = f2b(p[ni][3]);
                int gran = (ni * 2 + (g >> 1)) ^ (row & 7);
                *(ushort4*)((char*)Ps + row * 128 + (gran << 4) + (g & 1) * 8) = w4;
            }
        }
        asm volatile("s_waitcnt lgkmcnt(0)" ::: "memory");   // wave-local P landed

        // ---- O += P @ V ----
        bf16x8 ap[2];
        {
            int r = wid * 16 + lr;
#pragma unroll
            for (int ks = 0; ks < 2; ++ks) {
                int lg = ks * 4 + g;
                ap[ks] = *(const bf16x8*)((const char*)Ps + r * 128 + ((lg ^ (r & 7)) << 4));
            }
        }
        __builtin_amdgcn_s_setprio(1);
#pragma unroll
        for (int ni = 0; ni < 4; ++ni) {
            int r = ni * 16 + lr;    // d row in Vt tile
#pragma unroll
            for (int ks = 0; ks < 2; ++ks) {
                int lg = ks * 4 + g;
                bf16x8 bv = *(const bf16x8*)((const char*)&Vs[cur][0] + r * 128 + ((lg ^ (r & 7)) << 4));
                oacc[ni] = __builtin_amdgcn_mfma_f32_16x16x32_bf16(ap[ks], bv, oacc[ni], 0, 0, 0);
            }
        }
        __builtin_amdgcn_s_setprio(0);
        cur ^= 1;
    }

    // ---- epilogue: divide by l (broadcast per row), write bf16 ----
#pragma unroll
    for (int j = 0; j < 4; ++j) {
        float lj = __shfl(l, (lane & 48) | (g * 4 + j));
        float inv = 1.f / lj;
        int gr = q0 + wid * 16 + g * 4 + j;
#pragma unroll
        for (int ni = 0; ni < 4; ++ni) {
            int d = ni * 16 + lr;
            Og[((size_t)(b * SS + gr)) * DD + h * DH + d] = f2b(oacc[ni][j] * inv);
        }
    }
}

// ---------------- Launch ------------------------------------------------------
extern "C" void kernel_launch(void* const* d_in, const int* in_sizes, int n_in,
                              void* d_out, int out_size, void* d_ws, size_t ws_size,
                              hipStream_t stream) {
    const float* inputs    = (const float*)d_in[0];
    const float* ln1_scale = (const float*)d_in[1];
    const float* ln1_shift = (const float*)d_in[2];
    const float* Wq = (const float*)d_in[3];
    const float* bq = (const float*)d_in[4];
    const float* Wk = (const float*)d_in[5];
    const float* bk = (const float*)d_in[6];
    const float* Wv = (const float*)d_in[7];
    const float* bv = (const float*)d_in[8];
    const float* Wo = (const float*)d_in[9];
    const float* bo = (const float*)d_in[10];
    const float* W1 = (const float*)d_in[11];
    const float* b1 = (const float*)d_in[12];
    const float* W2 = (const float*)d_in[13];
    const float* b2 = (const float*)d_in[14];
    const float* ln2_scale = (const float*)d_in[15];
    const float* ln2_shift = (const float*)d_in[16];
    float* out = (float*)d_out;

    const size_t MB = 1024 * 1024;
    char* w = (char*)d_ws;
    // phase-1 buffers
    ushort* q_b   = (ushort*)(w + 0 * MB);     // 8MB (dead after attn)
    ushort* k_b   = (ushort*)(w + 8 * MB);     // 8MB (dead after attn)
    ushort* vt_b  = (ushort*)(w + 16 * MB);    // 8MB (dead after attn)
    ushort* att_b = (ushort*)(w + 24 * MB);    // 8MB (dead after Wo GEMM)
    // Wo split-K partials (contiguous 32MB), alive between Wo GEMM and reduce
    float*  pw    = (float*)(w + 32 * MB);     // 32MB (z=0: 32-48, z=1: 48-64)
    // phase-2 buffers (reuse dead regions)
    ushort* proj_b= (ushort*)(w + 0 * MB);     // 8MB (over q_b)
    ushort* o2_b  = (ushort*)(w + 8 * MB);     // 8MB (over k_b)
    // FFN2 split-K partials (contiguous 32MB, over vt/att/pw0)
    float*  pf    = (float*)(w + 16 * MB);     // 32MB (16-48)
    ushort* h1_b  = (ushort*)(w + 64 * MB);    // 32MB
    ushort* wq_t  = (ushort*)(w + 96 * MB);    // 2MB (q/k/v contiguous = fused 3072xK)
    ushort* wk_t  = (ushort*)(w + 98 * MB);
    ushort* wv_t  = (ushort*)(w + 100 * MB);
    ushort* wo_t  = (ushort*)(w + 102 * MB);
    ushort* w1_t  = (ushort*)(w + 104 * MB);   // 8MB
    ushort* w2_t  = (ushort*)(w + 112 * MB);   // 8MB
    ushort* xn_b  = (ushort*)(w + 120 * MB);   // 8MB

    // 0. weight convert+transpose
    transpose_bf16_kernel<<<dim3(DD / 32, DD / 32), 256, 0, stream>>>(Wq, wq_t, DD, DD);
    transpose_bf16_kernel<<<dim3(DD / 32, DD / 32), 256, 0, stream>>>(Wk, wk_t, DD, DD);
    transpose_bf16_kernel<<<dim3(DD / 32, DD / 32), 256, 0, stream>>>(Wv, wv_t, DD, DD);
    transpose_bf16_kernel<<<dim3(DD / 32, DD / 32), 256, 0, stream>>>(Wo, wo_t, DD, DD);
    transpose_bf16_kernel<<<dim3(FFN / 32, DD / 32), 256, 0, stream>>>(W1, w1_t, DD, FFN);
    transpose_bf16_kernel<<<dim3(DD / 32, FFN / 32), 256, 0, stream>>>(W2, w2_t, FFN, DD);

    // 1. LN1 -> bf16
    ln_kernel<<<NROW, 256, 0, stream>>>(inputs, ln1_scale, ln1_shift, xn_b);

    // 2. Fused QKV projection (N=3072; V written transposed per head). 768 blk.
    dim3 gqkv(3 * DD / GBN, NROW / GBM, 1);   // 24 x 32
    gemm_bf16_kernel<3, true, 3><<<gqkv, 512, 0, stream>>>(
        xn_b, wq_t, bq, nullptr, q_b, NROW, 3 * DD, DD, DD, bk, bv, k_b, vt_b);

    // 3. MFMA flash attention -> att_b (bf16)
    dim3 ga(BB * HH, SS / 64);
    attn_mfma_kernel<<<ga, 256, 0, stream>>>(q_b, k_b, vt_b, att_b);

    // 4. Output projection, split-K=2 -> fp32 partials pw. 512 blocks.
    dim3 g1z(DD / GBN, NROW / GBM, 2);        // 8 x 32 x 2
    gemm_bf16_kernel<4, false, 5><<<g1z, 512, 0, stream>>>(
        att_b, wo_t, nullptr, nullptr, pw, NROW, DD, DD / 2, DD, nullptr, nullptr, nullptr, nullptr);
    reduce_wo_kernel<<<(NROW * DD / 4) / 256, 256, 0, stream>>>(
        pw, pw + (size_t)NROW * DD, bo, proj_b);

    // 5. residual + LN2 -> o2 (bf16, serves as GEMM input AND final residual)
    ln_res_kernel<<<NROW, 256, 0, stream>>>(proj_b, inputs, ln2_scale, ln2_shift, o2_b);

    // 6. FFN up + relu -> h1 (bf16). 1024 blocks -> depth-3.
    dim3 g2(FFN / GBN, NROW / GBM, 1);
    gemm_bf16_kernel<1, true, 3><<<g2, 512, 0, stream>>>(
        o2_b, w1_t, b1, nullptr, h1_b, NROW, FFN, DD, DD, nullptr, nullptr, nullptr, nullptr);

    // 7. FFN down, split-K=2 -> fp32 partials pf. 512 blocks.
    gemm_bf16_kernel<4, false, 5><<<g1z, 512, 0, stream>>>(
        h1_b, w2_t, nullptr, nullptr, pf, NROW, DD, FFN / 2, FFN, nullptr, nullptr, nullptr, nullptr);
    reduce_ffn2_kernel<<<(NROW * DD / 4) / 256, 256, 0, stream>>>(
        pf, pf + (size_t)NROW * DD, b2, o2_b, out);
}

// Round 11
// 255.076 us; speedup vs baseline: 24.3999x; 1.0076x over previous
//
#include <hip/hip_runtime.h>
#include <hip/hip_bf16.h>
#include <math.h>

// Problem constants
#define BB 2
#define SS 2048
#define DD 1024
#define HH 16
#define DH 64
#define NROW (BB*SS)          // 4096
#define FFN (4*DD)            // 4096

typedef __attribute__((ext_vector_type(8))) __bf16 bf16x8;
typedef __attribute__((ext_vector_type(4))) __bf16 bf16x4;
typedef __attribute__((ext_vector_type(4))) float f32x4;

// Q pre-scale: 1/sqrt(64) * log2(e)  (softmax runs in exp2 domain)
#define QSCALE 0.18033688011112042f

__device__ __forceinline__ ushort f2b(float f) {
    union { float f; uint32_t u; } x; x.f = f;
    uint32_t r = x.u + 0x7FFF + ((x.u >> 16) & 1);
    return (ushort)(r >> 16);
}
__device__ __forceinline__ float b2f(ushort u) {
    union { uint32_t u; float f; } x; x.u = (uint32_t)u << 16;
    return x.f;
}

// ---------------- LayerNorm (torch semantics: ddof=1, eps on std) -> bf16 ----
__global__ __launch_bounds__(256)
void ln_kernel(const float* __restrict__ x, const float* __restrict__ scale,
               const float* __restrict__ shift, ushort* __restrict__ y) {
    int row = blockIdx.x;
    const float* xr = x + (size_t)row * DD;
    ushort* yr = y + (size_t)row * DD;
    int t = threadIdx.x;
    float v[4];
    float s = 0.f, ss = 0.f;
#pragma unroll
    for (int i = 0; i < 4; ++i) {
        v[i] = xr[t + 256 * i];
        s += v[i];
        ss += v[i] * v[i];
    }
#pragma unroll
    for (int off = 32; off; off >>= 1) {
        s  += __shfl_xor(s, off);
        ss += __shfl_xor(ss, off);
    }
    __shared__ float red[8];
    int w = t >> 6;
    if ((t & 63) == 0) { red[w] = s; red[w + 4] = ss; }
    __syncthreads();
    float st  = red[0] + red[1] + red[2] + red[3];
    float sst = red[4] + red[5] + red[6] + red[7];
    float mu = st * (1.f / DD);
    float var = (sst - DD * mu * mu) * (1.f / (DD - 1));
    var = fmaxf(var, 0.f);
    float inv = 1.f / (sqrtf(var) + 1e-9f);
#pragma unroll
    for (int i = 0; i < 4; ++i) {
        int c = t + 256 * i;
        yr[c] = f2b(scale[c] * (v[i] - mu) * inv + shift[c]);
    }
}

// LN over (a_bf16 + b_fp32): writes bf16 (for FFN GEMM input AND residual)
__global__ __launch_bounds__(256)
void ln_res_kernel(const ushort* __restrict__ xa, const float* __restrict__ xb,
                   const float* __restrict__ scale, const float* __restrict__ shift,
                   ushort* __restrict__ yb) {
    int row = blockIdx.x;
    const ushort* ar = xa + (size_t)row * DD;
    const float* br = xb + (size_t)row * DD;
    ushort* ybr = yb + (size_t)row * DD;
    int t = threadIdx.x;
    float v[4];
    float s = 0.f, ss = 0.f;
#pragma unroll
    for (int i = 0; i < 4; ++i) {
        int c = t + 256 * i;
        v[i] = b2f(ar[c]) + br[c];
        s += v[i];
        ss += v[i] * v[i];
    }
#pragma unroll
    for (int off = 32; off; off >>= 1) {
        s  += __shfl_xor(s, off);
        ss += __shfl_xor(ss, off);
    }
    __shared__ float red[8];
    int w = t >> 6;
    if ((t & 63) == 0) { red[w] = s; red[w + 4] = ss; }
    __syncthreads();
    float st  = red[0] + red[1] + red[2] + red[3];
    float sst = red[4] + red[5] + red[6] + red[7];
    float mu = st * (1.f / DD);
    float var = (sst - DD * mu * mu) * (1.f / (DD - 1));
    var = fmaxf(var, 0.f);
    float inv = 1.f / (sqrtf(var) + 1e-9f);
#pragma unroll
    for (int i = 0; i < 4; ++i) {
        int c = t + 256 * i;
        ybr[c] = f2b(scale[c] * (v[i] - mu) * inv + shift[c]);
    }
}

// ---------------- fp32 -> bf16 transpose-convert for weights -----------------
__global__ __launch_bounds__(256)
void transpose_bf16_kernel(const float* __restrict__ W, ushort* __restrict__ Wt,
                           int K, int N) {
    __shared__ ushort tile[32][33];
    int tx = threadIdx.x & 31;
    int ty = threadIdx.x >> 5;      // 0..7
    int n0 = blockIdx.x * 32;
    int k0 = blockIdx.y * 32;
#pragma unroll
    for (int i = 0; i < 32; i += 8)
        tile[ty + i][tx] = f2b(W[(size_t)(k0 + ty + i) * N + n0 + tx]);
    __syncthreads();
#pragma unroll
    for (int i = 0; i < 32; i += 8)
        Wt[(size_t)(n0 + ty + i) * K + k0 + tx] = tile[tx][ty + i];
}

// ---------------- split-K reduce kernels -------------------------------------
// proj = bf16(p0 + p1 + bias[col])
__global__ __launch_bounds__(256)
void reduce_wo_kernel(const float* __restrict__ p0, const float* __restrict__ p1,
                      const float* __restrict__ bias, ushort* __restrict__ yb) {
    int i = (blockIdx.x * 256 + threadIdx.x) * 4;
    float4 a = *reinterpret_cast<const float4*>(p0 + i);
    float4 b = *reinterpret_cast<const float4*>(p1 + i);
    int c = i & (DD - 1);
    float4 bs = *reinterpret_cast<const float4*>(bias + c);
    ushort4 o;
    o.x = f2b(a.x + b.x + bs.x);
    o.y = f2b(a.y + b.y + bs.y);
    o.z = f2b(a.z + b.z + bs.z);
    o.w = f2b(a.w + b.w + bs.w);
    *reinterpret_cast<ushort4*>(yb + i) = o;
}

// out = p0 + p1 + bias[col] + bf16_residual
__global__ __launch_bounds__(256)
void reduce_ffn2_kernel(const float* __restrict__ p0, const float* __restrict__ p1,
                        const float* __restrict__ bias, const ushort* __restrict__ res,
                        float* __restrict__ out) {
    int i = (blockIdx.x * 256 + threadIdx.x) * 4;
    float4 a = *reinterpret_cast<const float4*>(p0 + i);
    float4 b = *reinterpret_cast<const float4*>(p1 + i);
    ushort4 r = *reinterpret_cast<const ushort4*>(res + i);
    int c = i & (DD - 1);
    float4 bs = *reinterpret_cast<const float4*>(bias + c);
    float4 o;
    o.x = a.x + b.x + bs.x + b2f(r.x);
    o.y = a.y + b.y + bs.y + b2f(r.y);
    o.z = a.z + b.z + bs.z + b2f(r.z);
    o.w = a.w + b.w + bs.w + b2f(r.w);
    *reinterpret_cast<float4*>(out + i) = o;
}

// ---------------- bf16 MFMA GEMM: 8 waves, DEPTH-deep counted-vmcnt ring -----
// C = A(M x lda) @ Wt(N x lda)^T over K-slice [z*K, z*K+K) + epilogue.
// 512 threads; wave grid 2x4, wave-tile 64x32. XCD-swizzled (nwg%8==0).
// MODE 0: +bias (per BF16_OUT); 1: +bias,relu; 3: fused QKV epilogue (q scaled
// by QSCALE for exp2-domain softmax); MODE 4: raw fp32 partial store (split-K).
#define GBM 128
#define GBN 128
#define GBK 32

template <int MODE, bool BF16_OUT, int DEPTH>
__global__ __launch_bounds__(512)
void gemm_bf16_kernel(const ushort* __restrict__ A, const ushort* __restrict__ Wt,
                      const float* __restrict__ bias, const ushort* __restrict__ addsrc,
                      void* __restrict__ Cout, int M, int N, int K, int lda,
                      const float* __restrict__ bias2, const float* __restrict__ bias3,
                      void* __restrict__ out2, void* __restrict__ out3) {
    __shared__ ushort As[DEPTH][GBM * GBK];   // DEPTH x 8KB
    __shared__ ushort Bs[DEPTH][GBN * GBK];   // DEPTH x 8KB

    int tid = threadIdx.x;
    int lane = tid & 63;
    int wid = tid >> 6;              // 0..7
    int wr = wid >> 2, wc = wid & 3; // 2 x 4 wave grid

    // ---- bijective XCD swizzle (x,y only; z = K-slice) ----
    int gx = gridDim.x;
    int nwg = gx * gridDim.y;
    int orig = blockIdx.y * gx + blockIdx.x;
    int q8 = nwg >> 3;                       // nwg % 8 == 0 guaranteed by launch
    int swz = (orig & 7) * q8 + (orig >> 3);
    int bx = swz % gx, by = swz / gx;

    int brow = by * GBM;
    int bcol = bx * GBN;
    size_t koff = (size_t)blockIdx.z * K;

    int lrow = lane & 15;
    int kgrp = lane >> 4;

    f32x4 acc[4][2] = {};

    // staging: whole block loads A-tile with 1 instr, B-tile with 1 instr.
    int srow = tid >> 2;
    int sgran = (tid & 3) ^ ((srow >> 1) & 3);

    auto stage = [&](int buf, int k0) {
        const char* ga = (const char*)A +
            ((size_t)(brow + srow) * lda + koff + k0) * 2 + sgran * 16;
        __builtin_amdgcn_global_load_lds(
            (const __attribute__((address_space(1))) uint32_t*)ga,
            (__attribute__((address_space(3))) uint32_t*)(&As[buf][0] + (wid * 16) * GBK),
            16, 0, 0);
        const char* gb = (const char*)Wt +
            ((size_t)(bcol + srow) * lda + koff + k0) * 2 + sgran * 16;
        __builtin_amdgcn_global_load_lds(
            (const __attribute__((address_space(1))) uint32_t*)gb,
            (__attribute__((address_space(3))) uint32_t*)(&Bs[buf][0] + (wid * 16) * GBK),
            16, 0, 0);
    };

    int nk = K / GBK;
    constexpr int PRE = DEPTH - 1;           // stages in flight ahead of compute
#pragma unroll
    for (int s = 0; s < PRE; ++s)
        if (s < nk) stage(s, s * GBK);

    int cur = 0, stg = PRE;
    for (int t = 0; t < nk; ++t) {
        __builtin_amdgcn_sched_barrier(0);   // pin prev iter's ds_reads/MFMAs
        int rem = nk - 1 - t;                // stages still in flight beyond cur
        if constexpr (DEPTH == 5) {
            if (rem >= 3)      asm volatile("s_waitcnt vmcnt(6)" ::: "memory");
            else if (rem == 2) asm volatile("s_waitcnt vmcnt(4)" ::: "memory");
            else if (rem == 1) asm volatile("s_waitcnt vmcnt(2)" ::: "memory");
            else               asm volatile("s_waitcnt vmcnt(0)" ::: "memory");
        } else {
            if (rem >= 1)      asm volatile("s_waitcnt vmcnt(2)" ::: "memory");
            else               asm volatile("s_waitcnt vmcnt(0)" ::: "memory");
        }
        asm volatile("s_barrier" ::: "memory");          // no vmcnt drain
        if (t + PRE < nk) stage(stg, (t + PRE) * GBK);

        bf16x8 afrag[4], bfrag[2];
#pragma unroll
        for (int mi = 0; mi < 4; ++mi) {
            int row = wr * 64 + mi * 16 + lrow;
            int gran = kgrp ^ ((row >> 1) & 3);
            afrag[mi] = *(const bf16x8*)((const char*)&As[cur][0] + row * 64 + gran * 16);
        }
#pragma unroll
        for (int ni = 0; ni < 2; ++ni) {
            int row = wc * 32 + ni * 16 + lrow;
            int gran = kgrp ^ ((row >> 1) & 3);
            bfrag[ni] = *(const bf16x8*)((const char*)&Bs[cur][0] + row * 64 + gran * 16);
        }
#pragma unroll
        for (int mi = 0; mi < 4; ++mi)
#pragma unroll
            for (int ni = 0; ni < 2; ++ni)
                acc[mi][ni] = __builtin_amdgcn_mfma_f32_16x16x32_bf16(
                    afrag[mi], bfrag[ni], acc[mi][ni], 0, 0, 0);

        cur = (cur == DEPTH - 1) ? 0 : cur + 1;
        stg = (stg == DEPTH - 1) ? 0 : stg + 1;
    }

    if (MODE == 3) {
        int which = bcol >> 10;   // 0=q, 1=k, 2=v (128-tile never straddles)
        const float* bs = which == 0 ? bias : (which == 1 ? bias2 : bias3);
#pragma unroll
        for (int ni = 0; ni < 2; ++ni) {
            int col = bcol + wc * 32 + ni * 16 + lrow;
            int lcol = col & 1023;
            float bsv = bs[lcol];
#pragma unroll
            for (int mi = 0; mi < 4; ++mi) {
                f32x4 a = acc[mi][ni];
#pragma unroll
                for (int j = 0; j < 4; ++j) {
                    int row = brow + wr * 64 + mi * 16 + kgrp * 4 + j;
                    float val = a[j] + bsv;
                    if (which == 2) {
                        size_t idx = (size_t)(row >> 11) * ((size_t)DD * SS)
                                   + (size_t)lcol * SS + (row & (SS - 1));
                        ((ushort*)out3)[idx] = f2b(val);
                    } else if (which == 0) {
                        ((ushort*)Cout)[(size_t)row * DD + lcol] = f2b(val * QSCALE);
                    } else {
                        ((ushort*)out2)[(size_t)row * DD + lcol] = f2b(val);
                    }
                }
            }
        }
        return;
    }

    if (MODE == 4) {
        float* dst = (float*)Cout + (size_t)blockIdx.z * ((size_t)M * N);
#pragma unroll
        for (int ni = 0; ni < 2; ++ni) {
            int col = bcol + wc * 32 + ni * 16 + lrow;
#pragma unroll
            for (int mi = 0; mi < 4; ++mi) {
                f32x4 a = acc[mi][ni];
#pragma unroll
                for (int j = 0; j < 4; ++j) {
                    int row = brow + wr * 64 + mi * 16 + kgrp * 4 + j;
                    dst[(size_t)row * N + col] = a[j];
                }
            }
        }
        return;
    }

#pragma unroll
    for (int ni = 0; ni < 2; ++ni) {
        int col = bcol + wc * 32 + ni * 16 + lrow;
        float bsv = bias[col];
#pragma unroll
        for (int mi = 0; mi < 4; ++mi) {
            f32x4 a = acc[mi][ni];
#pragma unroll
            for (int j = 0; j < 4; ++j) {
                int row = brow + wr * 64 + mi * 16 + kgrp * 4 + j;
                float val = a[j] + bsv;
                if (MODE == 1) val = fmaxf(val, 0.f);
                if (BF16_OUT)
                    ((ushort*)Cout)[(size_t)row * N + col] = f2b(val);
                else
                    ((float*)Cout)[(size_t)row * N + col] = val;
            }
        }
    }
}

// ---------------- bf16 MFMA causal flash attention (swapped QK^T) ------------
// Block: 4 waves per (b, h, 64-query tile); wave w owns q rows [w*16, w*16+16).
// S^T = mfma(K, Q'): Q pre-scaled by 1/8*log2e -> softmax in exp2 domain.
// Defer-max (THR=11 log2): rescale only when __any(mx > m + THR).
// K/V double-buffered (depth-2); Ps overlays dead Qs. LDS = 40KB -> 4 blocks/CU.
// q-tile <- constant-sum swizzle: each CU's 4 resident blocks total 66 tiles.
__global__ __launch_bounds__(256)
void attn_mfma_kernel(const ushort* __restrict__ Qg, const ushort* __restrict__ Kg,
                      const ushort* __restrict__ Vtg, ushort* __restrict__ Og) {
    __shared__ ushort Qs[64 * 64];        // 8KB; reused as Ps after Q hoist
    __shared__ ushort Ks[2][64 * 64];     // 16KB
    __shared__ ushort Vs[2][64 * 64];     // 16KB

    int tid = threadIdx.x;
    int lane = tid & 63;
    int wid = tid >> 6;
    int bh = blockIdx.x;
    int b = bh >> 4, h = bh & 15;
    // constant-sum q-tile swizzle: y -> qt so {y, y+8, y+16, y+24} sum to 66
    int y = blockIdx.y;
    int jj = y >> 3, kk = y & 7;
    int qt = jj * 8 + ((jj & 1) ? 7 - kk : kk);
    int q0 = qt * 64;

    const ushort* Qbase = Qg + ((size_t)(b * SS + q0)) * DD + h * DH;
    const ushort* Kbase = Kg + ((size_t)(b * SS)) * DD + h * DH;
    const ushort* Vbase = Vtg + (size_t)bh * DH * SS;        // rows: d, stride SS

    int r0 = wid * 16;
    int rr0 = r0 + (lane >> 3);
    int g0 = lane & 7;
    int g = lane >> 4;               // 0..3 lane group
    int lr = lane & 15;              // q-row within wave (swapped layout)

    auto stageKV = [&](int buf, int k0) {
#pragma unroll
        for (int i = 0; i < 2; ++i) {
            int rr = rr0 + i * 8;
            int gg = g0 ^ (rr & 7);
            const ushort* srck = Kbase + (size_t)(k0 + rr) * DD + gg * 8;
            __builtin_amdgcn_global_load_lds(
                (const __attribute__((address_space(1))) uint32_t*)srck,
                (__attribute__((address_space(3))) uint32_t*)(&Ks[buf][0] + (r0 + i * 8) * 64),
                16, 0, 0);
            const ushort* srcv = Vbase + (size_t)rr * SS + k0 + gg * 8;
            __builtin_amdgcn_global_load_lds(
                (const __attribute__((address_space(1))) uint32_t*)srcv,
                (__attribute__((address_space(3))) uint32_t*)(&Vs[buf][0] + (r0 + i * 8) * 64),
                16, 0, 0);
        }
    };

    int nt = q0 / 64 + 1;

    // ---- prologue: Q (2 loads/wave, wave-local) + first K/V stage ----
    {
#pragma unroll
        for (int i = 0; i < 2; ++i) {
            int rr = rr0 + i * 8;
            int gg = g0 ^ (rr & 7);
            const ushort* src = Qbase + (size_t)rr * DD + gg * 8;
            __builtin_amdgcn_global_load_lds(
                (const __attribute__((address_space(1))) uint32_t*)src,
                (__attribute__((address_space(3))) uint32_t*)(Qs + (r0 + i * 8) * 64),
                16, 0, 0);
        }
    }
    stageKV(0, 0);
    asm volatile("s_waitcnt vmcnt(4)" ::: "memory");   // own Q rows landed (wave-local)

    // ---- hoist Q B-fragments (rows=q, k-major) ----
    bf16x8 aq[2];
    {
        int r = wid * 16 + lr;
#pragma unroll
        for (int ks = 0; ks < 2; ++ks) {
            int lg = ks * 4 + g;
            aq[ks] = *(const bf16x8*)((const char*)Qs + r * 128 + ((lg ^ (r & 7)) << 4));
        }
    }
    ushort* Ps = Qs;                 // Q dead in LDS from here

    f32x4 oacc[4] = {};
    float m = -INFINITY, l = 0.f;
    const float THR = 11.0f;         // exp2-domain defer-max threshold
    int qa = q0 + wid * 16 + lr;     // absolute q row for this lane

    int cur = 0;
    for (int t = 0; t < nt; ++t) {
        __builtin_amdgcn_sched_barrier(0);
        asm volatile("s_waitcnt vmcnt(0)" ::: "memory");   // stage(t) landed
        asm volatile("s_barrier" ::: "memory");
        if (t + 1 < nt) stageKV(cur ^ 1, (t + 1) * 64);
        int k0 = t * 64;

        // ---- S^T = K @ Q'^T : col(lane&15)=q-row, row=key (exp2 domain) ----
        f32x4 sacc[4] = {};
        __builtin_amdgcn_s_setprio(1);
#pragma unroll
        for (int ni = 0; ni < 4; ++ni) {
            int r = ni * 16 + lr;    // key row in K tile
#pragma unroll
            for (int ks = 0; ks < 2; ++ks) {
                int lg = ks * 4 + g;
                bf16x8 bk = *(const bf16x8*)((const char*)&Ks[cur][0] + r * 128 + ((lg ^ (r & 7)) << 4));
                sacc[ni] = __builtin_amdgcn_mfma_f32_16x16x32_bf16(bk, aq[ks], sacc[ni], 0, 0, 0);
            }
        }
        __builtin_amdgcn_s_setprio(0);

        // ---- causal mask (diagonal tile only) ----
        if (k0 == q0) {
#pragma unroll
            for (int ni = 0; ni < 4; ++ni) {
#pragma unroll
                for (int j = 0; j < 4; ++j) {
                    int key = q0 + ni * 16 + g * 4 + j;
                    if (key > qa) sacc[ni][j] = -INFINITY;
                }
            }
        }

        // ---- tile row-max ----
        float mx = sacc[0][0];
#pragma unroll
        for (int ni = 0; ni < 4; ++ni)
#pragma unroll
            for (int j = 0; j < 4; ++j) mx = fmaxf(mx, sacc[ni][j]);
        mx = fmaxf(mx, __shfl_xor(mx, 16));
        mx = fmaxf(mx, __shfl_xor(mx, 32));

        // ---- defer-max: rescale only when some row grew past THR ----
        if (__any(mx > m + THR)) {
            float mn = fmaxf(m, mx);
            float corr = __builtin_amdgcn_exp2f(m - mn);
            m = mn;
            l *= corr;
            float cj[4];
#pragma unroll
            for (int j = 0; j < 4; ++j)
                cj[j] = __shfl(corr, (lane & 48) | (g * 4 + j));
#pragma unroll
            for (int ni = 0; ni < 4; ++ni)
#pragma unroll
                for (int j = 0; j < 4; ++j) oacc[ni][j] *= cj[j];
        }

        // ---- P = exp2(S - m), row-sum ----
        float p[4][4];
        float rs = 0.f;
#pragma unroll
        for (int ni = 0; ni < 4; ++ni)
#pragma unroll
            for (int j = 0; j < 4; ++j) {
                p[ni][j] = __builtin_amdgcn_exp2f(sacc[ni][j] - m);
                rs += p[ni][j];
            }
        rs += __shfl_xor(rs, 16);
        rs += __shfl_xor(rs, 32);
        l += rs;

        // ---- P -> bf16 -> wave-private LDS slab (4 x 8B stores) ----
        {
            int row = wid * 16 + lr;
#pragma unroll
            for (int ni = 0; ni < 4; ++ni) {
                bf16x4 w4 = { (__bf16)p[ni][0], (__bf16)p[ni][1],
                              (__bf16)p[ni][2], (__bf16)p[ni][3] };
                int gran = (ni * 2 + (g >> 1)) ^ (row & 7);
                *(bf16x4*)((char*)Ps + row * 128 + (gran << 4) + (g & 1) * 8) = w4;
            }
        }
        asm volatile("s_waitcnt lgkmcnt(0)" ::: "memory");   // wave-local P landed

        // ---- O += P @ V ----
        bf16x8 ap[2];
        {
            int r = wid * 16 + lr;
#pragma unroll
            for (int ks = 0; ks < 2; ++ks) {
                int lg = ks * 4 + g;
                ap[ks] = *(const bf16x8*)((const char*)Ps + r * 128 + ((lg ^ (r & 7)) << 4));
            }
        }
        __builtin_amdgcn_s_setprio(1);
#pragma unroll
        for (int ni = 0; ni < 4; ++ni) {
            int r = ni * 16 + lr;    // d row in Vt tile
#pragma unroll
            for (int ks = 0; ks < 2; ++ks) {
                int lg = ks * 4 + g;
                bf16x8 bv = *(const bf16x8*)((const char*)&Vs[cur][0] + r * 128 + ((lg ^ (r & 7)) << 4));
                oacc[ni] = __builtin_amdgcn_mfma_f32_16x16x32_bf16(ap[ks], bv, oacc[ni], 0, 0, 0);
            }
        }
        __builtin_amdgcn_s_setprio(0);
        cur ^= 1;
    }

    // ---- epilogue: divide by l (broadcast per row), write bf16 ----
#pragma unroll
    for (int j = 0; j < 4; ++j) {
        float lj = __shfl(l, (lane & 48) | (g * 4 + j));
        float inv = 1.f / lj;
        int gr = q0 + wid * 16 + g * 4 + j;
#pragma unroll
        for (int ni = 0; ni < 4; ++ni) {
            int d = ni * 16 + lr;
            Og[((size_t)(b * SS + gr)) * DD + h * DH + d] = f2b(oacc[ni][j] * inv);
        }
    }
}

// ---------------- Launch ------------------------------------------------------
extern "C" void kernel_launch(void* const* d_in, const int* in_sizes, int n_in,
                              void* d_out, int out_size, void* d_ws, size_t ws_size,
                              hipStream_t stream) {
    const float* inputs    = (const float*)d_in[0];
    const float* ln1_scale = (const float*)d_in[1];
    const float* ln1_shift = (const float*)d_in[2];
    const float* Wq = (const float*)d_in[3];
    const float* bq = (const float*)d_in[4];
    const float* Wk = (const float*)d_in[5];
    const float* bk = (const float*)d_in[6];
    const float* Wv = (const float*)d_in[7];
    const float* bv = (const float*)d_in[8];
    const float* Wo = (const float*)d_in[9];
    const float* bo = (const float*)d_in[10];
    const float* W1 = (const float*)d_in[11];
    const float* b1 = (const float*)d_in[12];
    const float* W2 = (const float*)d_in[13];
    const float* b2 = (const float*)d_in[14];
    const float* ln2_scale = (const float*)d_in[15];
    const float* ln2_shift = (const float*)d_in[16];
    float* out = (float*)d_out;

    const size_t MB = 1024 * 1024;
    char* w = (char*)d_ws;
    // phase-1 buffers
    ushort* q_b   = (ushort*)(w + 0 * MB);     // 8MB (dead after attn)
    ushort* k_b   = (ushort*)(w + 8 * MB);     // 8MB (dead after attn)
    ushort* vt_b  = (ushort*)(w + 16 * MB);    // 8MB (dead after attn)
    ushort* att_b = (ushort*)(w + 24 * MB);    // 8MB (dead after Wo GEMM)
    // Wo split-K partials (contiguous 32MB), alive between Wo GEMM and reduce
    float*  pw    = (float*)(w + 32 * MB);     // 32MB (z=0: 32-48, z=1: 48-64)
    // phase-2 buffers (reuse dead regions)
    ushort* proj_b= (ushort*)(w + 0 * MB);     // 8MB (over q_b)
    ushort* o2_b  = (ushort*)(w + 8 * MB);     // 8MB (over k_b)
    // FFN2 split-K partials (contiguous 32MB, over vt/att/pw0)
    float*  pf    = (float*)(w + 16 * MB);     // 32MB (16-48)
    ushort* h1_b  = (ushort*)(w + 64 * MB);    // 32MB
    ushort* wq_t  = (ushort*)(w + 96 * MB);    // 2MB (q/k/v contiguous = fused 3072xK)
    ushort* wk_t  = (ushort*)(w + 98 * MB);
    ushort* wv_t  = (ushort*)(w + 100 * MB);
    ushort* wo_t  = (ushort*)(w + 102 * MB);
    ushort* w1_t  = (ushort*)(w + 104 * MB);   // 8MB
    ushort* w2_t  = (ushort*)(w + 112 * MB);   // 8MB
    ushort* xn_b  = (ushort*)(w + 120 * MB);   // 8MB

    // 0. weight convert+transpose
    transpose_bf16_kernel<<<dim3(DD / 32, DD / 32), 256, 0, stream>>>(Wq, wq_t, DD, DD);
    transpose_bf16_kernel<<<dim3(DD / 32, DD / 32), 256, 0, stream>>>(Wk, wk_t, DD, DD);
    transpose_bf16_kernel<<<dim3(DD / 32, DD / 32), 256, 0, stream>>>(Wv, wv_t, DD, DD);
    transpose_bf16_kernel<<<dim3(DD / 32, DD / 32), 256, 0, stream>>>(Wo, wo_t, DD, DD);
    transpose_bf16_kernel<<<dim3(FFN / 32, DD / 32), 256, 0, stream>>>(W1, w1_t, DD, FFN);
    transpose_bf16_kernel<<<dim3(DD / 32, FFN / 32), 256, 0, stream>>>(W2, w2_t, FFN, DD);

    // 1. LN1 -> bf16
    ln_kernel<<<NROW, 256, 0, stream>>>(inputs, ln1_scale, ln1_shift, xn_b);

    // 2. Fused QKV projection (N=3072; V transposed per head; q pre-scaled).
    dim3 gqkv(3 * DD / GBN, NROW / GBM, 1);   // 24 x 32
    gemm_bf16_kernel<3, true, 3><<<gqkv, 512, 0, stream>>>(
        xn_b, wq_t, bq, nullptr, q_b, NROW, 3 * DD, DD, DD, bk, bv, k_b, vt_b);

    // 3. MFMA flash attention -> att_b (bf16)
    dim3 ga(BB * HH, SS / 64);
    attn_mfma_kernel<<<ga, 256, 0, stream>>>(q_b, k_b, vt_b, att_b);

    // 4. Output projection, split-K=2 -> fp32 partials pw. 512 blocks.
    dim3 g1z(DD / GBN, NROW / GBM, 2);        // 8 x 32 x 2
    gemm_bf16_kernel<4, false, 5><<<g1z, 512, 0, stream>>>(
        att_b, wo_t, nullptr, nullptr, pw, NROW, DD, DD / 2, DD, nullptr, nullptr, nullptr, nullptr);
    reduce_wo_kernel<<<(NROW * DD / 4) / 256, 256, 0, stream>>>(
        pw, pw + (size_t)NROW * DD, bo, proj_b);

    // 5. residual + LN2 -> o2 (bf16, serves as GEMM input AND final residual)
    ln_res_kernel<<<NROW, 256, 0, stream>>>(proj_b, inputs, ln2_scale, ln2_shift, o2_b);

    // 6. FFN up + relu -> h1 (bf16). 1024 blocks -> depth-3.
    dim3 g2(FFN / GBN, NROW / GBM, 1);
    gemm_bf16_kernel<1, true, 3><<<g2, 512, 0, stream>>>(
        o2_b, w1_t, b1, nullptr, h1_b, NROW, FFN, DD, DD, nullptr, nullptr, nullptr, nullptr);

    // 7. FFN down, split-K=2 -> fp32 partials pf. 512 blocks.
    gemm_bf16_kernel<4, false, 5><<<g1z, 512, 0, stream>>>(
        h1_b, w2_t, nullptr, nullptr, pf, NROW, DD, FFN / 2, FFN, nullptr, nullptr, nullptr, nullptr);
    reduce_ffn2_kernel<<<(NROW * DD / 4) / 256, 256, 0, stream>>>(
        pf, pf + (size_t)NROW * DD, b2, o2_b, out);
}